// Round 12
// baseline (256.878 us; speedup 1.0000x reference)
//
#include <hip/hip_runtime.h>
#include <math.h>

// Problem constants: B=16, H=W=128, C=64, M1=M2=16
// Workspace layout (float offsets):
#define OFF_TBL 0u            // 128 x {cos,sin}(2*pi*m/128)          (256)
#define OFF_S1  256u          // instance-norm-1 raw sums [b*64+c][2] (2048)
#define OFF_S2  2304u         // instance-norm-2 stats (s1,s2)        (2048)
#define OFF_PQ  4352u         // PT[b][(ky*64+c)*2+ri][h] u32-packed bf16 hi/lo (4194304)
                              //   aliased later with Q[b][h][ky][o][2] f32
#define OFF_X   4198656u      // X[b][kx][ky][c][2] f32               (1048576)
#define OFF_O   5247232u      // Out[b][kx][ky][o][2] f32             (1048576)
                              //   head doubles (pre-mix) as u16 trig tables:
                              //   FdAh[32][128] @0, FdAl @4096, EdAh[64][128] @8192, EdAl @16384
#define OFF_WT  6295808u      // WT[mode][i][o][2]                    (4194304)
// total = 10490112 floats = 41.96 MB
// X region is dead after k_mix -> reuse as u16 arrays for bf16-split MLP weights:
//   u16[0..8192) w1hi   [8192..16384) w1lo   [16384..24576) w2hi
//   [24576..32768) w2lo  [32768..36864) Mhi  [36864..40960) Mlo

typedef __attribute__((ext_vector_type(8))) short bfrag;
typedef __attribute__((ext_vector_type(4))) float f4v;
#define MFMA(A,B,C) __builtin_amdgcn_mfma_f32_16x16x32_bf16(A,B,C,0,0,0)

// compile-time float4 component select -- NO address-taken indexing (scratch hazard)
#define F4GET(v, i) ((i)==0 ? (v).x : (i)==1 ? (v).y : (i)==2 ? (v).z : (v).w)

__device__ __forceinline__ unsigned short f2bf_rn(float x) {
    unsigned u = __float_as_uint(x);
    unsigned r = u + 0x7FFFu + ((u >> 16) & 1u);
    return (unsigned short)(r >> 16);
}
__device__ __forceinline__ float bf2f(unsigned short h) {
    return __uint_as_float(((unsigned)h) << 16);
}
__device__ __forceinline__ void split2(float x, unsigned short& hi, unsigned short& lo) {
    hi = f2bf_rn(x);
    lo = f2bf_rn(x - bf2f(hi));
}
// tanh-form GELU; matches exact GELU to <1e-5 for |x| <= 0.5 (our range)
__device__ __forceinline__ float gelu_t(float x) {
    float u = 0.79788456080286536f * (x + 0.044715f * x * x * x);
    float e = __expf(2.f * u);
    float th = 1.f - 2.f / (e + 1.f);
    return 0.5f * x * (1.f + th);
}

// block 0: twiddle table + zero S1/S2. blocks 1..48: bf16-split trig tables
// (F for dftw, E for dfth) into the O region (dead until k_mix overwrites).
__global__ void k_init(float* __restrict__ ws) {
    int t = threadIdx.x, bid = blockIdx.x;
    if (bid == 0) {
        if (t < 128) {
            double ang = 6.283185307179586476925286766559 * (double)t / 128.0;
            ws[OFF_TBL + 2*t]     = (float)cos(ang);
            ws[OFF_TBL + 2*t + 1] = (float)sin(ang);
        }
        for (int i = t; i < 4096; i += 256) ws[OFF_S1 + i] = 0.f;
        return;
    }
    int e = (bid - 1)*256 + t;   // 0..12287
    unsigned short* OU = (unsigned short*)(ws + OFF_O);
    const double TWO_PI = 6.283185307179586476925286766559;
    if (e < 4096) {              // FdA[row=ri*16+ky][w]: re rows cos, im rows -sin
        int row = e >> 7, w = e & 127, ky = row & 15;
        double ang = TWO_PI * (double)((ky * w) & 127) / 128.0;
        double v = (row < 16) ? cos(ang) : -sin(ang);
        unsigned short hi, lo; split2((float)v, hi, lo);
        OU[e] = hi; OU[4096 + e] = lo;
    } else {                     // EdA[row=2kx+s][h]: s=0 cos, s=1 sin (of freq f(kx))
        int e2 = e - 4096, row = e2 >> 7, h = e2 & 127;
        int kx = row >> 1, f = kx < 16 ? kx : 96 + kx;
        double ang = TWO_PI * (double)((f * h) & 127) / 128.0;
        double v = (row & 1) ? sin(ang) : cos(ang);
        unsigned short hi, lo; split2((float)v, hi, lo);
        OU[8192 + e2] = hi; OU[16384 + e2] = lo;
    }
}

// weight transpose: [i][o][kx][ky] (x4 arrays) -> WT[mode][i][o][{re,im}]. grid (64=i, 2=part)
__global__ void k_trans(const float* __restrict__ w1r, const float* __restrict__ w1i,
                        const float* __restrict__ w2r, const float* __restrict__ w2i,
                        float* __restrict__ ws) {
    __shared__ float Lr[16*257], Li[16*257];
    int t = threadIdx.x;
    int i = blockIdx.x;
    int part = blockIdx.y;
    float* WT = ws + OFF_WT;
    const float* wr = part ? w2r : w1r;
    const float* wi = part ? w2i : w1i;
    for (int oc = 0; oc < 4; oc++) {
        int o0 = oc * 16;
        __syncthreads();
        for (int idx = t; idx < 4096; idx += 256) {
            int oo = idx >> 8, m = idx & 255;
            Lr[oo*257 + m] = wr[(i*64 + o0 + oo)*256 + m];
            Li[oo*257 + m] = wi[(i*64 + o0 + oo)*256 + m];
        }
        __syncthreads();
        for (int idx = t; idx < 8192; idx += 256) {
            int mode = idx >> 5, rem = idx & 31, oo = rem >> 1, ri = rem & 1;
            float val = ri ? Li[oo*257 + mode] : Lr[oo*257 + mode];
            int gm = part*256 + mode;
            WT[((gm*64 + i)*64 + (o0 + oo))*2 + ri] = val;
        }
    }
}

// bf16-split MLP weights + iDFT-w matrix M into the dead X region. grid 80
__global__ void k_wmlp(const float* __restrict__ mw1, const float* __restrict__ mw2,
                       float* __restrict__ ws) {
    int i = blockIdx.x * 256 + threadIdx.x;   // [0, 20480)
    unsigned short* xu = (unsigned short*)(ws + OFF_X);
    if (i < 8192) {
        unsigned short hi, lo; split2(mw1[i], hi, lo);
        xu[i] = hi; xu[8192 + i] = lo;
    } else if (i < 16384) {
        int k = i - 8192;
        unsigned short hi, lo; split2(mw2[k], hi, lo);
        xu[16384 + k] = hi; xu[24576 + k] = lo;
    } else if (i < 20480) {
        int m = i - 16384;           // w*32 + k
        int w = m >> 5, k = m & 31;
        int ky = k >> 1;
        double ang = 6.283185307179586476925286766559 * (double)((ky * w) & 127) / 128.0;
        double v = (k & 1) ? -sin(ang) : cos(ang);
        double a = (ky == 0) ? 1.0 : 2.0;
        float val = (float)(v * a) * (1.f/16384.f);
        unsigned short hi, lo; split2(val, hi, lo);
        xu[32768 + m] = hi; xu[36864 + m] = lo;
    }
}

// ===== DIAGNOSTIC ABLATION of k_dftw (rule: ablate before optimizing) =====
// MODE 0: real kernel (R9 structure), writes PT + S1 atomics.
// MODE 1: global loads + stats only (asm-sunk). No LDS/MFMA/epilogue.
// MODE 2: loads + stats + split2 + LDS stage + frag reads, MFMA-light, acc sunk.
// MODE 3: NO global loads (synthetic reg data) + full stage/MFMA/epilogue;
//         writes garbage PT -- fully overwritten by the MODE-0 launch after it.
template<int MODE>
__global__ __launch_bounds__(256) void k_dftw_t(const float* __restrict__ x, float* __restrict__ ws) {
    __shared__ unsigned BTall[4096];    // 16KB: per-wave 4KB {BTh 2KB | BTl 2KB}; reused as trans
    int t = threadIdx.x;
    int hq = blockIdx.x, cs = blockIdx.y, b = blockIdx.z;
    int c0 = cs*32;
    int l = t & 63, wv = t >> 6;
    int h = hq*4 + wv;
    char* wbase = (char*)BTall + wv*4096;

    const unsigned short* OU = (const unsigned short*)(ws + OFF_O);
    const unsigned short* FdAh = OU, *FdAl = OU + 4096;

    // A-frags: FdA rows (mt*16 + lane&15), k = kc*32 + oct*8
    bfrag ma_h[2][4], ma_l[2][4];
    if (MODE != 1) {
        #pragma unroll
        for (int mt = 0; mt < 2; mt++)
            #pragma unroll
            for (int kc = 0; kc < 4; kc++) {
                int off = (mt*16 + (l & 15))*128 + kc*32 + (l >> 4)*8;
                ma_h[mt][kc] = *(const bfrag*)(FdAh + off);
                ma_l[mt][kc] = *(const bfrag*)(FdAl + off);
            }
    }
    f4v acc[2][2];
    #pragma unroll
    for (int mt = 0; mt < 2; mt++)
        #pragma unroll
        for (int nt = 0; nt < 2; nt++) acc[mt][nt] = (f4v){0.f,0.f,0.f,0.f};

    float s1a[4] = {0,0,0,0}, s2a[4] = {0,0,0,0};   // stats for c = c0 + 4*cq + j
    int cq = l & 7, r = l >> 3;
    const float* xb = x + ((long)(b*128 + h))*8192 + c0;  // this wave's h row, c half

    #pragma unroll
    for (int kc = 0; kc < 4; kc++) {
        // ---- stage (dense): 8-lane groups read 128B contiguous (2 full sectors) ----
        #pragma unroll
        for (int it = 0; it < 2; it++) {
            int wp = it*8 + r;                       // w-pair 0..15
            float4 a, bb;
            if (MODE == 3) {
                float base_ = (float)(t*3 + kc*5 + it*7) * 0.001f;
                a  = make_float4(base_, base_ + 0.1f, base_ + 0.2f, base_ + 0.3f);
                bb = make_float4(base_ + 0.4f, base_ + 0.5f, base_ + 0.6f, base_ + 0.7f);
            } else {
                const float* src = xb + (kc*32 + wp*2)*64 + cq*4;
                a = *(const float4*)src;
                bb = *(const float4*)(src + 64);
            }
            #pragma unroll
            for (int j = 0; j < 4; j++) {
                float va = F4GET(a, j), vb = F4GET(bb, j);
                s1a[j] += va + vb;
                s2a[j] += va*va + vb*vb;
                if (MODE != 1) {
                    unsigned short ah, al2, bh2, bl2;
                    split2(va, ah, al2); split2(vb, bh2, bl2);
                    unsigned hp = (unsigned)ah | ((unsigned)bh2 << 16);
                    unsigned lp = (unsigned)al2 | ((unsigned)bl2 << 16);
                    int lc = cq + 8*j;                   // col index 0..31
                    unsigned bad = (unsigned)(lc*64 + ((wp*4) ^ (((lc >> 1) & 3) << 4)));
                    *(unsigned*)(wbase + bad) = hp;
                    *(unsigned*)(wbase + 2048 + bad) = lp;
                }
            }
        }
        // ---- MFMA: 2 Ntiles x 2 Mtiles, 3-term hi/lo ----
        if (MODE != 1) {
            #pragma unroll
            for (int nt = 0; nt < 2; nt++) {
                int lc = nt*16 + (l & 15);
                unsigned ro = (unsigned)(lc*64 + (((l >> 4)*16) ^ (((lc >> 1) & 3) << 4)));
                bfrag bh = *(const bfrag*)(wbase + ro);
                bfrag bl = *(const bfrag*)(wbase + 2048 + ro);
                if (MODE == 2) {
                    // MFMA-light: keep frags + staging alive, 1/3 matrix work
                    acc[0][nt] = MFMA(ma_h[0][kc], bh, acc[0][nt]);
                    acc[0][nt] = MFMA(ma_h[0][kc], bl, acc[0][nt]);
                } else {
                    #pragma unroll
                    for (int mt = 0; mt < 2; mt++) {
                        f4v a_ = acc[mt][nt];
                        a_ = MFMA(ma_h[mt][kc], bh, a_);
                        a_ = MFMA(ma_h[mt][kc], bl, a_);
                        a_ = MFMA(ma_l[mt][kc], bh, a_);
                        acc[mt][nt] = a_;
                    }
                }
            }
        }
    }
    // ---- stats reduce (over r-groups sharing cq) ----
    #pragma unroll
    for (int j = 0; j < 4; j++) {
        s1a[j] += __shfl_down(s1a[j], 8, 64);
        s1a[j] += __shfl_down(s1a[j], 16, 64);
        s1a[j] += __shfl_down(s1a[j], 32, 64);
        s2a[j] += __shfl_down(s2a[j], 8, 64);
        s2a[j] += __shfl_down(s2a[j], 16, 64);
        s2a[j] += __shfl_down(s2a[j], 32, 64);
    }
    if (MODE == 0) {
        if (l < 8) {
            #pragma unroll
            for (int j = 0; j < 4; j++) {
                int c = c0 + 4*cq + j;
                atomicAdd(&ws[OFF_S1 + (b*64 + c)*2],     s1a[j]);
                atomicAdd(&ws[OFF_S1 + (b*64 + c)*2 + 1], s2a[j]);
            }
        }
    } else {
        #pragma unroll
        for (int j = 0; j < 4; j++)
            asm volatile("" :: "v"(s1a[j]), "v"(s2a[j]));   // keep loads alive (anti-DCE)
    }
    if (MODE == 2) {
        #pragma unroll
        for (int nt = 0; nt < 2; nt++)
            asm volatile("" :: "v"(acc[0][nt][0]), "v"(acc[0][nt][1]),
                             "v"(acc[0][nt][2]), "v"(acc[0][nt][3]));
        return;
    }
    if (MODE == 1) return;

    // ---- epilogue (MODE 0 and 3): split-pack -> wave trans buf -> PT ----
    #pragma unroll
    for (int mt = 0; mt < 2; mt++)
        #pragma unroll
        for (int nt = 0; nt < 2; nt++)
            #pragma unroll
            for (int rr = 0; rr < 4; rr++) {
                float v = acc[mt][nt][rr];
                unsigned short hi, lo; split2(v, hi, lo);
                int trow = mt*16 + (l >> 4)*4 + rr;
                int c_local = (l & 7)*4 + nt*2 + ((l >> 3) & 1);
                unsigned ad = (unsigned)(trow*128 + ((c_local*4) ^ ((trow & 7) << 4)));
                *(unsigned*)(wbase + ad) = ((unsigned)hi << 16) | (unsigned)lo;
            }
    __syncthreads();
    unsigned* PT = (unsigned*)(ws + OFF_PQ);
    #pragma unroll
    for (int s = 0; s < 4; s++) {
        int seg = s*256 + t;                 // 1024 (trow,c) pairs
        int trow = seg >> 5, c = seg & 31;
        unsigned ad = (unsigned)(trow*128 + ((c*4) ^ ((trow & 7) << 4)));
        uint4 vz;
        vz.x = *(const unsigned*)((const char*)BTall + ad);
        vz.y = *(const unsigned*)((const char*)BTall + 4096 + ad);
        vz.z = *(const unsigned*)((const char*)BTall + 8192 + ad);
        vz.w = *(const unsigned*)((const char*)BTall + 12288 + ad);
        int ri = trow >> 4, ky = trow & 15;
        long grow = ((long)(ky*64 + c0 + c))*2 + ri;
        *(uint4*)(PT + (((long)b*2048 + grow) << 7) + hq*4) = vz;
    }
}

// MFMA forward DFT along h: X[2kx+s][(c,ri)] = EdA @ PT (per ky,b).
__global__ __launch_bounds__(256) void k_dfth(float* __restrict__ ws) {
    __shared__ unsigned Bsh[16384];   // BTh 32KB (128 cols x 256B) | BTl 32KB
    int t = threadIdx.x;
    int ky = blockIdx.x, b = blockIdx.y;
    int l = t & 63, wv = t >> 6;
    char* bh_base = (char*)Bsh;
    char* bl_base = bh_base + 32768;
    const unsigned* PT = (const unsigned*)(ws + OFF_PQ);
    const unsigned short* OU = (const unsigned short*)(ws + OFF_O);
    const unsigned short* EdAh = OU + 8192, *EdAl = OU + 16384;

    {
        int n = t >> 1, hh = (t & 1)*64;
        const uint4* src = (const uint4*)(PT + ((long)b*2048 + ky*128 + n)*128 + hh);
        #pragma unroll
        for (int jj = 0; jj < 16; jj++) {
            uint4 v = src[jj];
            unsigned h01 = (v.x >> 16) | (v.y & 0xFFFF0000u);
            unsigned h23 = (v.z >> 16) | (v.w & 0xFFFF0000u);
            unsigned l01 = (v.x & 0xFFFFu) | (v.y << 16);
            unsigned l23 = (v.z & 0xFFFFu) | (v.w << 16);
            int kk = hh + jj*4;
            unsigned ad = (unsigned)(n*256 + ((kk*2) ^ ((n & 7) << 4)));
            *(uint2*)(bh_base + ad) = make_uint2(h01, h23);
            *(uint2*)(bl_base + ad) = make_uint2(l01, l23);
        }
    }
    bfrag ea_h[4], ea_l[4];
    #pragma unroll
    for (int kc = 0; kc < 4; kc++) {
        int off = (wv*16 + (l & 15))*128 + kc*32 + (l >> 4)*8;
        ea_h[kc] = *(const bfrag*)(EdAh + off);
        ea_l[kc] = *(const bfrag*)(EdAl + off);
    }
    __syncthreads();
    f4v acc[8];
    #pragma unroll
    for (int nt = 0; nt < 8; nt++) acc[nt] = (f4v){0.f,0.f,0.f,0.f};
    #pragma unroll
    for (int kc = 0; kc < 4; kc++)
        #pragma unroll
        for (int nt = 0; nt < 8; nt++) {
            int col = nt*16 + (l & 15);
            unsigned ro = (unsigned)(col*256 + ((kc*64 + (l >> 4)*16) ^ ((col & 7) << 4)));
            bfrag bh = *(const bfrag*)(bh_base + ro);
            bfrag bl = *(const bfrag*)(bl_base + ro);
            acc[nt] = MFMA(ea_h[kc], bh, acc[nt]);
            acc[nt] = MFMA(ea_h[kc], bl, acc[nt]);
            acc[nt] = MFMA(ea_l[kc], bh, acc[nt]);
        }
    float* X = ws + OFF_X;
    #pragma unroll
    for (int nt = 0; nt < 8; nt++)
        #pragma unroll
        for (int p = 0; p < 2; p++) {
            float s0 = acc[nt][2*p], s1 = acc[nt][2*p + 1];
            float partner = __shfl_xor(s1, 1, 64);
            float res = (l & 1) ? (s0 - partner) : (s0 + partner);
            int kx = wv*8 + (l >> 4)*2 + p;
            X[(((long)b*32 + kx)*16 + ky)*128 + nt*16 + (l & 15)] = res;
        }
}

// per-mode complex mix with rho1 scaling folded into X staging. grid 512 (=mode)
__global__ void k_mix(float* __restrict__ ws) {
    __shared__ float Wsh[8192];
    __shared__ float Xs[2048];
    __shared__ float rhoT[1024];
    int t = threadIdx.x;
    int mode = blockIdx.x;
    int kxI = mode >> 4, ky = mode & 15;
    const float* WT = ws + OFF_WT;
    const float* X = ws + OFF_X;
    float* O = ws + OFF_O;
    for (int i = t; i < 1024; i += 256) {
        float a = ws[OFF_S1 + 2*i], s = ws[OFF_S1 + 2*i + 1];
        float m = a * (1.f/16384.f);
        float v = s * (1.f/16384.f) - m*m;
        rhoT[i] = rsqrtf(v + 1e-5f);
    }
    for (int idx = t; idx < 8192; idx += 256) Wsh[idx] = WT[(long)mode*8192 + idx];
    __syncthreads();
    for (int idx = t; idx < 2048; idx += 256) {
        int b = idx >> 7, r = idx & 127;
        Xs[idx] = X[((b*32 + kxI)*16 + ky)*128 + r] * rhoT[b*64 + (r >> 1)];
    }
    __syncthreads();
    int o = t & 63, bg = t >> 6;
    float accr[4] = {0,0,0,0}, acci[4] = {0,0,0,0};
    for (int i = 0; i < 64; i++) {
        float wr = Wsh[(i*64 + o)*2], wi = Wsh[(i*64 + o)*2 + 1];
        #pragma unroll
        for (int j = 0; j < 4; j++) {
            float xr = Xs[(bg*4 + j)*128 + 2*i], xi = Xs[(bg*4 + j)*128 + 2*i + 1];
            accr[j] += xr*wr - xi*wi;
            acci[j] += xr*wi + xi*wr;
        }
    }
    #pragma unroll
    for (int j = 0; j < 4; j++) {
        int b = bg*4 + j;
        float2* dst = (float2*)(O + ((b*32 + kxI)*16 + ky)*128);
        dst[o] = make_float2(accr[j], acci[j]);
    }
}

// Parseval stats of y directly from O. grid (16=b, 4=gg), 256 thr.
__global__ void k_pstats(float* __restrict__ ws) {
    __shared__ float red[256];
    int t = threadIdx.x, b = blockIdx.x, gg = blockIdx.y;
    int c = t & 63, g = t >> 6;
    const float* O = ws + OFF_O + (long)b*65536;   // [(kxI*16+ky)*128 + 2c]
    float t0 = 0.f, t2 = 0.f;
    int k0 = gg*8 + g*2;
    for (int kxI = k0; kxI < k0 + 2; kxI++)
        for (int ky = 0; ky < 16; ky++) {
            float re = O[(kxI*16 + ky)*128 + 2*c];
            float im = O[(kxI*16 + ky)*128 + 2*c + 1];
            float p = re*re + im*im;
            if (ky == 0) t0 += p; else t2 += p;
        }
    float s2p = 0.5f*t0 + 2.f*t2;
    if (gg == 0 && g == 0) {
        float ar = O[2*c], ai = O[2*c + 1];        // kxI=0, ky=0
        float t1 = ar*ar - ai*ai;
        for (int k = 1; k <= 15; k++) {
            float xr = O[(k*16)*128 + 2*c],        xi = O[(k*16)*128 + 2*c + 1];
            float yr = O[((32-k)*16)*128 + 2*c],   yi = O[((32-k)*16)*128 + 2*c + 1];
            t1 += 2.f*(xr*yr - xi*yi);
        }
        s2p += 0.5f*t1;
        ws[OFF_S2 + (b*64 + c)*2] = ar;            // s1 (mean term)
    }
    red[t] = s2p;
    __syncthreads();
    if (t < 64) {
        float s = red[t] + red[t+64] + red[t+128] + red[t+192];
        atomicAdd(&ws[OFF_S2 + (b*64 + t)*2 + 1], s * (1.f/16384.f));
    }
}

// inverse DFT along h: Q[b][h][ky][o] = sum_kx Out e^{+i 2pi f(kx) h/128}. grid (hg=16,b=16)
__global__ void k_idfth(float* __restrict__ ws) {
    __shared__ float Os[8192];
    __shared__ float tblL[256];
    int t = threadIdx.x;
    int hg = blockIdx.x, b = blockIdx.y;
    for (int i = t; i < 256; i += 256) tblL[i] = ws[OFF_TBL + i];
    const float* O = ws + OFF_O;
    float* Q = ws + OFF_PQ;
    int o = t & 63, kyg = t >> 6;
    float accr[4][8], acci[4][8];
    #pragma unroll
    for (int kk = 0; kk < 4; kk++)
        #pragma unroll
        for (int h = 0; h < 8; h++) { accr[kk][h] = 0.f; acci[kk][h] = 0.f; }
    for (int kc = 0; kc < 8; kc++) {
        __syncthreads();
        for (int idx = t; idx < 8192; idx += 256) Os[idx] = O[(long)b*65536 + kc*8192 + idx];
        __syncthreads();
        for (int k4 = 0; k4 < 4; k4++) {
            int kxI = kc*4 + k4;
            int freq = kxI < 16 ? kxI : 96 + kxI;
            float vr[4], vi[4];
            #pragma unroll
            for (int kk = 0; kk < 4; kk++) {
                int ky = kyg*4 + kk;
                vr[kk] = Os[((k4*16 + ky)*64 + o)*2];
                vi[kk] = Os[((k4*16 + ky)*64 + o)*2 + 1];
            }
            for (int h = 0; h < 8; h++) {
                int habs = hg*8 + h;
                int m = (freq * habs) & 127;
                float cs = tblL[2*m], sn = tblL[2*m + 1];
                #pragma unroll
                for (int kk = 0; kk < 4; kk++) {
                    accr[kk][h] += vr[kk]*cs - vi[kk]*sn;   // * e^{+i th}
                    acci[kk][h] += vr[kk]*sn + vi[kk]*cs;
                }
            }
        }
    }
    #pragma unroll
    for (int kk = 0; kk < 4; kk++)
        #pragma unroll
        for (int h = 0; h < 8; h++) {
            int ky = kyg*4 + kk, habs = hg*8 + h;
            float2* dst = (float2*)(Q + ((long)(b*128 + habs)*16 + ky)*128);
            dst[o] = make_float2(accr[kk][h], acci[kk][h]);
        }
}

// fused MFMA kernel: Y = M@Qm (iDFT-w), z = (Y-mu)*rho, h = GELU(z@W1+b1),
// out = h@W2+b2. grid (h=128,b=16)
__global__ __launch_bounds__(256, 2) void k_mlp(const float* __restrict__ mb1,
                      const float* __restrict__ mb2,
                      float* __restrict__ out, const float* __restrict__ ws) {
    __shared__ unsigned short zhS[8192];                // z[w][64c], swz (w&7)<<4
    __shared__ unsigned short w1hS[8192];               // w1[j][64c], swz (j&7)<<4
    __shared__ unsigned short w2hS[8192];               // w2[o][128j], swz (o&15)<<4
    __shared__ unsigned short hhS[8192];                // h-half [w][64jl], swz (w&7)<<4
    __shared__ unsigned short qhS[2560], qlS[2560];     // QmT[c][40k] hi/lo
    __shared__ float muL[64], rhoL[64], b1L[128], b2L[64];
    int t = threadIdx.x;
    int h = blockIdx.x, b = blockIdx.y;
    int l = t & 63, wv = t >> 6;

    const unsigned short* xu = (const unsigned short*)(ws + OFF_X);
    const unsigned short* w1hG = xu;
    const unsigned short* w2hG = xu + 16384;
    const unsigned short* MhG  = xu + 32768, *MlG  = xu + 36864;

    for (int ch = t; ch < 1024; ch += 256) {       // w1: rows j, stride 128B
        int j = ch >> 3, c0 = (ch & 7) * 8;
        unsigned off = (unsigned)(j*128 + c0*2) ^ (unsigned)((j & 7) << 4);
        *(bfrag*)((char*)w1hS + off) = *(const bfrag*)(w1hG + ch*8);
    }
    for (int ch = t; ch < 1024; ch += 256) {       // w2: rows o, stride 256B
        int o = ch >> 4, j0 = (ch & 15) * 8;
        unsigned off = (unsigned)(o*256 + j0*2) ^ (unsigned)((o & 15) << 4);
        *(bfrag*)((char*)w2hS + off) = *(const bfrag*)(w2hG + ch*8);
    }
    const float* Qp = ws + OFF_PQ + (long)(b*128 + h)*2048;
    for (int i = t; i < 2048; i += 256) {
        int k = i & 31, c = i >> 5;
        float v = Qp[(k >> 1)*128 + c*2 + (k & 1)];
        unsigned short hi, lo; split2(v, hi, lo);
        qhS[c*40 + k] = hi; qlS[c*40 + k] = lo;
    }
    if (t < 64) {
        float s1 = ws[OFF_S2 + (b*64+t)*2], s2 = ws[OFF_S2 + (b*64+t)*2 + 1];
        float m = s1 * (1.f/16384.f);
        float v = s2 * (1.f/16384.f) - m*m;
        muL[t] = m; rhoL[t] = rsqrtf(v + 1e-5f);
        b2L[t] = mb2[t];
    }
    if (t >= 64 && t < 192) b1L[t - 64] = mb1[t - 64];
    bfrag ma_h[2], ma_l[2];
    #pragma unroll
    for (int q = 0; q < 2; q++) {
        int w = (wv + 4*q)*16 + (l & 15);
        ma_h[q] = *(const bfrag*)(MhG + w*32 + (l >> 4)*8);
        ma_l[q] = *(const bfrag*)(MlG + w*32 + (l >> 4)*8);
    }
    __syncthreads();   // cross-wave staging -- the ONLY barrier needed

    #pragma unroll
    for (int q = 0; q < 2; q++) {
        int wt = wv + 4*q;
        #pragma unroll
        for (int ct = 0; ct < 4; ct++) {
            unsigned ro = (unsigned)((ct*16 + (l & 15))*80 + (l >> 4)*16);
            bfrag bh = *(const bfrag*)((const char*)qhS + ro);
            bfrag bl = *(const bfrag*)((const char*)qlS + ro);
            f4v acc = {0.f, 0.f, 0.f, 0.f};
            acc = MFMA(ma_h[q], bh, acc);
            acc = MFMA(ma_h[q], bl, acc);
            acc = MFMA(ma_l[q], bh, acc);
            int c = ct*16 + (l & 15);
            float mu_ = muL[c], rh_ = rhoL[c];
            #pragma unroll
            for (int r = 0; r < 4; r++) {
                int w = wt*16 + (l >> 4)*4 + r;
                float z = (acc[r] - mu_) * rh_;
                unsigned off = (unsigned)(w*128 + c*2) ^ (unsigned)((w & 7) << 4);
                *(unsigned short*)((char*)zhS + off) = f2bf_rn(z);
            }
        }
    }

    bfrag za[2][2];
    #pragma unroll
    for (int q = 0; q < 2; q++) {
        int w = (wv + 4*q)*16 + (l & 15);
        #pragma unroll
        for (int ks = 0; ks < 2; ks++) {
            unsigned off = (unsigned)(w*128 + (ks*32 + (l >> 4)*8)*2) ^ (unsigned)((w & 7) << 4);
            za[q][ks] = *(const bfrag*)((const char*)zhS + off);
        }
    }
    f4v accO[2][4];
    #pragma unroll
    for (int q = 0; q < 2; q++)
        #pragma unroll
        for (int ot = 0; ot < 4; ot++) accO[q][ot] = (f4v){0.f,0.f,0.f,0.f};

    #pragma unroll
    for (int jh = 0; jh < 2; jh++) {
        #pragma unroll
        for (int q = 0; q < 2; q++) {
            int wt = wv + 4*q;
            #pragma unroll
            for (int jt = 0; jt < 4; jt++) {
                int j = jh*64 + jt*16 + (l & 15);
                f4v acc = {0.f, 0.f, 0.f, 0.f};
                #pragma unroll
                for (int ks = 0; ks < 2; ks++) {
                    unsigned off = (unsigned)(j*128 + (ks*32 + (l >> 4)*8)*2) ^ (unsigned)((j & 7) << 4);
                    bfrag bh = *(const bfrag*)((const char*)w1hS + off);
                    acc = MFMA(za[q][ks], bh, acc);
                }
                float bj = b1L[j];
                #pragma unroll
                for (int r = 0; r < 4; r++) {
                    int w = wt*16 + (l >> 4)*4 + r;
                    float hv = gelu_t(acc[r] + bj);
                    int jl = jt*16 + (l & 15);
                    unsigned off = (unsigned)(w*128 + jl*2) ^ (unsigned)((w & 7) << 4);
                    *(unsigned short*)((char*)hhS + off) = f2bf_rn(hv);
                }
            }
        }
        #pragma unroll
        for (int q = 0; q < 2; q++) {
            int w = (wv + 4*q)*16 + (l & 15);
            bfrag ha[2];
            #pragma unroll
            for (int ks = 0; ks < 2; ks++) {
                unsigned off = (unsigned)(w*128 + (ks*32 + (l >> 4)*8)*2) ^ (unsigned)((w & 7) << 4);
                ha[ks] = *(const bfrag*)((const char*)hhS + off);
            }
            #pragma unroll
            for (int ot = 0; ot < 4; ot++) {
                int o = ot*16 + (l & 15);
                f4v acc = accO[q][ot];
                #pragma unroll
                for (int ks = 0; ks < 2; ks++) {
                    int jj = jh*64 + ks*32 + (l >> 4)*8;
                    unsigned off = (unsigned)(o*256 + jj*2) ^ (unsigned)((o & 15) << 4);
                    bfrag bh = *(const bfrag*)((const char*)w2hS + off);
                    acc = MFMA(ha[ks], bh, acc);
                }
                accO[q][ot] = acc;
            }
        }
    }
    #pragma unroll
    for (int q = 0; q < 2; q++) {
        int wt = wv + 4*q;
        #pragma unroll
        for (int ot = 0; ot < 4; ot++) {
            int o = ot*16 + (l & 15);
            float bo = b2L[o];
            #pragma unroll
            for (int r = 0; r < 4; r++) {
                int w = wt*16 + (l >> 4)*4 + r;
                out[((long)(b*128 + h)*128 + w)*64 + o] = accO[q][ot][r] + bo;
            }
        }
    }
}

extern "C" void kernel_launch(void* const* d_in, const int* in_sizes, int n_in,
                              void* d_out, int out_size, void* d_ws, size_t ws_size,
                              hipStream_t stream) {
    const float* x   = (const float*)d_in[0];
    const float* w1r = (const float*)d_in[1];
    const float* w1i = (const float*)d_in[2];
    const float* w2r = (const float*)d_in[3];
    const float* w2i = (const float*)d_in[4];
    const float* mw1 = (const float*)d_in[5];
    const float* mb1 = (const float*)d_in[6];
    const float* mw2 = (const float*)d_in[7];
    const float* mb2 = (const float*)d_in[8];
    float* ws  = (float*)d_ws;
    float* out = (float*)d_out;

    k_init  <<<dim3(49),      dim3(256), 0, stream>>>(ws);
    k_trans <<<dim3(64,2),    dim3(256), 0, stream>>>(w1r, w1i, w2r, w2i, ws);
    // --- diagnostic ablation variants (side-effect-free; V3's PT garbage is
    //     fully overwritten by the real MODE-0 launch below) ---
    k_dftw_t<1><<<dim3(32,2,16), dim3(256), 0, stream>>>(x, ws);  // loads+stats only
    k_dftw_t<2><<<dim3(32,2,16), dim3(256), 0, stream>>>(x, ws);  // +stage, MFMA-light
    k_dftw_t<3><<<dim3(32,2,16), dim3(256), 0, stream>>>(x, ws);  // no loads, full compute
    k_dftw_t<0><<<dim3(32,2,16), dim3(256), 0, stream>>>(x, ws);  // REAL
    k_dfth  <<<dim3(16,16),   dim3(256), 0, stream>>>(ws);
    k_mix   <<<dim3(512),     dim3(256), 0, stream>>>(ws);
    k_wmlp  <<<dim3(80),      dim3(256), 0, stream>>>(mw1, mw2, ws);  // X dead after k_mix
    k_pstats<<<dim3(16,4),    dim3(256), 0, stream>>>(ws);
    k_idfth <<<dim3(16,16),   dim3(256), 0, stream>>>(ws);
    k_mlp   <<<dim3(128,16),  dim3(256), 0, stream>>>(mb1, mb2, out, ws);
}

// Round 13
// 217.965 us; speedup vs baseline: 1.1785x; 1.1785x over previous
//
#include <hip/hip_runtime.h>
#include <math.h>

// Problem constants: B=16, H=W=128, C=64, M1=M2=16
// Workspace layout (float offsets):
#define OFF_TBL 0u            // 128 x {cos,sin}(2*pi*m/128)          (256)
#define OFF_S1  256u          // instance-norm-1 raw sums [b*64+c][2] (2048)
#define OFF_S2  2304u         // instance-norm-2 stats (s1,s2)        (2048)
#define OFF_PQ  4352u         // PT2[b][hp32][ky16][c64][ri2][h4] u32 bf16 hi|lo (4194304)
                              //   aliased later with Q[b][h][ky][o][2] f32
#define OFF_X   4198656u      // X[b][kx][ky][c][2] f32               (1048576)
#define OFF_O   5247232u      // Out[b][kx][ky][o][2] f32             (1048576)
                              //   head doubles (pre-mix) as u16 trig tables:
                              //   FdAh[32][128] @0, FdAl @4096, EdAh[64][128] @8192, EdAl @16384
#define OFF_WT  6295808u      // WT[mode][i][o][2]                    (4194304)
// total = 10490112 floats = 41.96 MB
// d_out (67.1MB) doubles as scratch: xT[b][h][c][w] u32 (bf16 hi<<16|lo), 16.7M u32.
// xT is produced by k_xt, consumed by k_dftw, and d_out is fully overwritten by k_mlp.
// X region is dead after k_mix -> reuse as u16 arrays for bf16-split MLP weights:
//   u16[0..8192) w1hi   [8192..16384) w1lo   [16384..24576) w2hi
//   [24576..32768) w2lo  [32768..36864) Mhi  [36864..40960) Mlo

typedef __attribute__((ext_vector_type(8))) short bfrag;
typedef __attribute__((ext_vector_type(4))) float f4v;
#define MFMA(A,B,C) __builtin_amdgcn_mfma_f32_16x16x32_bf16(A,B,C,0,0,0)

// compile-time float4 component select -- NO address-taken indexing (scratch hazard)
#define F4GET(v, i) ((i)==0 ? (v).x : (i)==1 ? (v).y : (i)==2 ? (v).z : (v).w)

__device__ __forceinline__ unsigned short f2bf_rn(float x) {
    unsigned u = __float_as_uint(x);
    unsigned r = u + 0x7FFFu + ((u >> 16) & 1u);
    return (unsigned short)(r >> 16);
}
__device__ __forceinline__ float bf2f(unsigned short h) {
    return __uint_as_float(((unsigned)h) << 16);
}
__device__ __forceinline__ void split2(float x, unsigned short& hi, unsigned short& lo) {
    hi = f2bf_rn(x);
    lo = f2bf_rn(x - bf2f(hi));
}
// tanh-form GELU; matches exact GELU to <1e-5 for |x| <= 0.5 (our range)
__device__ __forceinline__ float gelu_t(float x) {
    float u = 0.79788456080286536f * (x + 0.044715f * x * x * x);
    float e = __expf(2.f * u);
    float th = 1.f - 2.f / (e + 1.f);
    return 0.5f * x * (1.f + th);
}

// block 0: twiddle table + zero S1/S2. blocks 1..48: bf16-split trig tables
// (F for dftw, E for dfth) into the O region (dead until k_mix overwrites).
__global__ void k_init(float* __restrict__ ws) {
    int t = threadIdx.x, bid = blockIdx.x;
    if (bid == 0) {
        if (t < 128) {
            double ang = 6.283185307179586476925286766559 * (double)t / 128.0;
            ws[OFF_TBL + 2*t]     = (float)cos(ang);
            ws[OFF_TBL + 2*t + 1] = (float)sin(ang);
        }
        for (int i = t; i < 4096; i += 256) ws[OFF_S1 + i] = 0.f;
        return;
    }
    int e = (bid - 1)*256 + t;   // 0..12287
    unsigned short* OU = (unsigned short*)(ws + OFF_O);
    const double TWO_PI = 6.283185307179586476925286766559;
    if (e < 4096) {              // FdA[row=ri*16+ky][w]: re rows cos, im rows -sin
        int row = e >> 7, w = e & 127, ky = row & 15;
        double ang = TWO_PI * (double)((ky * w) & 127) / 128.0;
        double v = (row < 16) ? cos(ang) : -sin(ang);
        unsigned short hi, lo; split2((float)v, hi, lo);
        OU[e] = hi; OU[4096 + e] = lo;
    } else {                     // EdA[row=2kx+s][h]: s=0 cos, s=1 sin (of freq f(kx))
        int e2 = e - 4096, row = e2 >> 7, h = e2 & 127;
        int kx = row >> 1, f = kx < 16 ? kx : 96 + kx;
        double ang = TWO_PI * (double)((f * h) & 127) / 128.0;
        double v = (row & 1) ? sin(ang) : cos(ang);
        unsigned short hi, lo; split2((float)v, hi, lo);
        OU[8192 + e2] = hi; OU[16384 + e2] = lo;
    }
}

// streaming transpose+convert: x[b][h][w][c] f32 -> xT[b][h][c][w] u32(bf16 hi|lo)
// in d_out scratch, with instance-norm-1 stats folded in. grid (hc=32, b=16).
// Reads and writes fully coalesced; LDS tile [c 64][w 128 pad132] u32 per h.
__global__ __launch_bounds__(256) void k_xt(const float* __restrict__ x,
                                            unsigned* __restrict__ xT,
                                            float* __restrict__ ws) {
    __shared__ unsigned Th[64*132];
    int t = threadIdx.x;
    int hc = blockIdx.x, b = blockIdx.y;
    float s1a[4] = {0,0,0,0}, s2a[4] = {0,0,0,0};
    int c4 = t & 15;
    for (int hh = 0; hh < 4; hh++) {
        int h = hc*4 + hh;
        const float4* row = (const float4*)(x + ((long)(b*128 + h))*8192);
        __syncthreads();                       // protect Th from prev readers
        #pragma unroll
        for (int i = 0; i < 2; i++) {
            int q = i*256 + t;
            int wq = q >> 4;                   // 0..31 (4-w quad)
            float4 v0 = row[(wq*4 + 0)*16 + c4];
            float4 v1 = row[(wq*4 + 1)*16 + c4];
            float4 v2 = row[(wq*4 + 2)*16 + c4];
            float4 v3 = row[(wq*4 + 3)*16 + c4];
            #pragma unroll
            for (int j = 0; j < 4; j++) {
                int c = c4*4 + j;
                float f0 = F4GET(v0, j), f1 = F4GET(v1, j);
                float f2 = F4GET(v2, j), f3 = F4GET(v3, j);
                s1a[j] += f0 + f1 + f2 + f3;
                s2a[j] += f0*f0 + f1*f1 + f2*f2 + f3*f3;
                unsigned short hi, lo;
                uint4 pk;
                split2(f0, hi, lo); pk.x = ((unsigned)hi << 16) | lo;
                split2(f1, hi, lo); pk.y = ((unsigned)hi << 16) | lo;
                split2(f2, hi, lo); pk.z = ((unsigned)hi << 16) | lo;
                split2(f3, hi, lo); pk.w = ((unsigned)hi << 16) | lo;
                *(uint4*)(Th + c*132 + wq*4) = pk;
            }
        }
        __syncthreads();
        unsigned* dst = xT + ((long)(b*128 + h))*8192;   // [c 64][w 128] u32
        #pragma unroll
        for (int i = 0; i < 8; i++) {
            int idx = i*256 + t;
            int c = idx >> 5, wq = idx & 31;
            ((uint4*)dst)[c*32 + wq] = *(const uint4*)(Th + c*132 + wq*4);
        }
    }
    // stats reduce: lanes l and l+16,l+32,l+48 share c4
    #pragma unroll
    for (int j = 0; j < 4; j++) {
        s1a[j] += __shfl_down(s1a[j], 16, 64);
        s1a[j] += __shfl_down(s1a[j], 32, 64);
        s2a[j] += __shfl_down(s2a[j], 16, 64);
        s2a[j] += __shfl_down(s2a[j], 32, 64);
    }
    if ((t & 63) < 16) {
        #pragma unroll
        for (int j = 0; j < 4; j++) {
            int c = c4*4 + j;
            atomicAdd(&ws[OFF_S1 + (b*64 + c)*2],     s1a[j]);
            atomicAdd(&ws[OFF_S1 + (b*64 + c)*2 + 1], s2a[j]);
        }
    }
}

// weight transpose: [i][o][kx][ky] (x4 arrays) -> WT[mode][i][o][{re,im}]. grid (64=i, 2=part)
__global__ void k_trans(const float* __restrict__ w1r, const float* __restrict__ w1i,
                        const float* __restrict__ w2r, const float* __restrict__ w2i,
                        float* __restrict__ ws) {
    __shared__ float Lr[16*257], Li[16*257];
    int t = threadIdx.x;
    int i = blockIdx.x;
    int part = blockIdx.y;
    float* WT = ws + OFF_WT;
    const float* wr = part ? w2r : w1r;
    const float* wi = part ? w2i : w1i;
    for (int oc = 0; oc < 4; oc++) {
        int o0 = oc * 16;
        __syncthreads();
        for (int idx = t; idx < 4096; idx += 256) {
            int oo = idx >> 8, m = idx & 255;
            Lr[oo*257 + m] = wr[(i*64 + o0 + oo)*256 + m];
            Li[oo*257 + m] = wi[(i*64 + o0 + oo)*256 + m];
        }
        __syncthreads();
        for (int idx = t; idx < 8192; idx += 256) {
            int mode = idx >> 5, rem = idx & 31, oo = rem >> 1, ri = rem & 1;
            float val = ri ? Li[oo*257 + mode] : Lr[oo*257 + mode];
            int gm = part*256 + mode;
            WT[((gm*64 + i)*64 + (o0 + oo))*2 + ri] = val;
        }
    }
}

// bf16-split MLP weights + iDFT-w matrix M into the dead X region. grid 80
__global__ void k_wmlp(const float* __restrict__ mw1, const float* __restrict__ mw2,
                       float* __restrict__ ws) {
    int i = blockIdx.x * 256 + threadIdx.x;   // [0, 20480)
    unsigned short* xu = (unsigned short*)(ws + OFF_X);
    if (i < 8192) {
        unsigned short hi, lo; split2(mw1[i], hi, lo);
        xu[i] = hi; xu[8192 + i] = lo;
    } else if (i < 16384) {
        int k = i - 8192;
        unsigned short hi, lo; split2(mw2[k], hi, lo);
        xu[16384 + k] = hi; xu[24576 + k] = lo;
    } else if (i < 20480) {
        int m = i - 16384;           // w*32 + k
        int w = m >> 5, k = m & 31;
        int ky = k >> 1;
        double ang = 6.283185307179586476925286766559 * (double)((ky * w) & 127) / 128.0;
        double v = (k & 1) ? -sin(ang) : cos(ang);
        double a = (ky == 0) ? 1.0 : 2.0;
        float val = (float)(v * a) * (1.f/16384.f);
        unsigned short hi, lo; split2(val, hi, lo);
        xu[32768 + m] = hi; xu[36864 + m] = lo;
    }
}

// MFMA forward DFT along w, dfth-style: big coalesced staging bursts from xT,
// pure MFMA, block-contiguous PT2 output (no scattered writes).
// grid (hp=32, b=16): block = 4 h x 64 c = 256 N-cols, K=128 w (2 chunks of 64),
// M=32 rows (ri*16+ky). Wave wv owns h-local wv (64 cols).
// PT2[b][hp][ky][c][ri][h4] u32(hi|lo): block writes its own 32KB contiguously.
__global__ __launch_bounds__(256) void k_dftw(const unsigned* __restrict__ xT,
                                              float* __restrict__ ws) {
    __shared__ unsigned short BshH[256*68];   // [n 256][k 64 pad68] u16, swz k^8(n&7)
    __shared__ unsigned short BshL[256*68];
    int t = threadIdx.x;
    int hp = blockIdx.x, b = blockIdx.y;
    int l = t & 63, wv = t >> 6;
    const unsigned short* OU = (const unsigned short*)(ws + OFF_O);
    const unsigned short* FdAh = OU, *FdAl = OU + 4096;
    f4v acc[2][4];
    #pragma unroll
    for (int mt = 0; mt < 2; mt++)
        #pragma unroll
        for (int nt = 0; nt < 4; nt++) acc[mt][nt] = (f4v){0.f,0.f,0.f,0.f};

    const uint4* xT4 = (const uint4*)(xT + ((long)(b*128 + hp*4))*8192);  // col n -> +n*32 u4

    for (int kc2 = 0; kc2 < 2; kc2++) {
        __syncthreads();                    // protect Bsh from prev MFMA readers
        #pragma unroll
        for (int i = 0; i < 16; i++) {
            int idx = i*256 + t;
            int n = idx >> 4, s = idx & 15;       // col n, 16B-seg s (4 w)
            uint4 v = xT4[n*32 + kc2*16 + s];
            unsigned h01 = (v.x >> 16) | (v.y & 0xFFFF0000u);
            unsigned h23 = (v.z >> 16) | (v.w & 0xFFFF0000u);
            unsigned l01 = (v.x & 0xFFFFu) | (v.y << 16);
            unsigned l23 = (v.z & 0xFFFFu) | (v.w << 16);
            unsigned ku = (unsigned)((s*4) ^ (8*(n & 7)));
            *(uint2*)(BshH + n*68 + ku) = make_uint2(h01, h23);
            *(uint2*)(BshL + n*68 + ku) = make_uint2(l01, l23);
        }
        __syncthreads();
        #pragma unroll
        for (int kcl = 0; kcl < 2; kcl++) {
            int kglob = kc2*64 + kcl*32 + (l >> 4)*8;
            bfrag mah[2], mal[2];
            #pragma unroll
            for (int mt = 0; mt < 2; mt++) {
                int row = mt*16 + (l & 15);
                mah[mt] = *(const bfrag*)(FdAh + row*128 + kglob);
                mal[mt] = *(const bfrag*)(FdAl + row*128 + kglob);
            }
            #pragma unroll
            for (int nt = 0; nt < 4; nt++) {
                int n = wv*64 + nt*16 + (l & 15);
                int kl = kcl*32 + (l >> 4)*8;
                unsigned ku = (unsigned)(kl ^ (8*(n & 7)));
                bfrag bh = *(const bfrag*)(BshH + n*68 + ku);
                bfrag bl = *(const bfrag*)(BshL + n*68 + ku);
                #pragma unroll
                for (int mt = 0; mt < 2; mt++) {
                    f4v a_ = acc[mt][nt];
                    a_ = MFMA(mah[mt], bh, a_);
                    a_ = MFMA(mah[mt], bl, a_);
                    a_ = MFMA(mal[mt], bh, a_);
                    acc[mt][nt] = a_;
                }
            }
        }
    }
    // ---- epilogue: pack -> TB (alias BshH), then block-contiguous PT2 write ----
    __syncthreads();
    unsigned* TB = (unsigned*)BshH;   // TB[ky][c*2+ri][h4], word stride 520 per ky
    #pragma unroll
    for (int mt = 0; mt < 2; mt++)
        #pragma unroll
        for (int nt = 0; nt < 4; nt++)
            #pragma unroll
            for (int rr = 0; rr < 4; rr++) {
                float v = acc[mt][nt][rr];
                unsigned short hi, lo; split2(v, hi, lo);
                int trow = mt*16 + (l >> 4)*4 + rr;
                int ri = trow >> 4, ky = trow & 15;
                int c = nt*16 + (l & 15);
                TB[ky*520 + (c*2 + ri)*4 + wv] = ((unsigned)hi << 16) | lo;
            }
    __syncthreads();
    unsigned* PTb = (unsigned*)(ws + OFF_PQ) + ((long)(b*32 + hp))*8192;
    #pragma unroll
    for (int i = 0; i < 8; i++) {
        int idx = i*256 + t;
        int ky = idx >> 7, m = idx & 127;
        ((uint4*)PTb)[idx] = *(const uint4*)(TB + ky*520 + m*4);
    }
}

// MFMA forward DFT along h: X[2kx+s][(c,ri)] = EdA @ PT2 (per ky,b).
// Staging reads 2KB contiguous runs per (hp,ky). grid (ky=16, b=16).
__global__ __launch_bounds__(256) void k_dfth(float* __restrict__ ws) {
    __shared__ unsigned Bsh[16384];   // BTh 32KB (128 cols x 256B) | BTl 32KB
    int t = threadIdx.x;
    int ky = blockIdx.x, b = blockIdx.y;
    int l = t & 63, wv = t >> 6;
    char* bh_base = (char*)Bsh;
    char* bl_base = bh_base + 32768;
    const uint4* PT4 = (const uint4*)((const unsigned*)(ws + OFF_PQ));
    const unsigned short* OU = (const unsigned short*)(ws + OFF_O);
    const unsigned short* EdAh = OU + 8192, *EdAl = OU + 16384;

    // ---- stage PT2: for (hp, n=(c,ri)) read uint4 (4 h), unpack -> BT[n][128 kk] ----
    #pragma unroll
    for (int i = 0; i < 16; i++) {
        int idx = i*256 + t;
        int hp = idx >> 7, n = idx & 127;
        uint4 v = PT4[((long)(b*32 + hp)*16 + ky)*128 + n];
        unsigned h01 = (v.x >> 16) | (v.y & 0xFFFF0000u);
        unsigned h23 = (v.z >> 16) | (v.w & 0xFFFF0000u);
        unsigned l01 = (v.x & 0xFFFFu) | (v.y << 16);
        unsigned l23 = (v.z & 0xFFFFu) | (v.w << 16);
        int kk = hp*4;
        unsigned ad = (unsigned)(n*256 + ((kk*2) ^ ((n & 7) << 4)));
        *(uint2*)(bh_base + ad) = make_uint2(h01, h23);
        *(uint2*)(bl_base + ad) = make_uint2(l01, l23);
    }
    // A-frags for this wave's Mtile
    bfrag ea_h[4], ea_l[4];
    #pragma unroll
    for (int kc = 0; kc < 4; kc++) {
        int off = (wv*16 + (l & 15))*128 + kc*32 + (l >> 4)*8;
        ea_h[kc] = *(const bfrag*)(EdAh + off);
        ea_l[kc] = *(const bfrag*)(EdAl + off);
    }
    __syncthreads();
    f4v acc[8];
    #pragma unroll
    for (int nt = 0; nt < 8; nt++) acc[nt] = (f4v){0.f,0.f,0.f,0.f};
    #pragma unroll
    for (int kc = 0; kc < 4; kc++)
        #pragma unroll
        for (int nt = 0; nt < 8; nt++) {
            int col = nt*16 + (l & 15);
            unsigned ro = (unsigned)(col*256 + ((kc*64 + (l >> 4)*16) ^ ((col & 7) << 4)));
            bfrag bh = *(const bfrag*)(bh_base + ro);
            bfrag bl = *(const bfrag*)(bl_base + ro);
            acc[nt] = MFMA(ea_h[kc], bh, acc[nt]);
            acc[nt] = MFMA(ea_h[kc], bl, acc[nt]);
            acc[nt] = MFMA(ea_l[kc], bh, acc[nt]);
        }
    // ---- epilogue: complex combine + store X (f32, legacy layout) ----
    float* X = ws + OFF_X;
    #pragma unroll
    for (int nt = 0; nt < 8; nt++)
        #pragma unroll
        for (int p = 0; p < 2; p++) {
            float s0 = acc[nt][2*p], s1 = acc[nt][2*p + 1];
            float partner = __shfl_xor(s1, 1, 64);
            float res = (l & 1) ? (s0 - partner) : (s0 + partner);
            int kx = wv*8 + (l >> 4)*2 + p;
            X[(((long)b*32 + kx)*16 + ky)*128 + nt*16 + (l & 15)] = res;
        }
}

// per-mode complex mix with rho1 scaling folded into X staging. grid 512 (=mode)
__global__ void k_mix(float* __restrict__ ws) {
    __shared__ float Wsh[8192];
    __shared__ float Xs[2048];
    __shared__ float rhoT[1024];
    int t = threadIdx.x;
    int mode = blockIdx.x;
    int kxI = mode >> 4, ky = mode & 15;
    const float* WT = ws + OFF_WT;
    const float* X = ws + OFF_X;
    float* O = ws + OFF_O;
    for (int i = t; i < 1024; i += 256) {
        float a = ws[OFF_S1 + 2*i], s = ws[OFF_S1 + 2*i + 1];
        float m = a * (1.f/16384.f);
        float v = s * (1.f/16384.f) - m*m;
        rhoT[i] = rsqrtf(v + 1e-5f);
    }
    for (int idx = t; idx < 8192; idx += 256) Wsh[idx] = WT[(long)mode*8192 + idx];
    __syncthreads();
    for (int idx = t; idx < 2048; idx += 256) {
        int b = idx >> 7, r = idx & 127;
        Xs[idx] = X[((b*32 + kxI)*16 + ky)*128 + r] * rhoT[b*64 + (r >> 1)];
    }
    __syncthreads();
    int o = t & 63, bg = t >> 6;
    float accr[4] = {0,0,0,0}, acci[4] = {0,0,0,0};
    for (int i = 0; i < 64; i++) {
        float wr = Wsh[(i*64 + o)*2], wi = Wsh[(i*64 + o)*2 + 1];
        #pragma unroll
        for (int j = 0; j < 4; j++) {
            float xr = Xs[(bg*4 + j)*128 + 2*i], xi = Xs[(bg*4 + j)*128 + 2*i + 1];
            accr[j] += xr*wr - xi*wi;
            acci[j] += xr*wi + xi*wr;
        }
    }
    #pragma unroll
    for (int j = 0; j < 4; j++) {
        int b = bg*4 + j;
        float2* dst = (float2*)(O + ((b*32 + kxI)*16 + ky)*128);
        dst[o] = make_float2(accr[j], acci[j]);
    }
}

// Parseval stats of y directly from O. grid (16=b, 4=gg), 256 thr.
__global__ void k_pstats(float* __restrict__ ws) {
    __shared__ float red[256];
    int t = threadIdx.x, b = blockIdx.x, gg = blockIdx.y;
    int c = t & 63, g = t >> 6;
    const float* O = ws + OFF_O + (long)b*65536;   // [(kxI*16+ky)*128 + 2c]
    float t0 = 0.f, t2 = 0.f;
    int k0 = gg*8 + g*2;
    for (int kxI = k0; kxI < k0 + 2; kxI++)
        for (int ky = 0; ky < 16; ky++) {
            float re = O[(kxI*16 + ky)*128 + 2*c];
            float im = O[(kxI*16 + ky)*128 + 2*c + 1];
            float p = re*re + im*im;
            if (ky == 0) t0 += p; else t2 += p;
        }
    float s2p = 0.5f*t0 + 2.f*t2;
    if (gg == 0 && g == 0) {
        float ar = O[2*c], ai = O[2*c + 1];        // kxI=0, ky=0
        float t1 = ar*ar - ai*ai;
        for (int k = 1; k <= 15; k++) {
            float xr = O[(k*16)*128 + 2*c],        xi = O[(k*16)*128 + 2*c + 1];
            float yr = O[((32-k)*16)*128 + 2*c],   yi = O[((32-k)*16)*128 + 2*c + 1];
            t1 += 2.f*(xr*yr - xi*yi);
        }
        s2p += 0.5f*t1;
        ws[OFF_S2 + (b*64 + c)*2] = ar;            // s1 (mean term)
    }
    red[t] = s2p;
    __syncthreads();
    if (t < 64) {
        float s = red[t] + red[t+64] + red[t+128] + red[t+192];
        atomicAdd(&ws[OFF_S2 + (b*64 + t)*2 + 1], s * (1.f/16384.f));
    }
}

// inverse DFT along h: Q[b][h][ky][o] = sum_kx Out e^{+i 2pi f(kx) h/128}. grid (hg=16,b=16)
__global__ void k_idfth(float* __restrict__ ws) {
    __shared__ float Os[8192];
    __shared__ float tblL[256];
    int t = threadIdx.x;
    int hg = blockIdx.x, b = blockIdx.y;
    for (int i = t; i < 256; i += 256) tblL[i] = ws[OFF_TBL + i];
    const float* O = ws + OFF_O;
    float* Q = ws + OFF_PQ;
    int o = t & 63, kyg = t >> 6;
    float accr[4][8], acci[4][8];
    #pragma unroll
    for (int kk = 0; kk < 4; kk++)
        #pragma unroll
        for (int h = 0; h < 8; h++) { accr[kk][h] = 0.f; acci[kk][h] = 0.f; }
    for (int kc = 0; kc < 8; kc++) {
        __syncthreads();
        for (int idx = t; idx < 8192; idx += 256) Os[idx] = O[(long)b*65536 + kc*8192 + idx];
        __syncthreads();
        for (int k4 = 0; k4 < 4; k4++) {
            int kxI = kc*4 + k4;
            int freq = kxI < 16 ? kxI : 96 + kxI;
            float vr[4], vi[4];
            #pragma unroll
            for (int kk = 0; kk < 4; kk++) {
                int ky = kyg*4 + kk;
                vr[kk] = Os[((k4*16 + ky)*64 + o)*2];
                vi[kk] = Os[((k4*16 + ky)*64 + o)*2 + 1];
            }
            for (int h = 0; h < 8; h++) {
                int habs = hg*8 + h;
                int m = (freq * habs) & 127;
                float cs = tblL[2*m], sn = tblL[2*m + 1];
                #pragma unroll
                for (int kk = 0; kk < 4; kk++) {
                    accr[kk][h] += vr[kk]*cs - vi[kk]*sn;   // * e^{+i th}
                    acci[kk][h] += vr[kk]*sn + vi[kk]*cs;
                }
            }
        }
    }
    #pragma unroll
    for (int kk = 0; kk < 4; kk++)
        #pragma unroll
        for (int h = 0; h < 8; h++) {
            int ky = kyg*4 + kk, habs = hg*8 + h;
            float2* dst = (float2*)(Q + ((long)(b*128 + habs)*16 + ky)*128);
            dst[o] = make_float2(accr[kk][h], acci[kk][h]);
        }
}

// fused MFMA kernel: Y = M@Qm (iDFT-w), z = (Y-mu)*rho, h = GELU(z@W1+b1),
// out = h@W2+b2. zhS/hhS rows are wave-private -> single staging barrier.
// grid (h=128,b=16). Overwrites ALL of d_out (reclaiming the xT scratch).
__global__ __launch_bounds__(256, 2) void k_mlp(const float* __restrict__ mb1,
                      const float* __restrict__ mb2,
                      float* __restrict__ out, const float* __restrict__ ws) {
    __shared__ unsigned short zhS[8192];                // z[w][64c], swz (w&7)<<4
    __shared__ unsigned short w1hS[8192];               // w1[j][64c], swz (j&7)<<4
    __shared__ unsigned short w2hS[8192];               // w2[o][128j], swz (o&15)<<4
    __shared__ unsigned short hhS[8192];                // h-half [w][64jl], swz (w&7)<<4
    __shared__ unsigned short qhS[2560], qlS[2560];     // QmT[c][40k] hi/lo
    __shared__ float muL[64], rhoL[64], b1L[128], b2L[64];
    int t = threadIdx.x;
    int h = blockIdx.x, b = blockIdx.y;
    int l = t & 63, wv = t >> 6;

    const unsigned short* xu = (const unsigned short*)(ws + OFF_X);
    const unsigned short* w1hG = xu;
    const unsigned short* w2hG = xu + 16384;
    const unsigned short* MhG  = xu + 32768, *MlG  = xu + 36864;

    for (int ch = t; ch < 1024; ch += 256) {       // w1: rows j, stride 128B
        int j = ch >> 3, c0 = (ch & 7) * 8;
        unsigned off = (unsigned)(j*128 + c0*2) ^ (unsigned)((j & 7) << 4);
        *(bfrag*)((char*)w1hS + off) = *(const bfrag*)(w1hG + ch*8);
    }
    for (int ch = t; ch < 1024; ch += 256) {       // w2: rows o, stride 256B
        int o = ch >> 4, j0 = (ch & 15) * 8;
        unsigned off = (unsigned)(o*256 + j0*2) ^ (unsigned)((o & 15) << 4);
        *(bfrag*)((char*)w2hS + off) = *(const bfrag*)(w2hG + ch*8);
    }
    const float* Qp = ws + OFF_PQ + (long)(b*128 + h)*2048;
    for (int i = t; i < 2048; i += 256) {
        int k = i & 31, c = i >> 5;
        float v = Qp[(k >> 1)*128 + c*2 + (k & 1)];
        unsigned short hi, lo; split2(v, hi, lo);
        qhS[c*40 + k] = hi; qlS[c*40 + k] = lo;
    }
    if (t < 64) {
        float s1 = ws[OFF_S2 + (b*64+t)*2], s2 = ws[OFF_S2 + (b*64+t)*2 + 1];
        float m = s1 * (1.f/16384.f);
        float v = s2 * (1.f/16384.f) - m*m;
        muL[t] = m; rhoL[t] = rsqrtf(v + 1e-5f);
        b2L[t] = mb2[t];
    }
    if (t >= 64 && t < 192) b1L[t - 64] = mb1[t - 64];
    bfrag ma_h[2], ma_l[2];
    #pragma unroll
    for (int q = 0; q < 2; q++) {
        int w = (wv + 4*q)*16 + (l & 15);
        ma_h[q] = *(const bfrag*)(MhG + w*32 + (l >> 4)*8);
        ma_l[q] = *(const bfrag*)(MlG + w*32 + (l >> 4)*8);
    }
    __syncthreads();   // cross-wave staging -- the ONLY barrier needed

    #pragma unroll
    for (int q = 0; q < 2; q++) {
        int wt = wv + 4*q;
        #pragma unroll
        for (int ct = 0; ct < 4; ct++) {
            unsigned ro = (unsigned)((ct*16 + (l & 15))*80 + (l >> 4)*16);
            bfrag bh = *(const bfrag*)((const char*)qhS + ro);
            bfrag bl = *(const bfrag*)((const char*)qlS + ro);
            f4v acc = {0.f, 0.f, 0.f, 0.f};
            acc = MFMA(ma_h[q], bh, acc);
            acc = MFMA(ma_h[q], bl, acc);
            acc = MFMA(ma_l[q], bh, acc);
            int c = ct*16 + (l & 15);
            float mu_ = muL[c], rh_ = rhoL[c];
            #pragma unroll
            for (int r = 0; r < 4; r++) {
                int w = wt*16 + (l >> 4)*4 + r;
                float z = (acc[r] - mu_) * rh_;
                unsigned off = (unsigned)(w*128 + c*2) ^ (unsigned)((w & 7) << 4);
                *(unsigned short*)((char*)zhS + off) = f2bf_rn(z);
            }
        }
    }

    bfrag za[2][2];
    #pragma unroll
    for (int q = 0; q < 2; q++) {
        int w = (wv + 4*q)*16 + (l & 15);
        #pragma unroll
        for (int ks = 0; ks < 2; ks++) {
            unsigned off = (unsigned)(w*128 + (ks*32 + (l >> 4)*8)*2) ^ (unsigned)((w & 7) << 4);
            za[q][ks] = *(const bfrag*)((const char*)zhS + off);
        }
    }
    f4v accO[2][4];
    #pragma unroll
    for (int q = 0; q < 2; q++)
        #pragma unroll
        for (int ot = 0; ot < 4; ot++) accO[q][ot] = (f4v){0.f,0.f,0.f,0.f};

    #pragma unroll
    for (int jh = 0; jh < 2; jh++) {
        #pragma unroll
        for (int q = 0; q < 2; q++) {
            int wt = wv + 4*q;
            #pragma unroll
            for (int jt = 0; jt < 4; jt++) {
                int j = jh*64 + jt*16 + (l & 15);
                f4v acc = {0.f, 0.f, 0.f, 0.f};
                #pragma unroll
                for (int ks = 0; ks < 2; ks++) {
                    unsigned off = (unsigned)(j*128 + (ks*32 + (l >> 4)*8)*2) ^ (unsigned)((j & 7) << 4);
                    bfrag bh = *(const bfrag*)((const char*)w1hS + off);
                    acc = MFMA(za[q][ks], bh, acc);
                }
                float bj = b1L[j];
                #pragma unroll
                for (int r = 0; r < 4; r++) {
                    int w = wt*16 + (l >> 4)*4 + r;
                    float hv = gelu_t(acc[r] + bj);
                    int jl = jt*16 + (l & 15);
                    unsigned off = (unsigned)(w*128 + jl*2) ^ (unsigned)((w & 7) << 4);
                    *(unsigned short*)((char*)hhS + off) = f2bf_rn(hv);
                }
            }
        }
        #pragma unroll
        for (int q = 0; q < 2; q++) {
            int w = (wv + 4*q)*16 + (l & 15);
            bfrag ha[2];
            #pragma unroll
            for (int ks = 0; ks < 2; ks++) {
                unsigned off = (unsigned)(w*128 + (ks*32 + (l >> 4)*8)*2) ^ (unsigned)((w & 7) << 4);
                ha[ks] = *(const bfrag*)((const char*)hhS + off);
            }
            #pragma unroll
            for (int ot = 0; ot < 4; ot++) {
                int o = ot*16 + (l & 15);
                f4v acc = accO[q][ot];
                #pragma unroll
                for (int ks = 0; ks < 2; ks++) {
                    int jj = jh*64 + ks*32 + (l >> 4)*8;
                    unsigned off = (unsigned)(o*256 + jj*2) ^ (unsigned)((o & 15) << 4);
                    bfrag bh = *(const bfrag*)((const char*)w2hS + off);
                    acc = MFMA(ha[ks], bh, acc);
                }
                accO[q][ot] = acc;
            }
        }
    }
    #pragma unroll
    for (int q = 0; q < 2; q++) {
        int wt = wv + 4*q;
        #pragma unroll
        for (int ot = 0; ot < 4; ot++) {
            int o = ot*16 + (l & 15);
            float bo = b2L[o];
            #pragma unroll
            for (int r = 0; r < 4; r++) {
                int w = wt*16 + (l >> 4)*4 + r;
                out[((long)(b*128 + h)*128 + w)*64 + o] = accO[q][ot][r] + bo;
            }
        }
    }
}

extern "C" void kernel_launch(void* const* d_in, const int* in_sizes, int n_in,
                              void* d_out, int out_size, void* d_ws, size_t ws_size,
                              hipStream_t stream) {
    const float* x   = (const float*)d_in[0];
    const float* w1r = (const float*)d_in[1];
    const float* w1i = (const float*)d_in[2];
    const float* w2r = (const float*)d_in[3];
    const float* w2i = (const float*)d_in[4];
    const float* mw1 = (const float*)d_in[5];
    const float* mb1 = (const float*)d_in[6];
    const float* mw2 = (const float*)d_in[7];
    const float* mb2 = (const float*)d_in[8];
    float* ws  = (float*)d_ws;
    float* out = (float*)d_out;
    unsigned* xT = (unsigned*)d_out;   // 16.7M u32 scratch; fully overwritten by k_mlp

    k_init  <<<dim3(49),      dim3(256), 0, stream>>>(ws);
    k_xt    <<<dim3(32,16),   dim3(256), 0, stream>>>(x, xT, ws);   // transpose + stats
    k_trans <<<dim3(64,2),    dim3(256), 0, stream>>>(w1r, w1i, w2r, w2i, ws);
    k_dftw  <<<dim3(32,16),   dim3(256), 0, stream>>>(xT, ws);
    k_dfth  <<<dim3(16,16),   dim3(256), 0, stream>>>(ws);
    k_mix   <<<dim3(512),     dim3(256), 0, stream>>>(ws);
    k_wmlp  <<<dim3(80),      dim3(256), 0, stream>>>(mw1, mw2, ws);  // X dead after k_mix
    k_pstats<<<dim3(16,4),    dim3(256), 0, stream>>>(ws);
    k_idfth <<<dim3(16,16),   dim3(256), 0, stream>>>(ws);
    k_mlp   <<<dim3(128,16),  dim3(256), 0, stream>>>(mb1, mb2, out, ws);
}

// Round 14
// 216.958 us; speedup vs baseline: 1.1840x; 1.0046x over previous
//
#include <hip/hip_runtime.h>
#include <math.h>

// Problem constants: B=16, H=W=128, C=64, M1=M2=16
// Workspace layout (float offsets):
#define OFF_TBL 0u            // 128 x {cos,sin}(2*pi*m/128)          (256)
#define OFF_S1  256u          // instance-norm-1 raw sums [b*64+c][2] (2048)
#define OFF_S2  2304u         // instance-norm-2 stats (s1,s2)        (2048)
#define OFF_PQ  4352u         // PT2[b][hp32][ky16][c64][ri2][h4] u32 bf16 hi|lo (4194304)
                              //   aliased later with Q[b][h][ky][o][2] f32
#define OFF_X   4198656u      // X[b][kx][ky][c][2] f32               (1048576)
#define OFF_O   5247232u      // Out[b][kx][ky][o][2] f32             (1048576)
                              //   head doubles (pre-mix) as u16 trig tables:
                              //   FdAh[32][128] @0, FdAl @4096, EdAh[64][128] @8192, EdAl @16384
#define OFF_WT  6295808u      // WT[mode][i][o][2]                    (4194304)
// total = 10490112 floats = 41.96 MB
// d_out (67.1MB) doubles as scratch: xT[b][h][c][w] u32 (bf16 hi<<16|lo), 16.7M u32.
// xT is produced by k_xt, consumed by k_dftw, and d_out is fully overwritten by k_mlp.
// X region is dead after k_mix -> reuse as u16 arrays for bf16-split MLP weights:
//   u16[0..8192) w1hi   [8192..16384) w1lo   [16384..24576) w2hi
//   [24576..32768) w2lo  [32768..36864) Mhi  [36864..40960) Mlo

typedef __attribute__((ext_vector_type(8))) short bfrag;
typedef __attribute__((ext_vector_type(4))) float f4v;
#define MFMA(A,B,C) __builtin_amdgcn_mfma_f32_16x16x32_bf16(A,B,C,0,0,0)

// compile-time float4 component select -- NO address-taken indexing (scratch hazard)
#define F4GET(v, i) ((i)==0 ? (v).x : (i)==1 ? (v).y : (i)==2 ? (v).z : (v).w)

__device__ __forceinline__ unsigned short f2bf_rn(float x) {
    unsigned u = __float_as_uint(x);
    unsigned r = u + 0x7FFFu + ((u >> 16) & 1u);
    return (unsigned short)(r >> 16);
}
__device__ __forceinline__ float bf2f(unsigned short h) {
    return __uint_as_float(((unsigned)h) << 16);
}
__device__ __forceinline__ void split2(float x, unsigned short& hi, unsigned short& lo) {
    hi = f2bf_rn(x);
    lo = f2bf_rn(x - bf2f(hi));
}
// tanh-form GELU; matches exact GELU to <1e-5 for |x| <= 0.5 (our range)
__device__ __forceinline__ float gelu_t(float x) {
    float u = 0.79788456080286536f * (x + 0.044715f * x * x * x);
    float e = __expf(2.f * u);
    float th = 1.f - 2.f / (e + 1.f);
    return 0.5f * x * (1.f + th);
}

// block 0: twiddle table + zero S1/S2. blocks 1..48: bf16-split trig tables
// (F for dftw, E for dfth) into the O region (dead until k_mix overwrites).
__global__ void k_init(float* __restrict__ ws) {
    int t = threadIdx.x, bid = blockIdx.x;
    if (bid == 0) {
        if (t < 128) {
            double ang = 6.283185307179586476925286766559 * (double)t / 128.0;
            ws[OFF_TBL + 2*t]     = (float)cos(ang);
            ws[OFF_TBL + 2*t + 1] = (float)sin(ang);
        }
        for (int i = t; i < 4096; i += 256) ws[OFF_S1 + i] = 0.f;
        return;
    }
    int e = (bid - 1)*256 + t;   // 0..12287
    unsigned short* OU = (unsigned short*)(ws + OFF_O);
    const double TWO_PI = 6.283185307179586476925286766559;
    if (e < 4096) {              // FdA[row=ri*16+ky][w]: re rows cos, im rows -sin
        int row = e >> 7, w = e & 127, ky = row & 15;
        double ang = TWO_PI * (double)((ky * w) & 127) / 128.0;
        double v = (row < 16) ? cos(ang) : -sin(ang);
        unsigned short hi, lo; split2((float)v, hi, lo);
        OU[e] = hi; OU[4096 + e] = lo;
    } else {                     // EdA[row=2kx+s][h]: s=0 cos, s=1 sin (of freq f(kx))
        int e2 = e - 4096, row = e2 >> 7, h = e2 & 127;
        int kx = row >> 1, f = kx < 16 ? kx : 96 + kx;
        double ang = TWO_PI * (double)((f * h) & 127) / 128.0;
        double v = (row & 1) ? sin(ang) : cos(ang);
        unsigned short hi, lo; split2((float)v, hi, lo);
        OU[8192 + e2] = hi; OU[16384 + e2] = lo;
    }
}

// streaming transpose+convert, BARRIER-FREE wave-private version:
// x[b][h][w][c] f32 -> xT[b][h][c][w] u32(bf16 hi|lo), stats folded in.
// grid (hb=64, b=16), 128 thr = 2 waves; wave wv owns h = hb*2+wv and its own
// 9.2KB LDS tile [c64][w32 pad36]. No __syncthreads -> no vmcnt(0) drains;
// loads 2-chunk software-pipelined (named rA/rB, compile-time indexed).
__global__ __launch_bounds__(128, 4) void k_xt(const float* __restrict__ x,
                                               unsigned* __restrict__ xT,
                                               float* __restrict__ ws) {
    __shared__ unsigned T2[2][64*36];
    int t = threadIdx.x;
    int l = t & 63, wv = t >> 6;
    int hb = blockIdx.x, b = blockIdx.y;
    int h = hb*2 + wv;
    unsigned* tile = T2[wv];
    int c4 = l & 15, wgrp = l >> 4;     // wgrp 0..3
    const float4* row = (const float4*)(x + ((long)(b*128 + h))*8192);
    unsigned* dstH = xT + ((long)(b*128 + h))*8192;
    float s1a[4] = {0,0,0,0}, s2a[4] = {0,0,0,0};

    float4 rA[8], rB[8];
    #define XT_LOAD(R, CH)                                              \
        _Pragma("unroll")                                               \
        for (int j = 0; j < 8; j++)                                     \
            R[j] = row[((CH)*32 + wgrp*8 + j)*16 + c4];
    #define XT_PROC(R, CH) {                                            \
        int w0 = (CH)*32;                                               \
        _Pragma("unroll")                                               \
        for (int cc = 0; cc < 4; cc++) {                                \
            int c = c4*4 + cc;                                          \
            _Pragma("unroll")                                           \
            for (int q = 0; q < 2; q++) {                               \
                float f0 = F4GET(R[q*4+0], cc), f1 = F4GET(R[q*4+1], cc); \
                float f2 = F4GET(R[q*4+2], cc), f3 = F4GET(R[q*4+3], cc); \
                s1a[cc] += f0 + f1 + f2 + f3;                           \
                s2a[cc] += f0*f0 + f1*f1 + f2*f2 + f3*f3;               \
                unsigned short hi_, lo_; uint4 pk;                      \
                split2(f0, hi_, lo_); pk.x = ((unsigned)hi_ << 16) | lo_; \
                split2(f1, hi_, lo_); pk.y = ((unsigned)hi_ << 16) | lo_; \
                split2(f2, hi_, lo_); pk.z = ((unsigned)hi_ << 16) | lo_; \
                split2(f3, hi_, lo_); pk.w = ((unsigned)hi_ << 16) | lo_; \
                *(uint4*)(tile + c*36 + wgrp*8 + q*4) = pk;             \
            }                                                           \
        }                                                               \
        _Pragma("unroll")                                               \
        for (int p = 0; p < 8; p++) {                                   \
            int c = p*8 + (l >> 3), wq = l & 7;                         \
            uint4 v = *(const uint4*)(tile + c*36 + wq*4);              \
            *(uint4*)(dstH + c*128 + w0 + wq*4) = v;                    \
        }                                                               \
    }

    XT_LOAD(rA, 0);
    XT_LOAD(rB, 1);
    XT_PROC(rA, 0);
    XT_LOAD(rA, 2);
    XT_PROC(rB, 1);
    XT_LOAD(rB, 3);
    XT_PROC(rA, 2);
    XT_PROC(rB, 3);
    #undef XT_LOAD
    #undef XT_PROC

    // stats reduce over wgrp (lanes l, l+16, l+32, l+48 share c4)
    #pragma unroll
    for (int j = 0; j < 4; j++) {
        s1a[j] += __shfl_down(s1a[j], 16, 64);
        s1a[j] += __shfl_down(s1a[j], 32, 64);
        s2a[j] += __shfl_down(s2a[j], 16, 64);
        s2a[j] += __shfl_down(s2a[j], 32, 64);
    }
    if (l < 16) {
        #pragma unroll
        for (int j = 0; j < 4; j++) {
            int c = c4*4 + j;
            atomicAdd(&ws[OFF_S1 + (b*64 + c)*2],     s1a[j]);
            atomicAdd(&ws[OFF_S1 + (b*64 + c)*2 + 1], s2a[j]);
        }
    }
}

// weight transpose: [i][o][kx][ky] (x4 arrays) -> WT[mode][i][o][{re,im}]. grid (64=i, 2=part)
__global__ void k_trans(const float* __restrict__ w1r, const float* __restrict__ w1i,
                        const float* __restrict__ w2r, const float* __restrict__ w2i,
                        float* __restrict__ ws) {
    __shared__ float Lr[16*257], Li[16*257];
    int t = threadIdx.x;
    int i = blockIdx.x;
    int part = blockIdx.y;
    float* WT = ws + OFF_WT;
    const float* wr = part ? w2r : w1r;
    const float* wi = part ? w2i : w1i;
    for (int oc = 0; oc < 4; oc++) {
        int o0 = oc * 16;
        __syncthreads();
        for (int idx = t; idx < 4096; idx += 256) {
            int oo = idx >> 8, m = idx & 255;
            Lr[oo*257 + m] = wr[(i*64 + o0 + oo)*256 + m];
            Li[oo*257 + m] = wi[(i*64 + o0 + oo)*256 + m];
        }
        __syncthreads();
        for (int idx = t; idx < 8192; idx += 256) {
            int mode = idx >> 5, rem = idx & 31, oo = rem >> 1, ri = rem & 1;
            float val = ri ? Li[oo*257 + mode] : Lr[oo*257 + mode];
            int gm = part*256 + mode;
            WT[((gm*64 + i)*64 + (o0 + oo))*2 + ri] = val;
        }
    }
}

// bf16-split MLP weights + iDFT-w matrix M into the dead X region. grid 80
__global__ void k_wmlp(const float* __restrict__ mw1, const float* __restrict__ mw2,
                       float* __restrict__ ws) {
    int i = blockIdx.x * 256 + threadIdx.x;   // [0, 20480)
    unsigned short* xu = (unsigned short*)(ws + OFF_X);
    if (i < 8192) {
        unsigned short hi, lo; split2(mw1[i], hi, lo);
        xu[i] = hi; xu[8192 + i] = lo;
    } else if (i < 16384) {
        int k = i - 8192;
        unsigned short hi, lo; split2(mw2[k], hi, lo);
        xu[16384 + k] = hi; xu[24576 + k] = lo;
    } else if (i < 20480) {
        int m = i - 16384;           // w*32 + k
        int w = m >> 5, k = m & 31;
        int ky = k >> 1;
        double ang = 6.283185307179586476925286766559 * (double)((ky * w) & 127) / 128.0;
        double v = (k & 1) ? -sin(ang) : cos(ang);
        double a = (ky == 0) ? 1.0 : 2.0;
        float val = (float)(v * a) * (1.f/16384.f);
        unsigned short hi, lo; split2(val, hi, lo);
        xu[32768 + m] = hi; xu[36864 + m] = lo;
    }
}

// MFMA forward DFT along w, dfth-style: big coalesced staging bursts from xT,
// pure MFMA, block-contiguous PT2 output (no scattered writes).
// grid (hp=32, b=16): block = 4 h x 64 c = 256 N-cols, K=128 w (2 chunks of 64),
// M=32 rows (ri*16+ky). Wave wv owns h-local wv (64 cols).
// PT2[b][hp][ky][c][ri][h4] u32(hi|lo): block writes its own 32KB contiguously.
__global__ __launch_bounds__(256) void k_dftw(const unsigned* __restrict__ xT,
                                              float* __restrict__ ws) {
    __shared__ unsigned short BshH[256*68];   // [n 256][k 64 pad68] u16, swz k^8(n&7)
    __shared__ unsigned short BshL[256*68];
    int t = threadIdx.x;
    int hp = blockIdx.x, b = blockIdx.y;
    int l = t & 63, wv = t >> 6;
    const unsigned short* OU = (const unsigned short*)(ws + OFF_O);
    const unsigned short* FdAh = OU, *FdAl = OU + 4096;
    f4v acc[2][4];
    #pragma unroll
    for (int mt = 0; mt < 2; mt++)
        #pragma unroll
        for (int nt = 0; nt < 4; nt++) acc[mt][nt] = (f4v){0.f,0.f,0.f,0.f};

    const uint4* xT4 = (const uint4*)(xT + ((long)(b*128 + hp*4))*8192);  // col n -> +n*32 u4

    for (int kc2 = 0; kc2 < 2; kc2++) {
        __syncthreads();                    // protect Bsh from prev MFMA readers
        #pragma unroll
        for (int i = 0; i < 16; i++) {
            int idx = i*256 + t;
            int n = idx >> 4, s = idx & 15;       // col n, 16B-seg s (4 w)
            uint4 v = xT4[n*32 + kc2*16 + s];
            unsigned h01 = (v.x >> 16) | (v.y & 0xFFFF0000u);
            unsigned h23 = (v.z >> 16) | (v.w & 0xFFFF0000u);
            unsigned l01 = (v.x & 0xFFFFu) | (v.y << 16);
            unsigned l23 = (v.z & 0xFFFFu) | (v.w << 16);
            unsigned ku = (unsigned)((s*4) ^ (8*(n & 7)));
            *(uint2*)(BshH + n*68 + ku) = make_uint2(h01, h23);
            *(uint2*)(BshL + n*68 + ku) = make_uint2(l01, l23);
        }
        __syncthreads();
        #pragma unroll
        for (int kcl = 0; kcl < 2; kcl++) {
            int kglob = kc2*64 + kcl*32 + (l >> 4)*8;
            bfrag mah[2], mal[2];
            #pragma unroll
            for (int mt = 0; mt < 2; mt++) {
                int row = mt*16 + (l & 15);
                mah[mt] = *(const bfrag*)(FdAh + row*128 + kglob);
                mal[mt] = *(const bfrag*)(FdAl + row*128 + kglob);
            }
            #pragma unroll
            for (int nt = 0; nt < 4; nt++) {
                int n = wv*64 + nt*16 + (l & 15);
                int kl = kcl*32 + (l >> 4)*8;
                unsigned ku = (unsigned)(kl ^ (8*(n & 7)));
                bfrag bh = *(const bfrag*)(BshH + n*68 + ku);
                bfrag bl = *(const bfrag*)(BshL + n*68 + ku);
                #pragma unroll
                for (int mt = 0; mt < 2; mt++) {
                    f4v a_ = acc[mt][nt];
                    a_ = MFMA(mah[mt], bh, a_);
                    a_ = MFMA(mah[mt], bl, a_);
                    a_ = MFMA(mal[mt], bh, a_);
                    acc[mt][nt] = a_;
                }
            }
        }
    }
    // ---- epilogue: pack -> TB (alias BshH), then block-contiguous PT2 write ----
    __syncthreads();
    unsigned* TB = (unsigned*)BshH;   // TB[ky][c*2+ri][h4], word stride 520 per ky
    #pragma unroll
    for (int mt = 0; mt < 2; mt++)
        #pragma unroll
        for (int nt = 0; nt < 4; nt++)
            #pragma unroll
            for (int rr = 0; rr < 4; rr++) {
                float v = acc[mt][nt][rr];
                unsigned short hi, lo; split2(v, hi, lo);
                int trow = mt*16 + (l >> 4)*4 + rr;
                int ri = trow >> 4, ky = trow & 15;
                int c = nt*16 + (l & 15);
                TB[ky*520 + (c*2 + ri)*4 + wv] = ((unsigned)hi << 16) | lo;
            }
    __syncthreads();
    unsigned* PTb = (unsigned*)(ws + OFF_PQ) + ((long)(b*32 + hp))*8192;
    #pragma unroll
    for (int i = 0; i < 8; i++) {
        int idx = i*256 + t;
        int ky = idx >> 7, m = idx & 127;
        ((uint4*)PTb)[idx] = *(const uint4*)(TB + ky*520 + m*4);
    }
}

// MFMA forward DFT along h: X[2kx+s][(c,ri)] = EdA @ PT2 (per ky,b).
// Staging reads 2KB contiguous runs per (hp,ky). grid (ky=16, b=16).
__global__ __launch_bounds__(256) void k_dfth(float* __restrict__ ws) {
    __shared__ unsigned Bsh[16384];   // BTh 32KB (128 cols x 256B) | BTl 32KB
    int t = threadIdx.x;
    int ky = blockIdx.x, b = blockIdx.y;
    int l = t & 63, wv = t >> 6;
    char* bh_base = (char*)Bsh;
    char* bl_base = bh_base + 32768;
    const uint4* PT4 = (const uint4*)((const unsigned*)(ws + OFF_PQ));
    const unsigned short* OU = (const unsigned short*)(ws + OFF_O);
    const unsigned short* EdAh = OU + 8192, *EdAl = OU + 16384;

    // ---- stage PT2: for (hp, n=(c,ri)) read uint4 (4 h), unpack -> BT[n][128 kk] ----
    #pragma unroll
    for (int i = 0; i < 16; i++) {
        int idx = i*256 + t;
        int hp = idx >> 7, n = idx & 127;
        uint4 v = PT4[((long)(b*32 + hp)*16 + ky)*128 + n];
        unsigned h01 = (v.x >> 16) | (v.y & 0xFFFF0000u);
        unsigned h23 = (v.z >> 16) | (v.w & 0xFFFF0000u);
        unsigned l01 = (v.x & 0xFFFFu) | (v.y << 16);
        unsigned l23 = (v.z & 0xFFFFu) | (v.w << 16);
        int kk = hp*4;
        unsigned ad = (unsigned)(n*256 + ((kk*2) ^ ((n & 7) << 4)));
        *(uint2*)(bh_base + ad) = make_uint2(h01, h23);
        *(uint2*)(bl_base + ad) = make_uint2(l01, l23);
    }
    // A-frags for this wave's Mtile
    bfrag ea_h[4], ea_l[4];
    #pragma unroll
    for (int kc = 0; kc < 4; kc++) {
        int off = (wv*16 + (l & 15))*128 + kc*32 + (l >> 4)*8;
        ea_h[kc] = *(const bfrag*)(EdAh + off);
        ea_l[kc] = *(const bfrag*)(EdAl + off);
    }
    __syncthreads();
    f4v acc[8];
    #pragma unroll
    for (int nt = 0; nt < 8; nt++) acc[nt] = (f4v){0.f,0.f,0.f,0.f};
    #pragma unroll
    for (int kc = 0; kc < 4; kc++)
        #pragma unroll
        for (int nt = 0; nt < 8; nt++) {
            int col = nt*16 + (l & 15);
            unsigned ro = (unsigned)(col*256 + ((kc*64 + (l >> 4)*16) ^ ((col & 7) << 4)));
            bfrag bh = *(const bfrag*)(bh_base + ro);
            bfrag bl = *(const bfrag*)(bl_base + ro);
            acc[nt] = MFMA(ea_h[kc], bh, acc[nt]);
            acc[nt] = MFMA(ea_h[kc], bl, acc[nt]);
            acc[nt] = MFMA(ea_l[kc], bh, acc[nt]);
        }
    // ---- epilogue: complex combine + store X (f32, legacy layout) ----
    float* X = ws + OFF_X;
    #pragma unroll
    for (int nt = 0; nt < 8; nt++)
        #pragma unroll
        for (int p = 0; p < 2; p++) {
            float s0 = acc[nt][2*p], s1 = acc[nt][2*p + 1];
            float partner = __shfl_xor(s1, 1, 64);
            float res = (l & 1) ? (s0 - partner) : (s0 + partner);
            int kx = wv*8 + (l >> 4)*2 + p;
            X[(((long)b*32 + kx)*16 + ky)*128 + nt*16 + (l & 15)] = res;
        }
}

// per-mode complex mix with rho1 scaling folded into X staging. grid 512 (=mode)
__global__ void k_mix(float* __restrict__ ws) {
    __shared__ float Wsh[8192];
    __shared__ float Xs[2048];
    __shared__ float rhoT[1024];
    int t = threadIdx.x;
    int mode = blockIdx.x;
    int kxI = mode >> 4, ky = mode & 15;
    const float* WT = ws + OFF_WT;
    const float* X = ws + OFF_X;
    float* O = ws + OFF_O;
    for (int i = t; i < 1024; i += 256) {
        float a = ws[OFF_S1 + 2*i], s = ws[OFF_S1 + 2*i + 1];
        float m = a * (1.f/16384.f);
        float v = s * (1.f/16384.f) - m*m;
        rhoT[i] = rsqrtf(v + 1e-5f);
    }
    for (int idx = t; idx < 8192; idx += 256) Wsh[idx] = WT[(long)mode*8192 + idx];
    __syncthreads();
    for (int idx = t; idx < 2048; idx += 256) {
        int b = idx >> 7, r = idx & 127;
        Xs[idx] = X[((b*32 + kxI)*16 + ky)*128 + r] * rhoT[b*64 + (r >> 1)];
    }
    __syncthreads();
    int o = t & 63, bg = t >> 6;
    float accr[4] = {0,0,0,0}, acci[4] = {0,0,0,0};
    for (int i = 0; i < 64; i++) {
        float wr = Wsh[(i*64 + o)*2], wi = Wsh[(i*64 + o)*2 + 1];
        #pragma unroll
        for (int j = 0; j < 4; j++) {
            float xr = Xs[(bg*4 + j)*128 + 2*i], xi = Xs[(bg*4 + j)*128 + 2*i + 1];
            accr[j] += xr*wr - xi*wi;
            acci[j] += xr*wi + xi*wr;
        }
    }
    #pragma unroll
    for (int j = 0; j < 4; j++) {
        int b = bg*4 + j;
        float2* dst = (float2*)(O + ((b*32 + kxI)*16 + ky)*128);
        dst[o] = make_float2(accr[j], acci[j]);
    }
}

// Parseval stats of y directly from O. grid (16=b, 4=gg), 256 thr.
__global__ void k_pstats(float* __restrict__ ws) {
    __shared__ float red[256];
    int t = threadIdx.x, b = blockIdx.x, gg = blockIdx.y;
    int c = t & 63, g = t >> 6;
    const float* O = ws + OFF_O + (long)b*65536;   // [(kxI*16+ky)*128 + 2c]
    float t0 = 0.f, t2 = 0.f;
    int k0 = gg*8 + g*2;
    for (int kxI = k0; kxI < k0 + 2; kxI++)
        for (int ky = 0; ky < 16; ky++) {
            float re = O[(kxI*16 + ky)*128 + 2*c];
            float im = O[(kxI*16 + ky)*128 + 2*c + 1];
            float p = re*re + im*im;
            if (ky == 0) t0 += p; else t2 += p;
        }
    float s2p = 0.5f*t0 + 2.f*t2;
    if (gg == 0 && g == 0) {
        float ar = O[2*c], ai = O[2*c + 1];        // kxI=0, ky=0
        float t1 = ar*ar - ai*ai;
        for (int k = 1; k <= 15; k++) {
            float xr = O[(k*16)*128 + 2*c],        xi = O[(k*16)*128 + 2*c + 1];
            float yr = O[((32-k)*16)*128 + 2*c],   yi = O[((32-k)*16)*128 + 2*c + 1];
            t1 += 2.f*(xr*yr - xi*yi);
        }
        s2p += 0.5f*t1;
        ws[OFF_S2 + (b*64 + c)*2] = ar;            // s1 (mean term)
    }
    red[t] = s2p;
    __syncthreads();
    if (t < 64) {
        float s = red[t] + red[t+64] + red[t+128] + red[t+192];
        atomicAdd(&ws[OFF_S2 + (b*64 + t)*2 + 1], s * (1.f/16384.f));
    }
}

// inverse DFT along h: Q[b][h][ky][o] = sum_kx Out e^{+i 2pi f(kx) h/128}. grid (hg=16,b=16)
__global__ void k_idfth(float* __restrict__ ws) {
    __shared__ float Os[8192];
    __shared__ float tblL[256];
    int t = threadIdx.x;
    int hg = blockIdx.x, b = blockIdx.y;
    for (int i = t; i < 256; i += 256) tblL[i] = ws[OFF_TBL + i];
    const float* O = ws + OFF_O;
    float* Q = ws + OFF_PQ;
    int o = t & 63, kyg = t >> 6;
    float accr[4][8], acci[4][8];
    #pragma unroll
    for (int kk = 0; kk < 4; kk++)
        #pragma unroll
        for (int h = 0; h < 8; h++) { accr[kk][h] = 0.f; acci[kk][h] = 0.f; }
    for (int kc = 0; kc < 8; kc++) {
        __syncthreads();
        for (int idx = t; idx < 8192; idx += 256) Os[idx] = O[(long)b*65536 + kc*8192 + idx];
        __syncthreads();
        for (int k4 = 0; k4 < 4; k4++) {
            int kxI = kc*4 + k4;
            int freq = kxI < 16 ? kxI : 96 + kxI;
            float vr[4], vi[4];
            #pragma unroll
            for (int kk = 0; kk < 4; kk++) {
                int ky = kyg*4 + kk;
                vr[kk] = Os[((k4*16 + ky)*64 + o)*2];
                vi[kk] = Os[((k4*16 + ky)*64 + o)*2 + 1];
            }
            for (int h = 0; h < 8; h++) {
                int habs = hg*8 + h;
                int m = (freq * habs) & 127;
                float cs = tblL[2*m], sn = tblL[2*m + 1];
                #pragma unroll
                for (int kk = 0; kk < 4; kk++) {
                    accr[kk][h] += vr[kk]*cs - vi[kk]*sn;   // * e^{+i th}
                    acci[kk][h] += vr[kk]*sn + vi[kk]*cs;
                }
            }
        }
    }
    #pragma unroll
    for (int kk = 0; kk < 4; kk++)
        #pragma unroll
        for (int h = 0; h < 8; h++) {
            int ky = kyg*4 + kk, habs = hg*8 + h;
            float2* dst = (float2*)(Q + ((long)(b*128 + habs)*16 + ky)*128);
            dst[o] = make_float2(accr[kk][h], acci[kk][h]);
        }
}

// fused MFMA kernel: Y = M@Qm (iDFT-w), z = (Y-mu)*rho, h = GELU(z@W1+b1),
// out = h@W2+b2. zhS/hhS rows are wave-private -> single staging barrier.
// grid (h=128,b=16). Overwrites ALL of d_out (reclaiming the xT scratch).
__global__ __launch_bounds__(256, 2) void k_mlp(const float* __restrict__ mb1,
                      const float* __restrict__ mb2,
                      float* __restrict__ out, const float* __restrict__ ws) {
    __shared__ unsigned short zhS[8192];                // z[w][64c], swz (w&7)<<4
    __shared__ unsigned short w1hS[8192];               // w1[j][64c], swz (j&7)<<4
    __shared__ unsigned short w2hS[8192];               // w2[o][128j], swz (o&15)<<4
    __shared__ unsigned short hhS[8192];                // h-half [w][64jl], swz (w&7)<<4
    __shared__ unsigned short qhS[2560], qlS[2560];     // QmT[c][40k] hi/lo
    __shared__ float muL[64], rhoL[64], b1L[128], b2L[64];
    int t = threadIdx.x;
    int h = blockIdx.x, b = blockIdx.y;
    int l = t & 63, wv = t >> 6;

    const unsigned short* xu = (const unsigned short*)(ws + OFF_X);
    const unsigned short* w1hG = xu;
    const unsigned short* w2hG = xu + 16384;
    const unsigned short* MhG  = xu + 32768, *MlG  = xu + 36864;

    for (int ch = t; ch < 1024; ch += 256) {       // w1: rows j, stride 128B
        int j = ch >> 3, c0 = (ch & 7) * 8;
        unsigned off = (unsigned)(j*128 + c0*2) ^ (unsigned)((j & 7) << 4);
        *(bfrag*)((char*)w1hS + off) = *(const bfrag*)(w1hG + ch*8);
    }
    for (int ch = t; ch < 1024; ch += 256) {       // w2: rows o, stride 256B
        int o = ch >> 4, j0 = (ch & 15) * 8;
        unsigned off = (unsigned)(o*256 + j0*2) ^ (unsigned)((o & 15) << 4);
        *(bfrag*)((char*)w2hS + off) = *(const bfrag*)(w2hG + ch*8);
    }
    const float* Qp = ws + OFF_PQ + (long)(b*128 + h)*2048;
    for (int i = t; i < 2048; i += 256) {
        int k = i & 31, c = i >> 5;
        float v = Qp[(k >> 1)*128 + c*2 + (k & 1)];
        unsigned short hi, lo; split2(v, hi, lo);
        qhS[c*40 + k] = hi; qlS[c*40 + k] = lo;
    }
    if (t < 64) {
        float s1 = ws[OFF_S2 + (b*64+t)*2], s2 = ws[OFF_S2 + (b*64+t)*2 + 1];
        float m = s1 * (1.f/16384.f);
        float v = s2 * (1.f/16384.f) - m*m;
        muL[t] = m; rhoL[t] = rsqrtf(v + 1e-5f);
        b2L[t] = mb2[t];
    }
    if (t >= 64 && t < 192) b1L[t - 64] = mb1[t - 64];
    bfrag ma_h[2], ma_l[2];
    #pragma unroll
    for (int q = 0; q < 2; q++) {
        int w = (wv + 4*q)*16 + (l & 15);
        ma_h[q] = *(const bfrag*)(MhG + w*32 + (l >> 4)*8);
        ma_l[q] = *(const bfrag*)(MlG + w*32 + (l >> 4)*8);
    }
    __syncthreads();   // cross-wave staging -- the ONLY barrier needed

    #pragma unroll
    for (int q = 0; q < 2; q++) {
        int wt = wv + 4*q;
        #pragma unroll
        for (int ct = 0; ct < 4; ct++) {
            unsigned ro = (unsigned)((ct*16 + (l & 15))*80 + (l >> 4)*16);
            bfrag bh = *(const bfrag*)((const char*)qhS + ro);
            bfrag bl = *(const bfrag*)((const char*)qlS + ro);
            f4v acc = {0.f, 0.f, 0.f, 0.f};
            acc = MFMA(ma_h[q], bh, acc);
            acc = MFMA(ma_h[q], bl, acc);
            acc = MFMA(ma_l[q], bh, acc);
            int c = ct*16 + (l & 15);
            float mu_ = muL[c], rh_ = rhoL[c];
            #pragma unroll
            for (int r = 0; r < 4; r++) {
                int w = wt*16 + (l >> 4)*4 + r;
                float z = (acc[r] - mu_) * rh_;
                unsigned off = (unsigned)(w*128 + c*2) ^ (unsigned)((w & 7) << 4);
                *(unsigned short*)((char*)zhS + off) = f2bf_rn(z);
            }
        }
    }

    bfrag za[2][2];
    #pragma unroll
    for (int q = 0; q < 2; q++) {
        int w = (wv + 4*q)*16 + (l & 15);
        #pragma unroll
        for (int ks = 0; ks < 2; ks++) {
            unsigned off = (unsigned)(w*128 + (ks*32 + (l >> 4)*8)*2) ^ (unsigned)((w & 7) << 4);
            za[q][ks] = *(const bfrag*)((const char*)zhS + off);
        }
    }
    f4v accO[2][4];
    #pragma unroll
    for (int q = 0; q < 2; q++)
        #pragma unroll
        for (int ot = 0; ot < 4; ot++) accO[q][ot] = (f4v){0.f,0.f,0.f,0.f};

    #pragma unroll
    for (int jh = 0; jh < 2; jh++) {
        #pragma unroll
        for (int q = 0; q < 2; q++) {
            int wt = wv + 4*q;
            #pragma unroll
            for (int jt = 0; jt < 4; jt++) {
                int j = jh*64 + jt*16 + (l & 15);
                f4v acc = {0.f, 0.f, 0.f, 0.f};
                #pragma unroll
                for (int ks = 0; ks < 2; ks++) {
                    unsigned off = (unsigned)(j*128 + (ks*32 + (l >> 4)*8)*2) ^ (unsigned)((j & 7) << 4);
                    bfrag bh = *(const bfrag*)((const char*)w1hS + off);
                    acc = MFMA(za[q][ks], bh, acc);
                }
                float bj = b1L[j];
                #pragma unroll
                for (int r = 0; r < 4; r++) {
                    int w = wt*16 + (l >> 4)*4 + r;
                    float hv = gelu_t(acc[r] + bj);
                    int jl = jt*16 + (l & 15);
                    unsigned off = (unsigned)(w*128 + jl*2) ^ (unsigned)((w & 7) << 4);
                    *(unsigned short*)((char*)hhS + off) = f2bf_rn(hv);
                }
            }
        }
        #pragma unroll
        for (int q = 0; q < 2; q++) {
            int w = (wv + 4*q)*16 + (l & 15);
            bfrag ha[2];
            #pragma unroll
            for (int ks = 0; ks < 2; ks++) {
                unsigned off = (unsigned)(w*128 + (ks*32 + (l >> 4)*8)*2) ^ (unsigned)((w & 7) << 4);
                ha[ks] = *(const bfrag*)((const char*)hhS + off);
            }
            #pragma unroll
            for (int ot = 0; ot < 4; ot++) {
                int o = ot*16 + (l & 15);
                f4v acc = accO[q][ot];
                #pragma unroll
                for (int ks = 0; ks < 2; ks++) {
                    int jj = jh*64 + ks*32 + (l >> 4)*8;
                    unsigned off = (unsigned)(o*256 + jj*2) ^ (unsigned)((o & 15) << 4);
                    bfrag bh = *(const bfrag*)((const char*)w2hS + off);
                    acc = MFMA(ha[ks], bh, acc);
                }
                accO[q][ot] = acc;
            }
        }
    }
    #pragma unroll
    for (int q = 0; q < 2; q++) {
        int wt = wv + 4*q;
        #pragma unroll
        for (int ot = 0; ot < 4; ot++) {
            int o = ot*16 + (l & 15);
            float bo = b2L[o];
            #pragma unroll
            for (int r = 0; r < 4; r++) {
                int w = wt*16 + (l >> 4)*4 + r;
                out[((long)(b*128 + h)*128 + w)*64 + o] = accO[q][ot][r] + bo;
            }
        }
    }
}

extern "C" void kernel_launch(void* const* d_in, const int* in_sizes, int n_in,
                              void* d_out, int out_size, void* d_ws, size_t ws_size,
                              hipStream_t stream) {
    const float* x   = (const float*)d_in[0];
    const float* w1r = (const float*)d_in[1];
    const float* w1i = (const float*)d_in[2];
    const float* w2r = (const float*)d_in[3];
    const float* w2i = (const float*)d_in[4];
    const float* mw1 = (const float*)d_in[5];
    const float* mb1 = (const float*)d_in[6];
    const float* mw2 = (const float*)d_in[7];
    const float* mb2 = (const float*)d_in[8];
    float* ws  = (float*)d_ws;
    float* out = (float*)d_out;
    unsigned* xT = (unsigned*)d_out;   // 16.7M u32 scratch; fully overwritten by k_mlp

    k_init  <<<dim3(49),      dim3(256), 0, stream>>>(ws);
    k_xt    <<<dim3(64,16),   dim3(128), 0, stream>>>(x, xT, ws);   // transpose + stats
    k_trans <<<dim3(64,2),    dim3(256), 0, stream>>>(w1r, w1i, w2r, w2i, ws);
    k_dftw  <<<dim3(32,16),   dim3(256), 0, stream>>>(xT, ws);
    k_dfth  <<<dim3(16,16),   dim3(256), 0, stream>>>(ws);
    k_mix   <<<dim3(512),     dim3(256), 0, stream>>>(ws);
    k_wmlp  <<<dim3(80),      dim3(256), 0, stream>>>(mw1, mw2, ws);  // X dead after k_mix
    k_pstats<<<dim3(16,4),    dim3(256), 0, stream>>>(ws);
    k_idfth <<<dim3(16,16),   dim3(256), 0, stream>>>(ws);
    k_mlp   <<<dim3(128,16),  dim3(256), 0, stream>>>(mb1, mb2, out, ws);
}

// Round 15
// 210.620 us; speedup vs baseline: 1.2196x; 1.0301x over previous
//
#include <hip/hip_runtime.h>
#include <math.h>

// Problem constants: B=16, H=W=128, C=64, M1=M2=16
// Workspace layout (float offsets):
#define OFF_TBL 0u            // 128 x {cos,sin}(2*pi*m/128)          (256)
#define OFF_S1  256u          // instance-norm-1 raw sums [b*64+c][2] (2048)
#define OFF_S2  2304u         // instance-norm-2 stats (s1,s2)        (2048)
#define OFF_PQ  4352u         // PT2[b][hp32][ky16][c64][ri2][h4] u32 bf16 hi|lo (4194304)
                              //   aliased later with Q[b][h][ky][o][2] f32
#define OFF_X   4198656u      // X[b][kx][ky][c][2] f32               (1048576)
#define OFF_O   5247232u      // Out[b][kx][ky][o][2] f32             (1048576)
                              //   head doubles (pre-mix) as u16 trig tables:
                              //   FdAh[32][128] @0, FdAl @4096, EdAh[64][128] @8192, EdAl @16384
#define OFF_WT  6295808u      // WT[mode][i][o][2]                    (4194304)
// total = 10490112 floats = 41.96 MB
// X region is dead after k_mix -> reuse as u16 arrays for bf16-split MLP weights:
//   u16[0..8192) w1hi   [8192..16384) w1lo   [16384..24576) w2hi
//   [24576..32768) w2lo  [32768..36864) Mhi  [36864..40960) Mlo

typedef __attribute__((ext_vector_type(8))) short bfrag;
typedef __attribute__((ext_vector_type(4))) float f4v;
#define MFMA(A,B,C) __builtin_amdgcn_mfma_f32_16x16x32_bf16(A,B,C,0,0,0)

// compile-time float4 component select -- NO address-taken indexing (scratch hazard)
#define F4GET(v, i) ((i)==0 ? (v).x : (i)==1 ? (v).y : (i)==2 ? (v).z : (v).w)

__device__ __forceinline__ unsigned short f2bf_rn(float x) {
    unsigned u = __float_as_uint(x);
    unsigned r = u + 0x7FFFu + ((u >> 16) & 1u);
    return (unsigned short)(r >> 16);
}
__device__ __forceinline__ float bf2f(unsigned short h) {
    return __uint_as_float(((unsigned)h) << 16);
}
__device__ __forceinline__ void split2(float x, unsigned short& hi, unsigned short& lo) {
    hi = f2bf_rn(x);
    lo = f2bf_rn(x - bf2f(hi));
}
// tanh-form GELU; matches exact GELU to <1e-5 for |x| <= 0.5 (our range)
__device__ __forceinline__ float gelu_t(float x) {
    float u = 0.79788456080286536f * (x + 0.044715f * x * x * x);
    float e = __expf(2.f * u);
    float th = 1.f - 2.f / (e + 1.f);
    return 0.5f * x * (1.f + th);
}

// block 0: twiddle table + zero S1/S2. blocks 1..48: bf16-split trig tables
// (F for dftw, E for dfth) into the O region (dead until k_mix overwrites).
__global__ void k_init(float* __restrict__ ws) {
    int t = threadIdx.x, bid = blockIdx.x;
    if (bid == 0) {
        if (t < 128) {
            double ang = 6.283185307179586476925286766559 * (double)t / 128.0;
            ws[OFF_TBL + 2*t]     = (float)cos(ang);
            ws[OFF_TBL + 2*t + 1] = (float)sin(ang);
        }
        for (int i = t; i < 4096; i += 256) ws[OFF_S1 + i] = 0.f;
        return;
    }
    int e = (bid - 1)*256 + t;   // 0..12287
    unsigned short* OU = (unsigned short*)(ws + OFF_O);
    const double TWO_PI = 6.283185307179586476925286766559;
    if (e < 4096) {              // FdA[row=ri*16+ky][w]: re rows cos, im rows -sin
        int row = e >> 7, w = e & 127, ky = row & 15;
        double ang = TWO_PI * (double)((ky * w) & 127) / 128.0;
        double v = (row < 16) ? cos(ang) : -sin(ang);
        unsigned short hi, lo; split2((float)v, hi, lo);
        OU[e] = hi; OU[4096 + e] = lo;
    } else {                     // EdA[row=2kx+s][h]: s=0 cos, s=1 sin (of freq f(kx))
        int e2 = e - 4096, row = e2 >> 7, h = e2 & 127;
        int kx = row >> 1, f = kx < 16 ? kx : 96 + kx;
        double ang = TWO_PI * (double)((f * h) & 127) / 128.0;
        double v = (row & 1) ? sin(ang) : cos(ang);
        unsigned short hi, lo; split2((float)v, hi, lo);
        OU[8192 + e2] = hi; OU[16384 + e2] = lo;
    }
}

// weight transpose: [i][o][kx][ky] (x4 arrays) -> WT[mode][i][o][{re,im}]. grid (64=i, 2=part)
__global__ void k_trans(const float* __restrict__ w1r, const float* __restrict__ w1i,
                        const float* __restrict__ w2r, const float* __restrict__ w2i,
                        float* __restrict__ ws) {
    __shared__ float Lr[16*257], Li[16*257];
    int t = threadIdx.x;
    int i = blockIdx.x;
    int part = blockIdx.y;
    float* WT = ws + OFF_WT;
    const float* wr = part ? w2r : w1r;
    const float* wi = part ? w2i : w1i;
    for (int oc = 0; oc < 4; oc++) {
        int o0 = oc * 16;
        __syncthreads();
        for (int idx = t; idx < 4096; idx += 256) {
            int oo = idx >> 8, m = idx & 255;
            Lr[oo*257 + m] = wr[(i*64 + o0 + oo)*256 + m];
            Li[oo*257 + m] = wi[(i*64 + o0 + oo)*256 + m];
        }
        __syncthreads();
        for (int idx = t; idx < 8192; idx += 256) {
            int mode = idx >> 5, rem = idx & 31, oo = rem >> 1, ri = rem & 1;
            float val = ri ? Li[oo*257 + mode] : Lr[oo*257 + mode];
            int gm = part*256 + mode;
            WT[((gm*64 + i)*64 + (o0 + oo))*2 + ri] = val;
        }
    }
}

// bf16-split MLP weights + iDFT-w matrix M into the dead X region. grid 80
__global__ void k_wmlp(const float* __restrict__ mw1, const float* __restrict__ mw2,
                       float* __restrict__ ws) {
    int i = blockIdx.x * 256 + threadIdx.x;   // [0, 20480)
    unsigned short* xu = (unsigned short*)(ws + OFF_X);
    if (i < 8192) {
        unsigned short hi, lo; split2(mw1[i], hi, lo);
        xu[i] = hi; xu[8192 + i] = lo;
    } else if (i < 16384) {
        int k = i - 8192;
        unsigned short hi, lo; split2(mw2[k], hi, lo);
        xu[16384 + k] = hi; xu[24576 + k] = lo;
    } else if (i < 20480) {
        int m = i - 16384;           // w*32 + k
        int w = m >> 5, k = m & 31;
        int ky = k >> 1;
        double ang = 6.283185307179586476925286766559 * (double)((ky * w) & 127) / 128.0;
        double v = (k & 1) ? -sin(ang) : cos(ang);
        double a = (ky == 0) ? 1.0 : 2.0;
        float val = (float)(v * a) * (1.f/16384.f);
        unsigned short hi, lo; split2(val, hi, lo);
        xu[32768 + m] = hi; xu[36864 + m] = lo;
    }
}

// MFMA forward DFT along w reading x DIRECTLY (k_xt deleted): dfth-style
// cooperative staging with fused transpose+bf16-split+stats, pure MFMA,
// block-contiguous PT2 output. grid (hp=32, b=16): block = 4 h x 64 c =
// 256 N-cols, K=128 w (2 chunks of 64). Wave wv owns h-local wv (64 cols).
// PT2[b][hp][ky][c][ri][h4] u32(hi|lo): block writes its own 32KB contiguously.
__global__ __launch_bounds__(256) void k_dftw(const float* __restrict__ x,
                                              float* __restrict__ ws) {
    __shared__ unsigned short BshH[256*68];   // [n=hl*64+c][k 64 pad68] u16, swz k^8(n&7)
    __shared__ unsigned short BshL[256*68];
    int t = threadIdx.x;
    int hp = blockIdx.x, b = blockIdx.y;
    int l = t & 63, wv = t >> 6;
    const unsigned short* OU = (const unsigned short*)(ws + OFF_O);
    const unsigned short* FdAh = OU, *FdAl = OU + 4096;
    f4v acc[2][4];
    #pragma unroll
    for (int mt = 0; mt < 2; mt++)
        #pragma unroll
        for (int nt = 0; nt < 4; nt++) acc[mt][nt] = (f4v){0.f,0.f,0.f,0.f};

    float s1a[4] = {0,0,0,0}, s2a[4] = {0,0,0,0};   // stats for c = c4*4 + j
    int c4 = t & 15;
    const float* xb = x + ((long)(b*128 + hp*4))*8192;   // 4 h rows

    for (int kc2 = 0; kc2 < 2; kc2++) {
        __syncthreads();                    // protect Bsh from prev MFMA readers
        // ---- stage direct from x: 16-lane groups read full 256B c-lines ----
        #pragma unroll
        for (int i = 0; i < 16; i++) {
            int idx = i*256 + t;
            int hw = idx >> 4;              // 0..255: hl = hw>>6, wl = hw&63
            int hl = hw >> 6, wl = hw & 63;
            float4 v = *(const float4*)(xb + ((long)hl*8192) + (kc2*64 + wl)*64 + c4*4);
            #pragma unroll
            for (int j = 0; j < 4; j++) {
                float f = F4GET(v, j);
                s1a[j] += f;
                s2a[j] += f*f;
                unsigned short hi, lo; split2(f, hi, lo);
                int n = hl*64 + c4*4 + j;
                unsigned ku = (unsigned)(wl ^ (8*(n & 7)));
                BshH[n*68 + ku] = hi;
                BshL[n*68 + ku] = lo;
            }
        }
        __syncthreads();
        // ---- MFMA: 4 Ntiles x 2 Mtiles, 3-term hi/lo ----
        #pragma unroll
        for (int kcl = 0; kcl < 2; kcl++) {
            int kglob = kc2*64 + kcl*32 + (l >> 4)*8;
            bfrag mah[2], mal[2];
            #pragma unroll
            for (int mt = 0; mt < 2; mt++) {
                int row = mt*16 + (l & 15);
                mah[mt] = *(const bfrag*)(FdAh + row*128 + kglob);
                mal[mt] = *(const bfrag*)(FdAl + row*128 + kglob);
            }
            #pragma unroll
            for (int nt = 0; nt < 4; nt++) {
                int n = wv*64 + nt*16 + (l & 15);
                int kl = kcl*32 + (l >> 4)*8;
                unsigned ku = (unsigned)(kl ^ (8*(n & 7)));
                bfrag bh = *(const bfrag*)(BshH + n*68 + ku);
                bfrag bl = *(const bfrag*)(BshL + n*68 + ku);
                #pragma unroll
                for (int mt = 0; mt < 2; mt++) {
                    f4v a_ = acc[mt][nt];
                    a_ = MFMA(mah[mt], bh, a_);
                    a_ = MFMA(mah[mt], bl, a_);
                    a_ = MFMA(mal[mt], bh, a_);
                    acc[mt][nt] = a_;
                }
            }
        }
    }
    // ---- stats reduce (lanes l, l+16, l+32, l+48 share c4) + atomics ----
    #pragma unroll
    for (int j = 0; j < 4; j++) {
        s1a[j] += __shfl_down(s1a[j], 16, 64);
        s1a[j] += __shfl_down(s1a[j], 32, 64);
        s2a[j] += __shfl_down(s2a[j], 16, 64);
        s2a[j] += __shfl_down(s2a[j], 32, 64);
    }
    if (l < 16) {
        #pragma unroll
        for (int j = 0; j < 4; j++) {
            int c = c4*4 + j;
            atomicAdd(&ws[OFF_S1 + (b*64 + c)*2],     s1a[j]);
            atomicAdd(&ws[OFF_S1 + (b*64 + c)*2 + 1], s2a[j]);
        }
    }
    // ---- epilogue: pack -> TB (alias BshH), then block-contiguous PT2 write ----
    __syncthreads();
    unsigned* TB = (unsigned*)BshH;   // TB[ky][c*2+ri][h4], word stride 520 per ky
    #pragma unroll
    for (int mt = 0; mt < 2; mt++)
        #pragma unroll
        for (int nt = 0; nt < 4; nt++)
            #pragma unroll
            for (int rr = 0; rr < 4; rr++) {
                float v = acc[mt][nt][rr];
                unsigned short hi, lo; split2(v, hi, lo);
                int trow = mt*16 + (l >> 4)*4 + rr;
                int ri = trow >> 4, ky = trow & 15;
                int c = nt*16 + (l & 15);
                TB[ky*520 + (c*2 + ri)*4 + wv] = ((unsigned)hi << 16) | lo;
            }
    __syncthreads();
    unsigned* PTb = (unsigned*)(ws + OFF_PQ) + ((long)(b*32 + hp))*8192;
    #pragma unroll
    for (int i = 0; i < 8; i++) {
        int idx = i*256 + t;
        int ky = idx >> 7, m = idx & 127;
        ((uint4*)PTb)[idx] = *(const uint4*)(TB + ky*520 + m*4);
    }
}

// MFMA forward DFT along h: X[2kx+s][(c,ri)] = EdA @ PT2 (per ky,b).
// Staging reads 2KB contiguous runs per (hp,ky). grid (ky=16, b=16).
__global__ __launch_bounds__(256) void k_dfth(float* __restrict__ ws) {
    __shared__ unsigned Bsh[16384];   // BTh 32KB (128 cols x 256B) | BTl 32KB
    int t = threadIdx.x;
    int ky = blockIdx.x, b = blockIdx.y;
    int l = t & 63, wv = t >> 6;
    char* bh_base = (char*)Bsh;
    char* bl_base = bh_base + 32768;
    const uint4* PT4 = (const uint4*)((const unsigned*)(ws + OFF_PQ));
    const unsigned short* OU = (const unsigned short*)(ws + OFF_O);
    const unsigned short* EdAh = OU + 8192, *EdAl = OU + 16384;

    // ---- stage PT2: for (hp, n=(c,ri)) read uint4 (4 h), unpack -> BT[n][128 kk] ----
    #pragma unroll
    for (int i = 0; i < 16; i++) {
        int idx = i*256 + t;
        int hp = idx >> 7, n = idx & 127;
        uint4 v = PT4[((long)(b*32 + hp)*16 + ky)*128 + n];
        unsigned h01 = (v.x >> 16) | (v.y & 0xFFFF0000u);
        unsigned h23 = (v.z >> 16) | (v.w & 0xFFFF0000u);
        unsigned l01 = (v.x & 0xFFFFu) | (v.y << 16);
        unsigned l23 = (v.z & 0xFFFFu) | (v.w << 16);
        int kk = hp*4;
        unsigned ad = (unsigned)(n*256 + ((kk*2) ^ ((n & 7) << 4)));
        *(uint2*)(bh_base + ad) = make_uint2(h01, h23);
        *(uint2*)(bl_base + ad) = make_uint2(l01, l23);
    }
    // A-frags for this wave's Mtile
    bfrag ea_h[4], ea_l[4];
    #pragma unroll
    for (int kc = 0; kc < 4; kc++) {
        int off = (wv*16 + (l & 15))*128 + kc*32 + (l >> 4)*8;
        ea_h[kc] = *(const bfrag*)(EdAh + off);
        ea_l[kc] = *(const bfrag*)(EdAl + off);
    }
    __syncthreads();
    f4v acc[8];
    #pragma unroll
    for (int nt = 0; nt < 8; nt++) acc[nt] = (f4v){0.f,0.f,0.f,0.f};
    #pragma unroll
    for (int kc = 0; kc < 4; kc++)
        #pragma unroll
        for (int nt = 0; nt < 8; nt++) {
            int col = nt*16 + (l & 15);
            unsigned ro = (unsigned)(col*256 + ((kc*64 + (l >> 4)*16) ^ ((col & 7) << 4)));
            bfrag bh = *(const bfrag*)(bh_base + ro);
            bfrag bl = *(const bfrag*)(bl_base + ro);
            acc[nt] = MFMA(ea_h[kc], bh, acc[nt]);
            acc[nt] = MFMA(ea_h[kc], bl, acc[nt]);
            acc[nt] = MFMA(ea_l[kc], bh, acc[nt]);
        }
    // ---- epilogue: complex combine + store X (f32, legacy layout) ----
    float* X = ws + OFF_X;
    #pragma unroll
    for (int nt = 0; nt < 8; nt++)
        #pragma unroll
        for (int p = 0; p < 2; p++) {
            float s0 = acc[nt][2*p], s1 = acc[nt][2*p + 1];
            float partner = __shfl_xor(s1, 1, 64);
            float res = (l & 1) ? (s0 - partner) : (s0 + partner);
            int kx = wv*8 + (l >> 4)*2 + p;
            X[(((long)b*32 + kx)*16 + ky)*128 + nt*16 + (l & 15)] = res;
        }
}

// per-mode complex mix with rho1 scaling folded into X staging. grid 512 (=mode)
__global__ void k_mix(float* __restrict__ ws) {
    __shared__ float Wsh[8192];
    __shared__ float Xs[2048];
    __shared__ float rhoT[1024];
    int t = threadIdx.x;
    int mode = blockIdx.x;
    int kxI = mode >> 4, ky = mode & 15;
    const float* WT = ws + OFF_WT;
    const float* X = ws + OFF_X;
    float* O = ws + OFF_O;
    for (int i = t; i < 1024; i += 256) {
        float a = ws[OFF_S1 + 2*i], s = ws[OFF_S1 + 2*i + 1];
        float m = a * (1.f/16384.f);
        float v = s * (1.f/16384.f) - m*m;
        rhoT[i] = rsqrtf(v + 1e-5f);
    }
    for (int idx = t; idx < 8192; idx += 256) Wsh[idx] = WT[(long)mode*8192 + idx];
    __syncthreads();
    for (int idx = t; idx < 2048; idx += 256) {
        int b = idx >> 7, r = idx & 127;
        Xs[idx] = X[((b*32 + kxI)*16 + ky)*128 + r] * rhoT[b*64 + (r >> 1)];
    }
    __syncthreads();
    int o = t & 63, bg = t >> 6;
    float accr[4] = {0,0,0,0}, acci[4] = {0,0,0,0};
    for (int i = 0; i < 64; i++) {
        float wr = Wsh[(i*64 + o)*2], wi = Wsh[(i*64 + o)*2 + 1];
        #pragma unroll
        for (int j = 0; j < 4; j++) {
            float xr = Xs[(bg*4 + j)*128 + 2*i], xi = Xs[(bg*4 + j)*128 + 2*i + 1];
            accr[j] += xr*wr - xi*wi;
            acci[j] += xr*wi + xi*wr;
        }
    }
    #pragma unroll
    for (int j = 0; j < 4; j++) {
        int b = bg*4 + j;
        float2* dst = (float2*)(O + ((b*32 + kxI)*16 + ky)*128);
        dst[o] = make_float2(accr[j], acci[j]);
    }
}

// Parseval stats of y directly from O. grid (16=b, 4=gg), 256 thr.
__global__ void k_pstats(float* __restrict__ ws) {
    __shared__ float red[256];
    int t = threadIdx.x, b = blockIdx.x, gg = blockIdx.y;
    int c = t & 63, g = t >> 6;
    const float* O = ws + OFF_O + (long)b*65536;   // [(kxI*16+ky)*128 + 2c]
    float t0 = 0.f, t2 = 0.f;
    int k0 = gg*8 + g*2;
    for (int kxI = k0; kxI < k0 + 2; kxI++)
        for (int ky = 0; ky < 16; ky++) {
            float re = O[(kxI*16 + ky)*128 + 2*c];
            float im = O[(kxI*16 + ky)*128 + 2*c + 1];
            float p = re*re + im*im;
            if (ky == 0) t0 += p; else t2 += p;
        }
    float s2p = 0.5f*t0 + 2.f*t2;
    if (gg == 0 && g == 0) {
        float ar = O[2*c], ai = O[2*c + 1];        // kxI=0, ky=0
        float t1 = ar*ar - ai*ai;
        for (int k = 1; k <= 15; k++) {
            float xr = O[(k*16)*128 + 2*c],        xi = O[(k*16)*128 + 2*c + 1];
            float yr = O[((32-k)*16)*128 + 2*c],   yi = O[((32-k)*16)*128 + 2*c + 1];
            t1 += 2.f*(xr*yr - xi*yi);
        }
        s2p += 0.5f*t1;
        ws[OFF_S2 + (b*64 + c)*2] = ar;            // s1 (mean term)
    }
    red[t] = s2p;
    __syncthreads();
    if (t < 64) {
        float s = red[t] + red[t+64] + red[t+128] + red[t+192];
        atomicAdd(&ws[OFF_S2 + (b*64 + t)*2 + 1], s * (1.f/16384.f));
    }
}

// inverse DFT along h: Q[b][h][ky][o] = sum_kx Out e^{+i 2pi f(kx) h/128}. grid (hg=16,b=16)
__global__ void k_idfth(float* __restrict__ ws) {
    __shared__ float Os[8192];
    __shared__ float tblL[256];
    int t = threadIdx.x;
    int hg = blockIdx.x, b = blockIdx.y;
    for (int i = t; i < 256; i += 256) tblL[i] = ws[OFF_TBL + i];
    const float* O = ws + OFF_O;
    float* Q = ws + OFF_PQ;
    int o = t & 63, kyg = t >> 6;
    float accr[4][8], acci[4][8];
    #pragma unroll
    for (int kk = 0; kk < 4; kk++)
        #pragma unroll
        for (int h = 0; h < 8; h++) { accr[kk][h] = 0.f; acci[kk][h] = 0.f; }
    for (int kc = 0; kc < 8; kc++) {
        __syncthreads();
        for (int idx = t; idx < 8192; idx += 256) Os[idx] = O[(long)b*65536 + kc*8192 + idx];
        __syncthreads();
        for (int k4 = 0; k4 < 4; k4++) {
            int kxI = kc*4 + k4;
            int freq = kxI < 16 ? kxI : 96 + kxI;
            float vr[4], vi[4];
            #pragma unroll
            for (int kk = 0; kk < 4; kk++) {
                int ky = kyg*4 + kk;
                vr[kk] = Os[((k4*16 + ky)*64 + o)*2];
                vi[kk] = Os[((k4*16 + ky)*64 + o)*2 + 1];
            }
            for (int h = 0; h < 8; h++) {
                int habs = hg*8 + h;
                int m = (freq * habs) & 127;
                float cs = tblL[2*m], sn = tblL[2*m + 1];
                #pragma unroll
                for (int kk = 0; kk < 4; kk++) {
                    accr[kk][h] += vr[kk]*cs - vi[kk]*sn;   // * e^{+i th}
                    acci[kk][h] += vr[kk]*sn + vi[kk]*cs;
                }
            }
        }
    }
    #pragma unroll
    for (int kk = 0; kk < 4; kk++)
        #pragma unroll
        for (int h = 0; h < 8; h++) {
            int ky = kyg*4 + kk, habs = hg*8 + h;
            float2* dst = (float2*)(Q + ((long)(b*128 + habs)*16 + ky)*128);
            dst[o] = make_float2(accr[kk][h], acci[kk][h]);
        }
}

// fused MFMA kernel: Y = M@Qm (iDFT-w), z = (Y-mu)*rho, h = GELU(z@W1+b1),
// out = h@W2+b2. zhS/hhS rows are wave-private -> single staging barrier.
// grid (h=128,b=16).
__global__ __launch_bounds__(256, 2) void k_mlp(const float* __restrict__ mb1,
                      const float* __restrict__ mb2,
                      float* __restrict__ out, const float* __restrict__ ws) {
    __shared__ unsigned short zhS[8192];                // z[w][64c], swz (w&7)<<4
    __shared__ unsigned short w1hS[8192];               // w1[j][64c], swz (j&7)<<4
    __shared__ unsigned short w2hS[8192];               // w2[o][128j], swz (o&15)<<4
    __shared__ unsigned short hhS[8192];                // h-half [w][64jl], swz (w&7)<<4
    __shared__ unsigned short qhS[2560], qlS[2560];     // QmT[c][40k] hi/lo
    __shared__ float muL[64], rhoL[64], b1L[128], b2L[64];
    int t = threadIdx.x;
    int h = blockIdx.x, b = blockIdx.y;
    int l = t & 63, wv = t >> 6;

    const unsigned short* xu = (const unsigned short*)(ws + OFF_X);
    const unsigned short* w1hG = xu;
    const unsigned short* w2hG = xu + 16384;
    const unsigned short* MhG  = xu + 32768, *MlG  = xu + 36864;

    for (int ch = t; ch < 1024; ch += 256) {       // w1: rows j, stride 128B
        int j = ch >> 3, c0 = (ch & 7) * 8;
        unsigned off = (unsigned)(j*128 + c0*2) ^ (unsigned)((j & 7) << 4);
        *(bfrag*)((char*)w1hS + off) = *(const bfrag*)(w1hG + ch*8);
    }
    for (int ch = t; ch < 1024; ch += 256) {       // w2: rows o, stride 256B
        int o = ch >> 4, j0 = (ch & 15) * 8;
        unsigned off = (unsigned)(o*256 + j0*2) ^ (unsigned)((o & 15) << 4);
        *(bfrag*)((char*)w2hS + off) = *(const bfrag*)(w2hG + ch*8);
    }
    const float* Qp = ws + OFF_PQ + (long)(b*128 + h)*2048;
    for (int i = t; i < 2048; i += 256) {
        int k = i & 31, c = i >> 5;
        float v = Qp[(k >> 1)*128 + c*2 + (k & 1)];
        unsigned short hi, lo; split2(v, hi, lo);
        qhS[c*40 + k] = hi; qlS[c*40 + k] = lo;
    }
    if (t < 64) {
        float s1 = ws[OFF_S2 + (b*64+t)*2], s2 = ws[OFF_S2 + (b*64+t)*2 + 1];
        float m = s1 * (1.f/16384.f);
        float v = s2 * (1.f/16384.f) - m*m;
        muL[t] = m; rhoL[t] = rsqrtf(v + 1e-5f);
        b2L[t] = mb2[t];
    }
    if (t >= 64 && t < 192) b1L[t - 64] = mb1[t - 64];
    bfrag ma_h[2], ma_l[2];
    #pragma unroll
    for (int q = 0; q < 2; q++) {
        int w = (wv + 4*q)*16 + (l & 15);
        ma_h[q] = *(const bfrag*)(MhG + w*32 + (l >> 4)*8);
        ma_l[q] = *(const bfrag*)(MlG + w*32 + (l >> 4)*8);
    }
    __syncthreads();   // cross-wave staging -- the ONLY barrier needed

    #pragma unroll
    for (int q = 0; q < 2; q++) {
        int wt = wv + 4*q;
        #pragma unroll
        for (int ct = 0; ct < 4; ct++) {
            unsigned ro = (unsigned)((ct*16 + (l & 15))*80 + (l >> 4)*16);
            bfrag bh = *(const bfrag*)((const char*)qhS + ro);
            bfrag bl = *(const bfrag*)((const char*)qlS + ro);
            f4v acc = {0.f, 0.f, 0.f, 0.f};
            acc = MFMA(ma_h[q], bh, acc);
            acc = MFMA(ma_h[q], bl, acc);
            acc = MFMA(ma_l[q], bh, acc);
            int c = ct*16 + (l & 15);
            float mu_ = muL[c], rh_ = rhoL[c];
            #pragma unroll
            for (int r = 0; r < 4; r++) {
                int w = wt*16 + (l >> 4)*4 + r;
                float z = (acc[r] - mu_) * rh_;
                unsigned off = (unsigned)(w*128 + c*2) ^ (unsigned)((w & 7) << 4);
                *(unsigned short*)((char*)zhS + off) = f2bf_rn(z);
            }
        }
    }

    bfrag za[2][2];
    #pragma unroll
    for (int q = 0; q < 2; q++) {
        int w = (wv + 4*q)*16 + (l & 15);
        #pragma unroll
        for (int ks = 0; ks < 2; ks++) {
            unsigned off = (unsigned)(w*128 + (ks*32 + (l >> 4)*8)*2) ^ (unsigned)((w & 7) << 4);
            za[q][ks] = *(const bfrag*)((const char*)zhS + off);
        }
    }
    f4v accO[2][4];
    #pragma unroll
    for (int q = 0; q < 2; q++)
        #pragma unroll
        for (int ot = 0; ot < 4; ot++) accO[q][ot] = (f4v){0.f,0.f,0.f,0.f};

    #pragma unroll
    for (int jh = 0; jh < 2; jh++) {
        #pragma unroll
        for (int q = 0; q < 2; q++) {
            int wt = wv + 4*q;
            #pragma unroll
            for (int jt = 0; jt < 4; jt++) {
                int j = jh*64 + jt*16 + (l & 15);
                f4v acc = {0.f, 0.f, 0.f, 0.f};
                #pragma unroll
                for (int ks = 0; ks < 2; ks++) {
                    unsigned off = (unsigned)(j*128 + (ks*32 + (l >> 4)*8)*2) ^ (unsigned)((j & 7) << 4);
                    bfrag bh = *(const bfrag*)((const char*)w1hS + off);
                    acc = MFMA(za[q][ks], bh, acc);
                }
                float bj = b1L[j];
                #pragma unroll
                for (int r = 0; r < 4; r++) {
                    int w = wt*16 + (l >> 4)*4 + r;
                    float hv = gelu_t(acc[r] + bj);
                    int jl = jt*16 + (l & 15);
                    unsigned off = (unsigned)(w*128 + jl*2) ^ (unsigned)((w & 7) << 4);
                    *(unsigned short*)((char*)hhS + off) = f2bf_rn(hv);
                }
            }
        }
        #pragma unroll
        for (int q = 0; q < 2; q++) {
            int w = (wv + 4*q)*16 + (l & 15);
            bfrag ha[2];
            #pragma unroll
            for (int ks = 0; ks < 2; ks++) {
                unsigned off = (unsigned)(w*128 + (ks*32 + (l >> 4)*8)*2) ^ (unsigned)((w & 7) << 4);
                ha[ks] = *(const bfrag*)((const char*)hhS + off);
            }
            #pragma unroll
            for (int ot = 0; ot < 4; ot++) {
                int o = ot*16 + (l & 15);
                f4v acc = accO[q][ot];
                #pragma unroll
                for (int ks = 0; ks < 2; ks++) {
                    int jj = jh*64 + ks*32 + (l >> 4)*8;
                    unsigned off = (unsigned)(o*256 + jj*2) ^ (unsigned)((o & 15) << 4);
                    bfrag bh = *(const bfrag*)((const char*)w2hS + off);
                    acc = MFMA(ha[ks], bh, acc);
                }
                accO[q][ot] = acc;
            }
        }
    }
    #pragma unroll
    for (int q = 0; q < 2; q++) {
        int wt = wv + 4*q;
        #pragma unroll
        for (int ot = 0; ot < 4; ot++) {
            int o = ot*16 + (l & 15);
            float bo = b2L[o];
            #pragma unroll
            for (int r = 0; r < 4; r++) {
                int w = wt*16 + (l >> 4)*4 + r;
                out[((long)(b*128 + h)*128 + w)*64 + o] = accO[q][ot][r] + bo;
            }
        }
    }
}

extern "C" void kernel_launch(void* const* d_in, const int* in_sizes, int n_in,
                              void* d_out, int out_size, void* d_ws, size_t ws_size,
                              hipStream_t stream) {
    const float* x   = (const float*)d_in[0];
    const float* w1r = (const float*)d_in[1];
    const float* w1i = (const float*)d_in[2];
    const float* w2r = (const float*)d_in[3];
    const float* w2i = (const float*)d_in[4];
    const float* mw1 = (const float*)d_in[5];
    const float* mb1 = (const float*)d_in[6];
    const float* mw2 = (const float*)d_in[7];
    const float* mb2 = (const float*)d_in[8];
    float* ws  = (float*)d_ws;
    float* out = (float*)d_out;

    k_init  <<<dim3(49),      dim3(256), 0, stream>>>(ws);
    k_trans <<<dim3(64,2),    dim3(256), 0, stream>>>(w1r, w1i, w2r, w2i, ws);
    k_dftw  <<<dim3(32,16),   dim3(256), 0, stream>>>(x, ws);   // direct x read; stats folded
    k_dfth  <<<dim3(16,16),   dim3(256), 0, stream>>>(ws);
    k_mix   <<<dim3(512),     dim3(256), 0, stream>>>(ws);
    k_wmlp  <<<dim3(80),      dim3(256), 0, stream>>>(mw1, mw2, ws);  // X dead after k_mix
    k_pstats<<<dim3(16,4),    dim3(256), 0, stream>>>(ws);
    k_idfth <<<dim3(16,16),   dim3(256), 0, stream>>>(ws);
    k_mlp   <<<dim3(128,16),  dim3(256), 0, stream>>>(mb1, mb2, out, ws);
}

// Round 16
// 203.061 us; speedup vs baseline: 1.2650x; 1.0372x over previous
//
#include <hip/hip_runtime.h>
#include <math.h>

// Problem constants: B=16, H=W=128, C=64, M1=M2=16
// Workspace layout (float offsets):
#define OFF_TBL 0u            // 128 x {cos,sin}(2*pi*m/128)          (256)
#define OFF_S1  256u          // instance-norm-1 raw sums [b*64+c][2] (2048)
#define OFF_S2  2304u         // instance-norm-2 stats (s1,s2)        (2048)
#define OFF_PQ  4352u         // PT2[b][hp32][ky16][c64][ri2][h4] u32 bf16 hi|lo (4194304)
                              //   aliased later with Q[b][h][ky][o][2] f32
#define OFF_X   4198656u      // X[b][kx][ky][c][2] f32               (1048576)
#define OFF_O   5247232u      // Out[b][kx][ky][o][2] f32             (1048576)
                              //   head doubles (pre-mix) as u16 trig tables:
                              //   FdAh[32][128] @0, FdAl @4096, EdAh[64][128] @8192, EdAl @16384
#define OFF_WT  6295808u      // WT[mode][i][o][2]                    (4194304)
// total = 10490112 floats = 41.96 MB
// X region is dead after k_mix -> reuse as u16 arrays for bf16-split MLP weights:
//   u16[0..8192) w1hi   [8192..16384) w1lo   [16384..24576) w2hi
//   [24576..32768) w2lo  [32768..36864) Mhi  [36864..40960) Mlo

typedef __attribute__((ext_vector_type(8))) short bfrag;
typedef __attribute__((ext_vector_type(4))) float f4v;
#define MFMA(A,B,C) __builtin_amdgcn_mfma_f32_16x16x32_bf16(A,B,C,0,0,0)

// compile-time float4 component select -- NO address-taken indexing (scratch hazard)
#define F4GET(v, i) ((i)==0 ? (v).x : (i)==1 ? (v).y : (i)==2 ? (v).z : (v).w)

__device__ __forceinline__ unsigned short f2bf_rn(float x) {
    unsigned u = __float_as_uint(x);
    unsigned r = u + 0x7FFFu + ((u >> 16) & 1u);
    return (unsigned short)(r >> 16);
}
__device__ __forceinline__ float bf2f(unsigned short h) {
    return __uint_as_float(((unsigned)h) << 16);
}
__device__ __forceinline__ void split2(float x, unsigned short& hi, unsigned short& lo) {
    hi = f2bf_rn(x);
    lo = f2bf_rn(x - bf2f(hi));
}
// tanh-form GELU; matches exact GELU to <1e-5 for |x| <= 0.5 (our range)
__device__ __forceinline__ float gelu_t(float x) {
    float u = 0.79788456080286536f * (x + 0.044715f * x * x * x);
    float e = __expf(2.f * u);
    float th = 1.f - 2.f / (e + 1.f);
    return 0.5f * x * (1.f + th);
}

// block 0: twiddle table + zero S1/S2. blocks 1..48: bf16-split trig tables
// (F for dftw, E for dfth) into the O region (dead until k_mix overwrites).
__global__ void k_init(float* __restrict__ ws) {
    int t = threadIdx.x, bid = blockIdx.x;
    if (bid == 0) {
        if (t < 128) {
            double ang = 6.283185307179586476925286766559 * (double)t / 128.0;
            ws[OFF_TBL + 2*t]     = (float)cos(ang);
            ws[OFF_TBL + 2*t + 1] = (float)sin(ang);
        }
        for (int i = t; i < 4096; i += 256) ws[OFF_S1 + i] = 0.f;
        return;
    }
    int e = (bid - 1)*256 + t;   // 0..12287
    unsigned short* OU = (unsigned short*)(ws + OFF_O);
    const double TWO_PI = 6.283185307179586476925286766559;
    if (e < 4096) {              // FdA[row=ri*16+ky][w]: re rows cos, im rows -sin
        int row = e >> 7, w = e & 127, ky = row & 15;
        double ang = TWO_PI * (double)((ky * w) & 127) / 128.0;
        double v = (row < 16) ? cos(ang) : -sin(ang);
        unsigned short hi, lo; split2((float)v, hi, lo);
        OU[e] = hi; OU[4096 + e] = lo;
    } else {                     // EdA[row=2kx+s][h]: s=0 cos, s=1 sin (of freq f(kx))
        int e2 = e - 4096, row = e2 >> 7, h = e2 & 127;
        int kx = row >> 1, f = kx < 16 ? kx : 96 + kx;
        double ang = TWO_PI * (double)((f * h) & 127) / 128.0;
        double v = (row & 1) ? sin(ang) : cos(ang);
        unsigned short hi, lo; split2((float)v, hi, lo);
        OU[8192 + e2] = hi; OU[16384 + e2] = lo;
    }
}

// weight transpose: [i][o][kx][ky] (x4 arrays) -> WT[mode][i][o][{re,im}]. grid (64=i, 2=part)
__global__ void k_trans(const float* __restrict__ w1r, const float* __restrict__ w1i,
                        const float* __restrict__ w2r, const float* __restrict__ w2i,
                        float* __restrict__ ws) {
    __shared__ float Lr[16*257], Li[16*257];
    int t = threadIdx.x;
    int i = blockIdx.x;
    int part = blockIdx.y;
    float* WT = ws + OFF_WT;
    const float* wr = part ? w2r : w1r;
    const float* wi = part ? w2i : w1i;
    for (int oc = 0; oc < 4; oc++) {
        int o0 = oc * 16;
        __syncthreads();
        for (int idx = t; idx < 4096; idx += 256) {
            int oo = idx >> 8, m = idx & 255;
            Lr[oo*257 + m] = wr[(i*64 + o0 + oo)*256 + m];
            Li[oo*257 + m] = wi[(i*64 + o0 + oo)*256 + m];
        }
        __syncthreads();
        for (int idx = t; idx < 8192; idx += 256) {
            int mode = idx >> 5, rem = idx & 31, oo = rem >> 1, ri = rem & 1;
            float val = ri ? Li[oo*257 + mode] : Lr[oo*257 + mode];
            int gm = part*256 + mode;
            WT[((gm*64 + i)*64 + (o0 + oo))*2 + ri] = val;
        }
    }
}

// bf16-split MLP weights + iDFT-w matrix M into the dead X region. grid 80
__global__ void k_wmlp(const float* __restrict__ mw1, const float* __restrict__ mw2,
                       float* __restrict__ ws) {
    int i = blockIdx.x * 256 + threadIdx.x;   // [0, 20480)
    unsigned short* xu = (unsigned short*)(ws + OFF_X);
    if (i < 8192) {
        unsigned short hi, lo; split2(mw1[i], hi, lo);
        xu[i] = hi; xu[8192 + i] = lo;
    } else if (i < 16384) {
        int k = i - 8192;
        unsigned short hi, lo; split2(mw2[k], hi, lo);
        xu[16384 + k] = hi; xu[24576 + k] = lo;
    } else if (i < 20480) {
        int m = i - 16384;           // w*32 + k
        int w = m >> 5, k = m & 31;
        int ky = k >> 1;
        double ang = 6.283185307179586476925286766559 * (double)((ky * w) & 127) / 128.0;
        double v = (k & 1) ? -sin(ang) : cos(ang);
        double a = (ky == 0) ? 1.0 : 2.0;
        float val = (float)(v * a) * (1.f/16384.f);
        unsigned short hi, lo; split2(val, hi, lo);
        xu[32768 + m] = hi; xu[36864 + m] = lo;
    }
}

// MFMA forward DFT along w reading x DIRECTLY, x quantized to SINGLE bf16
// (lo-part dropped: error budget allows ~0.16% rel on the spectral path;
// F table keeps hi/lo, so 2-term MFMA). LDS 34KB -> 4 blocks/CU.
// grid (hp=32, b=16): block = 4 h x 64 c = 256 N-cols, K=128 w (2 chunks).
// PT2[b][hp][ky][c][ri][h4] u32(hi|lo): block writes its own 32KB contiguously.
__global__ __launch_bounds__(256) void k_dftw(const float* __restrict__ x,
                                              float* __restrict__ ws) {
    __shared__ unsigned short BshH[256*68];   // [n=hl*64+c][k 64 pad68] u16, swz k^8(n&7)
    int t = threadIdx.x;
    int hp = blockIdx.x, b = blockIdx.y;
    int l = t & 63, wv = t >> 6;
    const unsigned short* OU = (const unsigned short*)(ws + OFF_O);
    const unsigned short* FdAh = OU, *FdAl = OU + 4096;
    f4v acc[2][4];
    #pragma unroll
    for (int mt = 0; mt < 2; mt++)
        #pragma unroll
        for (int nt = 0; nt < 4; nt++) acc[mt][nt] = (f4v){0.f,0.f,0.f,0.f};

    float s1a[4] = {0,0,0,0}, s2a[4] = {0,0,0,0};   // stats for c = c4*4 + j
    int c4 = t & 15;
    const float* xb = x + ((long)(b*128 + hp*4))*8192;   // 4 h rows

    for (int kc2 = 0; kc2 < 2; kc2++) {
        __syncthreads();                    // protect Bsh from prev MFMA readers
        // ---- stage direct from x: 16-lane groups read full 256B c-lines ----
        #pragma unroll
        for (int i = 0; i < 16; i++) {
            int idx = i*256 + t;
            int hw = idx >> 4;              // 0..255: hl = hw>>6, wl = hw&63
            int hl = hw >> 6, wl = hw & 63;
            float4 v = *(const float4*)(xb + ((long)hl*8192) + (kc2*64 + wl)*64 + c4*4);
            #pragma unroll
            for (int j = 0; j < 4; j++) {
                float f = F4GET(v, j);
                s1a[j] += f;
                s2a[j] += f*f;
                int n = hl*64 + c4*4 + j;
                unsigned ku = (unsigned)(wl ^ (8*(n & 7)));
                BshH[n*68 + ku] = f2bf_rn(f);       // single-bf16 x
            }
        }
        __syncthreads();
        // ---- MFMA: 4 Ntiles x 2 Mtiles, 2-term (F hi/lo x bf16 x) ----
        #pragma unroll
        for (int kcl = 0; kcl < 2; kcl++) {
            int kglob = kc2*64 + kcl*32 + (l >> 4)*8;
            bfrag mah[2], mal[2];
            #pragma unroll
            for (int mt = 0; mt < 2; mt++) {
                int row = mt*16 + (l & 15);
                mah[mt] = *(const bfrag*)(FdAh + row*128 + kglob);
                mal[mt] = *(const bfrag*)(FdAl + row*128 + kglob);
            }
            #pragma unroll
            for (int nt = 0; nt < 4; nt++) {
                int n = wv*64 + nt*16 + (l & 15);
                int kl = kcl*32 + (l >> 4)*8;
                unsigned ku = (unsigned)(kl ^ (8*(n & 7)));
                bfrag bh = *(const bfrag*)(BshH + n*68 + ku);
                #pragma unroll
                for (int mt = 0; mt < 2; mt++) {
                    f4v a_ = acc[mt][nt];
                    a_ = MFMA(mah[mt], bh, a_);
                    a_ = MFMA(mal[mt], bh, a_);
                    acc[mt][nt] = a_;
                }
            }
        }
    }
    // ---- stats reduce (lanes l, l+16, l+32, l+48 share c4) + atomics ----
    #pragma unroll
    for (int j = 0; j < 4; j++) {
        s1a[j] += __shfl_down(s1a[j], 16, 64);
        s1a[j] += __shfl_down(s1a[j], 32, 64);
        s2a[j] += __shfl_down(s2a[j], 16, 64);
        s2a[j] += __shfl_down(s2a[j], 32, 64);
    }
    if (l < 16) {
        #pragma unroll
        for (int j = 0; j < 4; j++) {
            int c = c4*4 + j;
            atomicAdd(&ws[OFF_S1 + (b*64 + c)*2],     s1a[j]);
            atomicAdd(&ws[OFF_S1 + (b*64 + c)*2 + 1], s2a[j]);
        }
    }
    // ---- epilogue: pack -> TB (alias BshH), then block-contiguous PT2 write ----
    __syncthreads();
    unsigned* TB = (unsigned*)BshH;   // TB[ky][c*2+ri][h4], word stride 520 per ky
    #pragma unroll
    for (int mt = 0; mt < 2; mt++)
        #pragma unroll
        for (int nt = 0; nt < 4; nt++)
            #pragma unroll
            for (int rr = 0; rr < 4; rr++) {
                float v = acc[mt][nt][rr];
                unsigned short hi, lo; split2(v, hi, lo);
                int trow = mt*16 + (l >> 4)*4 + rr;
                int ri = trow >> 4, ky = trow & 15;
                int c = nt*16 + (l & 15);
                TB[ky*520 + (c*2 + ri)*4 + wv] = ((unsigned)hi << 16) | lo;
            }
    __syncthreads();
    unsigned* PTb = (unsigned*)(ws + OFF_PQ) + ((long)(b*32 + hp))*8192;
    #pragma unroll
    for (int i = 0; i < 8; i++) {
        int idx = i*256 + t;
        int ky = idx >> 7, m = idx & 127;
        ((uint4*)PTb)[idx] = *(const uint4*)(TB + ky*520 + m*4);
    }
}

// MFMA forward DFT along h: X[2kx+s][(c,ri)] = EdA @ PT2 (per ky,b).
// Staging reads 2KB contiguous runs per (hp,ky). grid (ky=16, b=16).
__global__ __launch_bounds__(256) void k_dfth(float* __restrict__ ws) {
    __shared__ unsigned Bsh[16384];   // BTh 32KB (128 cols x 256B) | BTl 32KB
    int t = threadIdx.x;
    int ky = blockIdx.x, b = blockIdx.y;
    int l = t & 63, wv = t >> 6;
    char* bh_base = (char*)Bsh;
    char* bl_base = bh_base + 32768;
    const uint4* PT4 = (const uint4*)((const unsigned*)(ws + OFF_PQ));
    const unsigned short* OU = (const unsigned short*)(ws + OFF_O);
    const unsigned short* EdAh = OU + 8192, *EdAl = OU + 16384;

    // ---- stage PT2: for (hp, n=(c,ri)) read uint4 (4 h), unpack -> BT[n][128 kk] ----
    #pragma unroll
    for (int i = 0; i < 16; i++) {
        int idx = i*256 + t;
        int hp = idx >> 7, n = idx & 127;
        uint4 v = PT4[((long)(b*32 + hp)*16 + ky)*128 + n];
        unsigned h01 = (v.x >> 16) | (v.y & 0xFFFF0000u);
        unsigned h23 = (v.z >> 16) | (v.w & 0xFFFF0000u);
        unsigned l01 = (v.x & 0xFFFFu) | (v.y << 16);
        unsigned l23 = (v.z & 0xFFFFu) | (v.w << 16);
        int kk = hp*4;
        unsigned ad = (unsigned)(n*256 + ((kk*2) ^ ((n & 7) << 4)));
        *(uint2*)(bh_base + ad) = make_uint2(h01, h23);
        *(uint2*)(bl_base + ad) = make_uint2(l01, l23);
    }
    // A-frags for this wave's Mtile
    bfrag ea_h[4], ea_l[4];
    #pragma unroll
    for (int kc = 0; kc < 4; kc++) {
        int off = (wv*16 + (l & 15))*128 + kc*32 + (l >> 4)*8;
        ea_h[kc] = *(const bfrag*)(EdAh + off);
        ea_l[kc] = *(const bfrag*)(EdAl + off);
    }
    __syncthreads();
    f4v acc[8];
    #pragma unroll
    for (int nt = 0; nt < 8; nt++) acc[nt] = (f4v){0.f,0.f,0.f,0.f};
    #pragma unroll
    for (int kc = 0; kc < 4; kc++)
        #pragma unroll
        for (int nt = 0; nt < 8; nt++) {
            int col = nt*16 + (l & 15);
            unsigned ro = (unsigned)(col*256 + ((kc*64 + (l >> 4)*16) ^ ((col & 7) << 4)));
            bfrag bh = *(const bfrag*)(bh_base + ro);
            bfrag bl = *(const bfrag*)(bl_base + ro);
            acc[nt] = MFMA(ea_h[kc], bh, acc[nt]);
            acc[nt] = MFMA(ea_h[kc], bl, acc[nt]);
            acc[nt] = MFMA(ea_l[kc], bh, acc[nt]);
        }
    // ---- epilogue: complex combine + store X (f32, legacy layout) ----
    float* X = ws + OFF_X;
    #pragma unroll
    for (int nt = 0; nt < 8; nt++)
        #pragma unroll
        for (int p = 0; p < 2; p++) {
            float s0 = acc[nt][2*p], s1 = acc[nt][2*p + 1];
            float partner = __shfl_xor(s1, 1, 64);
            float res = (l & 1) ? (s0 - partner) : (s0 + partner);
            int kx = wv*8 + (l >> 4)*2 + p;
            X[(((long)b*32 + kx)*16 + ky)*128 + nt*16 + (l & 15)] = res;
        }
}

// per-mode complex mix with rho1 scaling folded into X staging. grid 512 (=mode)
__global__ void k_mix(float* __restrict__ ws) {
    __shared__ float Wsh[8192];
    __shared__ float Xs[2048];
    __shared__ float rhoT[1024];
    int t = threadIdx.x;
    int mode = blockIdx.x;
    int kxI = mode >> 4, ky = mode & 15;
    const float* WT = ws + OFF_WT;
    const float* X = ws + OFF_X;
    float* O = ws + OFF_O;
    for (int i = t; i < 1024; i += 256) {
        float a = ws[OFF_S1 + 2*i], s = ws[OFF_S1 + 2*i + 1];
        float m = a * (1.f/16384.f);
        float v = s * (1.f/16384.f) - m*m;
        rhoT[i] = rsqrtf(v + 1e-5f);
    }
    for (int idx = t; idx < 8192; idx += 256) Wsh[idx] = WT[(long)mode*8192 + idx];
    __syncthreads();
    for (int idx = t; idx < 2048; idx += 256) {
        int b = idx >> 7, r = idx & 127;
        Xs[idx] = X[((b*32 + kxI)*16 + ky)*128 + r] * rhoT[b*64 + (r >> 1)];
    }
    __syncthreads();
    int o = t & 63, bg = t >> 6;
    float accr[4] = {0,0,0,0}, acci[4] = {0,0,0,0};
    for (int i = 0; i < 64; i++) {
        float wr = Wsh[(i*64 + o)*2], wi = Wsh[(i*64 + o)*2 + 1];
        #pragma unroll
        for (int j = 0; j < 4; j++) {
            float xr = Xs[(bg*4 + j)*128 + 2*i], xi = Xs[(bg*4 + j)*128 + 2*i + 1];
            accr[j] += xr*wr - xi*wi;
            acci[j] += xr*wi + xi*wr;
        }
    }
    #pragma unroll
    for (int j = 0; j < 4; j++) {
        int b = bg*4 + j;
        float2* dst = (float2*)(O + ((b*32 + kxI)*16 + ky)*128);
        dst[o] = make_float2(accr[j], acci[j]);
    }
}

// Parseval stats of y directly from O. grid (16=b, 4=gg), 256 thr.
__global__ void k_pstats(float* __restrict__ ws) {
    __shared__ float red[256];
    int t = threadIdx.x, b = blockIdx.x, gg = blockIdx.y;
    int c = t & 63, g = t >> 6;
    const float* O = ws + OFF_O + (long)b*65536;   // [(kxI*16+ky)*128 + 2c]
    float t0 = 0.f, t2 = 0.f;
    int k0 = gg*8 + g*2;
    for (int kxI = k0; kxI < k0 + 2; kxI++)
        for (int ky = 0; ky < 16; ky++) {
            float re = O[(kxI*16 + ky)*128 + 2*c];
            float im = O[(kxI*16 + ky)*128 + 2*c + 1];
            float p = re*re + im*im;
            if (ky == 0) t0 += p; else t2 += p;
        }
    float s2p = 0.5f*t0 + 2.f*t2;
    if (gg == 0 && g == 0) {
        float ar = O[2*c], ai = O[2*c + 1];        // kxI=0, ky=0
        float t1 = ar*ar - ai*ai;
        for (int k = 1; k <= 15; k++) {
            float xr = O[(k*16)*128 + 2*c],        xi = O[(k*16)*128 + 2*c + 1];
            float yr = O[((32-k)*16)*128 + 2*c],   yi = O[((32-k)*16)*128 + 2*c + 1];
            t1 += 2.f*(xr*yr - xi*yi);
        }
        s2p += 0.5f*t1;
        ws[OFF_S2 + (b*64 + c)*2] = ar;            // s1 (mean term)
    }
    red[t] = s2p;
    __syncthreads();
    if (t < 64) {
        float s = red[t] + red[t+64] + red[t+128] + red[t+192];
        atomicAdd(&ws[OFF_S2 + (b*64 + t)*2 + 1], s * (1.f/16384.f));
    }
}

// inverse DFT along h: Q[b][h][ky][o] = sum_kx Out e^{+i 2pi f(kx) h/128}. grid (hg=16,b=16)
__global__ void k_idfth(float* __restrict__ ws) {
    __shared__ float Os[8192];
    __shared__ float tblL[256];
    int t = threadIdx.x;
    int hg = blockIdx.x, b = blockIdx.y;
    for (int i = t; i < 256; i += 256) tblL[i] = ws[OFF_TBL + i];
    const float* O = ws + OFF_O;
    float* Q = ws + OFF_PQ;
    int o = t & 63, kyg = t >> 6;
    float accr[4][8], acci[4][8];
    #pragma unroll
    for (int kk = 0; kk < 4; kk++)
        #pragma unroll
        for (int h = 0; h < 8; h++) { accr[kk][h] = 0.f; acci[kk][h] = 0.f; }
    for (int kc = 0; kc < 8; kc++) {
        __syncthreads();
        for (int idx = t; idx < 8192; idx += 256) Os[idx] = O[(long)b*65536 + kc*8192 + idx];
        __syncthreads();
        for (int k4 = 0; k4 < 4; k4++) {
            int kxI = kc*4 + k4;
            int freq = kxI < 16 ? kxI : 96 + kxI;
            float vr[4], vi[4];
            #pragma unroll
            for (int kk = 0; kk < 4; kk++) {
                int ky = kyg*4 + kk;
                vr[kk] = Os[((k4*16 + ky)*64 + o)*2];
                vi[kk] = Os[((k4*16 + ky)*64 + o)*2 + 1];
            }
            for (int h = 0; h < 8; h++) {
                int habs = hg*8 + h;
                int m = (freq * habs) & 127;
                float cs = tblL[2*m], sn = tblL[2*m + 1];
                #pragma unroll
                for (int kk = 0; kk < 4; kk++) {
                    accr[kk][h] += vr[kk]*cs - vi[kk]*sn;   // * e^{+i th}
                    acci[kk][h] += vr[kk]*sn + vi[kk]*cs;
                }
            }
        }
    }
    #pragma unroll
    for (int kk = 0; kk < 4; kk++)
        #pragma unroll
        for (int h = 0; h < 8; h++) {
            int ky = kyg*4 + kk, habs = hg*8 + h;
            float2* dst = (float2*)(Q + ((long)(b*128 + habs)*16 + ky)*128);
            dst[o] = make_float2(accr[kk][h], acci[kk][h]);
        }
}

// fused MFMA kernel: Y = M@Qm (iDFT-w), z = (Y-mu)*rho, h = GELU(z@W1+b1),
// out = h@W2+b2. zhS/hhS rows are wave-private -> single staging barrier.
// grid (h=128,b=16).
__global__ __launch_bounds__(256, 2) void k_mlp(const float* __restrict__ mb1,
                      const float* __restrict__ mb2,
                      float* __restrict__ out, const float* __restrict__ ws) {
    __shared__ unsigned short zhS[8192];                // z[w][64c], swz (w&7)<<4
    __shared__ unsigned short w1hS[8192];               // w1[j][64c], swz (j&7)<<4
    __shared__ unsigned short w2hS[8192];               // w2[o][128j], swz (o&15)<<4
    __shared__ unsigned short hhS[8192];                // h-half [w][64jl], swz (w&7)<<4
    __shared__ unsigned short qhS[2560], qlS[2560];     // QmT[c][40k] hi/lo
    __shared__ float muL[64], rhoL[64], b1L[128], b2L[64];
    int t = threadIdx.x;
    int h = blockIdx.x, b = blockIdx.y;
    int l = t & 63, wv = t >> 6;

    const unsigned short* xu = (const unsigned short*)(ws + OFF_X);
    const unsigned short* w1hG = xu;
    const unsigned short* w2hG = xu + 16384;
    const unsigned short* MhG  = xu + 32768, *MlG  = xu + 36864;

    for (int ch = t; ch < 1024; ch += 256) {       // w1: rows j, stride 128B
        int j = ch >> 3, c0 = (ch & 7) * 8;
        unsigned off = (unsigned)(j*128 + c0*2) ^ (unsigned)((j & 7) << 4);
        *(bfrag*)((char*)w1hS + off) = *(const bfrag*)(w1hG + ch*8);
    }
    for (int ch = t; ch < 1024; ch += 256) {       // w2: rows o, stride 256B
        int o = ch >> 4, j0 = (ch & 15) * 8;
        unsigned off = (unsigned)(o*256 + j0*2) ^ (unsigned)((o & 15) << 4);
        *(bfrag*)((char*)w2hS + off) = *(const bfrag*)(w2hG + ch*8);
    }
    const float* Qp = ws + OFF_PQ + (long)(b*128 + h)*2048;
    for (int i = t; i < 2048; i += 256) {
        int k = i & 31, c = i >> 5;
        float v = Qp[(k >> 1)*128 + c*2 + (k & 1)];
        unsigned short hi, lo; split2(v, hi, lo);
        qhS[c*40 + k] = hi; qlS[c*40 + k] = lo;
    }
    if (t < 64) {
        float s1 = ws[OFF_S2 + (b*64+t)*2], s2 = ws[OFF_S2 + (b*64+t)*2 + 1];
        float m = s1 * (1.f/16384.f);
        float v = s2 * (1.f/16384.f) - m*m;
        muL[t] = m; rhoL[t] = rsqrtf(v + 1e-5f);
        b2L[t] = mb2[t];
    }
    if (t >= 64 && t < 192) b1L[t - 64] = mb1[t - 64];
    bfrag ma_h[2], ma_l[2];
    #pragma unroll
    for (int q = 0; q < 2; q++) {
        int w = (wv + 4*q)*16 + (l & 15);
        ma_h[q] = *(const bfrag*)(MhG + w*32 + (l >> 4)*8);
        ma_l[q] = *(const bfrag*)(MlG + w*32 + (l >> 4)*8);
    }
    __syncthreads();   // cross-wave staging -- the ONLY barrier needed

    #pragma unroll
    for (int q = 0; q < 2; q++) {
        int wt = wv + 4*q;
        #pragma unroll
        for (int ct = 0; ct < 4; ct++) {
            unsigned ro = (unsigned)((ct*16 + (l & 15))*80 + (l >> 4)*16);
            bfrag bh = *(const bfrag*)((const char*)qhS + ro);
            bfrag bl = *(const bfrag*)((const char*)qlS + ro);
            f4v acc = {0.f, 0.f, 0.f, 0.f};
            acc = MFMA(ma_h[q], bh, acc);
            acc = MFMA(ma_h[q], bl, acc);
            acc = MFMA(ma_l[q], bh, acc);
            int c = ct*16 + (l & 15);
            float mu_ = muL[c], rh_ = rhoL[c];
            #pragma unroll
            for (int r = 0; r < 4; r++) {
                int w = wt*16 + (l >> 4)*4 + r;
                float z = (acc[r] - mu_) * rh_;
                unsigned off = (unsigned)(w*128 + c*2) ^ (unsigned)((w & 7) << 4);
                *(unsigned short*)((char*)zhS + off) = f2bf_rn(z);
            }
        }
    }

    bfrag za[2][2];
    #pragma unroll
    for (int q = 0; q < 2; q++) {
        int w = (wv + 4*q)*16 + (l & 15);
        #pragma unroll
        for (int ks = 0; ks < 2; ks++) {
            unsigned off = (unsigned)(w*128 + (ks*32 + (l >> 4)*8)*2) ^ (unsigned)((w & 7) << 4);
            za[q][ks] = *(const bfrag*)((const char*)zhS + off);
        }
    }
    f4v accO[2][4];
    #pragma unroll
    for (int q = 0; q < 2; q++)
        #pragma unroll
        for (int ot = 0; ot < 4; ot++) accO[q][ot] = (f4v){0.f,0.f,0.f,0.f};

    #pragma unroll
    for (int jh = 0; jh < 2; jh++) {
        #pragma unroll
        for (int q = 0; q < 2; q++) {
            int wt = wv + 4*q;
            #pragma unroll
            for (int jt = 0; jt < 4; jt++) {
                int j = jh*64 + jt*16 + (l & 15);
                f4v acc = {0.f, 0.f, 0.f, 0.f};
                #pragma unroll
                for (int ks = 0; ks < 2; ks++) {
                    unsigned off = (unsigned)(j*128 + (ks*32 + (l >> 4)*8)*2) ^ (unsigned)((j & 7) << 4);
                    bfrag bh = *(const bfrag*)((const char*)w1hS + off);
                    acc = MFMA(za[q][ks], bh, acc);
                }
                float bj = b1L[j];
                #pragma unroll
                for (int r = 0; r < 4; r++) {
                    int w = wt*16 + (l >> 4)*4 + r;
                    float hv = gelu_t(acc[r] + bj);
                    int jl = jt*16 + (l & 15);
                    unsigned off = (unsigned)(w*128 + jl*2) ^ (unsigned)((w & 7) << 4);
                    *(unsigned short*)((char*)hhS + off) = f2bf_rn(hv);
                }
            }
        }
        #pragma unroll
        for (int q = 0; q < 2; q++) {
            int w = (wv + 4*q)*16 + (l & 15);
            bfrag ha[2];
            #pragma unroll
            for (int ks = 0; ks < 2; ks++) {
                unsigned off = (unsigned)(w*128 + (ks*32 + (l >> 4)*8)*2) ^ (unsigned)((w & 7) << 4);
                ha[ks] = *(const bfrag*)((const char*)hhS + off);
            }
            #pragma unroll
            for (int ot = 0; ot < 4; ot++) {
                int o = ot*16 + (l & 15);
                f4v acc = accO[q][ot];
                #pragma unroll
                for (int ks = 0; ks < 2; ks++) {
                    int jj = jh*64 + ks*32 + (l >> 4)*8;
                    unsigned off = (unsigned)(o*256 + jj*2) ^ (unsigned)((o & 15) << 4);
                    bfrag bh = *(const bfrag*)((const char*)w2hS + off);
                    acc = MFMA(ha[ks], bh, acc);
                }
                accO[q][ot] = acc;
            }
        }
    }
    #pragma unroll
    for (int q = 0; q < 2; q++) {
        int wt = wv + 4*q;
        #pragma unroll
        for (int ot = 0; ot < 4; ot++) {
            int o = ot*16 + (l & 15);
            float bo = b2L[o];
            #pragma unroll
            for (int r = 0; r < 4; r++) {
                int w = wt*16 + (l >> 4)*4 + r;
                out[((long)(b*128 + h)*128 + w)*64 + o] = accO[q][ot][r] + bo;
            }
        }
    }
}

extern "C" void kernel_launch(void* const* d_in, const int* in_sizes, int n_in,
                              void* d_out, int out_size, void* d_ws, size_t ws_size,
                              hipStream_t stream) {
    const float* x   = (const float*)d_in[0];
    const float* w1r = (const float*)d_in[1];
    const float* w1i = (const float*)d_in[2];
    const float* w2r = (const float*)d_in[3];
    const float* w2i = (const float*)d_in[4];
    const float* mw1 = (const float*)d_in[5];
    const float* mb1 = (const float*)d_in[6];
    const float* mw2 = (const float*)d_in[7];
    const float* mb2 = (const float*)d_in[8];
    float* ws  = (float*)d_ws;
    float* out = (float*)d_out;

    k_init  <<<dim3(49),      dim3(256), 0, stream>>>(ws);
    k_trans <<<dim3(64,2),    dim3(256), 0, stream>>>(w1r, w1i, w2r, w2i, ws);
    k_dftw  <<<dim3(32,16),   dim3(256), 0, stream>>>(x, ws);   // direct x read; stats folded
    k_dfth  <<<dim3(16,16),   dim3(256), 0, stream>>>(ws);
    k_mix   <<<dim3(512),     dim3(256), 0, stream>>>(ws);
    k_wmlp  <<<dim3(80),      dim3(256), 0, stream>>>(mw1, mw2, ws);  // X dead after k_mix
    k_pstats<<<dim3(16,4),    dim3(256), 0, stream>>>(ws);
    k_idfth <<<dim3(16,16),   dim3(256), 0, stream>>>(ws);
    k_mlp   <<<dim3(128,16),  dim3(256), 0, stream>>>(mb1, mb2, out, ws);
}

// Round 17
// 157.186 us; speedup vs baseline: 1.6342x; 1.2919x over previous
//
#include <hip/hip_runtime.h>
#include <math.h>

// Problem constants: B=16, H=W=128, C=64, M1=M2=16
// Workspace layout (float offsets):
#define OFF_TBL 0u            // 128 x {cos,sin}(2*pi*m/128)          (256)
#define OFF_S1  256u          // instance-norm-1 raw sums [b*64+c][2] (2048)
#define OFF_S2  2304u         // instance-norm-2 stats (s1,s2)        (2048)
#define OFF_PQ  4352u         // PT2[b][hp32][ky16][c64][ri2][h4] u32 bf16 hi|lo (4194304)
                              //   aliased later with Q[b][h][ky][o][2] f32
#define OFF_X   4198656u      // X[b][kx][ky][c][2] f32               (1048576)
#define OFF_O   5247232u      // Out[b][kx][ky][o][2] f32             (1048576)
                              //   head doubles (pre-mix) as u16 trig tables:
                              //   FdAh[32][128] @0, FdAl @4096, EdAh[64][128] @8192, EdAl @16384
#define OFF_WT  6295808u      // WT[mode][i][o][2]                    (4194304)
// total = 10490112 floats = 41.96 MB
// X region is dead after k_mix -> reuse as u16 arrays for bf16-split MLP weights:
//   u16[0..8192) w1hi   [8192..16384) w1lo   [16384..24576) w2hi
//   [24576..32768) w2lo  [32768..36864) Mhi  [36864..40960) Mlo

typedef __attribute__((ext_vector_type(8))) short bfrag;
typedef __attribute__((ext_vector_type(4))) float f4v;
#define MFMA(A,B,C) __builtin_amdgcn_mfma_f32_16x16x32_bf16(A,B,C,0,0,0)

// compile-time float4 component select -- NO address-taken indexing (scratch hazard)
#define F4GET(v, i) ((i)==0 ? (v).x : (i)==1 ? (v).y : (i)==2 ? (v).z : (v).w)

__device__ __forceinline__ unsigned short f2bf_rn(float x) {
    unsigned u = __float_as_uint(x);
    unsigned r = u + 0x7FFFu + ((u >> 16) & 1u);
    return (unsigned short)(r >> 16);
}
__device__ __forceinline__ float bf2f(unsigned short h) {
    return __uint_as_float(((unsigned)h) << 16);
}
__device__ __forceinline__ void split2(float x, unsigned short& hi, unsigned short& lo) {
    hi = f2bf_rn(x);
    lo = f2bf_rn(x - bf2f(hi));
}
// tanh-form GELU; matches exact GELU to <1e-5 for |x| <= 0.5 (our range)
__device__ __forceinline__ float gelu_t(float x) {
    float u = 0.79788456080286536f * (x + 0.044715f * x * x * x);
    float e = __expf(2.f * u);
    float th = 1.f - 2.f / (e + 1.f);
    return 0.5f * x * (1.f + th);
}

// block 0: twiddle table + zero S1/S2. blocks 1..48: bf16-split trig tables
// (F for dftw, E for dfth) into the O region (dead until k_mix overwrites).
__global__ void k_init(float* __restrict__ ws) {
    int t = threadIdx.x, bid = blockIdx.x;
    if (bid == 0) {
        if (t < 128) {
            double ang = 6.283185307179586476925286766559 * (double)t / 128.0;
            ws[OFF_TBL + 2*t]     = (float)cos(ang);
            ws[OFF_TBL + 2*t + 1] = (float)sin(ang);
        }
        for (int i = t; i < 4096; i += 256) ws[OFF_S1 + i] = 0.f;
        return;
    }
    int e = (bid - 1)*256 + t;   // 0..12287
    unsigned short* OU = (unsigned short*)(ws + OFF_O);
    const double TWO_PI = 6.283185307179586476925286766559;
    if (e < 4096) {              // FdA[row=ri*16+ky][w]: re rows cos, im rows -sin
        int row = e >> 7, w = e & 127, ky = row & 15;
        double ang = TWO_PI * (double)((ky * w) & 127) / 128.0;
        double v = (row < 16) ? cos(ang) : -sin(ang);
        unsigned short hi, lo; split2((float)v, hi, lo);
        OU[e] = hi; OU[4096 + e] = lo;
    } else {                     // EdA[row=2kx+s][h]: s=0 cos, s=1 sin (of freq f(kx))
        int e2 = e - 4096, row = e2 >> 7, h = e2 & 127;
        int kx = row >> 1, f = kx < 16 ? kx : 96 + kx;
        double ang = TWO_PI * (double)((f * h) & 127) / 128.0;
        double v = (row & 1) ? sin(ang) : cos(ang);
        unsigned short hi, lo; split2((float)v, hi, lo);
        OU[8192 + e2] = hi; OU[16384 + e2] = lo;
    }
}

// weight transpose: [i][o][kx][ky] (x4 arrays) -> WT[mode][i][o][{re,im}]. grid (64=i, 2=part)
__global__ void k_trans(const float* __restrict__ w1r, const float* __restrict__ w1i,
                        const float* __restrict__ w2r, const float* __restrict__ w2i,
                        float* __restrict__ ws) {
    __shared__ float Lr[16*257], Li[16*257];
    int t = threadIdx.x;
    int i = blockIdx.x;
    int part = blockIdx.y;
    float* WT = ws + OFF_WT;
    const float* wr = part ? w2r : w1r;
    const float* wi = part ? w2i : w1i;
    for (int oc = 0; oc < 4; oc++) {
        int o0 = oc * 16;
        __syncthreads();
        for (int idx = t; idx < 4096; idx += 256) {
            int oo = idx >> 8, m = idx & 255;
            Lr[oo*257 + m] = wr[(i*64 + o0 + oo)*256 + m];
            Li[oo*257 + m] = wi[(i*64 + o0 + oo)*256 + m];
        }
        __syncthreads();
        for (int idx = t; idx < 8192; idx += 256) {
            int mode = idx >> 5, rem = idx & 31, oo = rem >> 1, ri = rem & 1;
            float val = ri ? Li[oo*257 + mode] : Lr[oo*257 + mode];
            int gm = part*256 + mode;
            WT[((gm*64 + i)*64 + (o0 + oo))*2 + ri] = val;
        }
    }
}

// bf16-split MLP weights + iDFT-w matrix M into the dead X region. grid 80
__global__ void k_wmlp(const float* __restrict__ mw1, const float* __restrict__ mw2,
                       float* __restrict__ ws) {
    int i = blockIdx.x * 256 + threadIdx.x;   // [0, 20480)
    unsigned short* xu = (unsigned short*)(ws + OFF_X);
    if (i < 8192) {
        unsigned short hi, lo; split2(mw1[i], hi, lo);
        xu[i] = hi; xu[8192 + i] = lo;
    } else if (i < 16384) {
        int k = i - 8192;
        unsigned short hi, lo; split2(mw2[k], hi, lo);
        xu[16384 + k] = hi; xu[24576 + k] = lo;
    } else if (i < 20480) {
        int m = i - 16384;           // w*32 + k
        int w = m >> 5, k = m & 31;
        int ky = k >> 1;
        double ang = 6.283185307179586476925286766559 * (double)((ky * w) & 127) / 128.0;
        double v = (k & 1) ? -sin(ang) : cos(ang);
        double a = (ky == 0) ? 1.0 : 2.0;
        float val = (float)(v * a) * (1.f/16384.f);
        unsigned short hi, lo; split2(val, hi, lo);
        xu[32768 + m] = hi; xu[36864 + m] = lo;
    }
}

// MFMA forward DFT along w reading x DIRECTLY, x quantized to SINGLE bf16
// (lo-part dropped; F table keeps hi/lo, so 2-term MFMA). LDS 34KB.
// grid (hp=32, b=16): block = 4 h x 64 c = 256 N-cols, K=128 w (2 chunks).
// PT2[b][hp][ky][c][ri][h4] u32(hi|lo): block writes its own 32KB contiguously.
__global__ __launch_bounds__(256) void k_dftw(const float* __restrict__ x,
                                              float* __restrict__ ws) {
    __shared__ unsigned short BshH[256*68];   // [n=hl*64+c][k 64 pad68] u16, swz k^8(n&7)
    int t = threadIdx.x;
    int hp = blockIdx.x, b = blockIdx.y;
    int l = t & 63, wv = t >> 6;
    const unsigned short* OU = (const unsigned short*)(ws + OFF_O);
    const unsigned short* FdAh = OU, *FdAl = OU + 4096;
    f4v acc[2][4];
    #pragma unroll
    for (int mt = 0; mt < 2; mt++)
        #pragma unroll
        for (int nt = 0; nt < 4; nt++) acc[mt][nt] = (f4v){0.f,0.f,0.f,0.f};

    float s1a[4] = {0,0,0,0}, s2a[4] = {0,0,0,0};   // stats for c = c4*4 + j
    int c4 = t & 15;
    const float* xb = x + ((long)(b*128 + hp*4))*8192;   // 4 h rows

    for (int kc2 = 0; kc2 < 2; kc2++) {
        __syncthreads();                    // protect Bsh from prev MFMA readers
        // ---- stage direct from x: 16-lane groups read full 256B c-lines ----
        #pragma unroll
        for (int i = 0; i < 16; i++) {
            int idx = i*256 + t;
            int hw = idx >> 4;              // 0..255: hl = hw>>6, wl = hw&63
            int hl = hw >> 6, wl = hw & 63;
            float4 v = *(const float4*)(xb + ((long)hl*8192) + (kc2*64 + wl)*64 + c4*4);
            #pragma unroll
            for (int j = 0; j < 4; j++) {
                float f = F4GET(v, j);
                s1a[j] += f;
                s2a[j] += f*f;
                int n = hl*64 + c4*4 + j;
                unsigned ku = (unsigned)(wl ^ (8*(n & 7)));
                BshH[n*68 + ku] = f2bf_rn(f);       // single-bf16 x
            }
        }
        __syncthreads();
        // ---- MFMA: 4 Ntiles x 2 Mtiles, 2-term (F hi/lo x bf16 x) ----
        #pragma unroll
        for (int kcl = 0; kcl < 2; kcl++) {
            int kglob = kc2*64 + kcl*32 + (l >> 4)*8;
            bfrag mah[2], mal[2];
            #pragma unroll
            for (int mt = 0; mt < 2; mt++) {
                int row = mt*16 + (l & 15);
                mah[mt] = *(const bfrag*)(FdAh + row*128 + kglob);
                mal[mt] = *(const bfrag*)(FdAl + row*128 + kglob);
            }
            #pragma unroll
            for (int nt = 0; nt < 4; nt++) {
                int n = wv*64 + nt*16 + (l & 15);
                int kl = kcl*32 + (l >> 4)*8;
                unsigned ku = (unsigned)(kl ^ (8*(n & 7)));
                bfrag bh = *(const bfrag*)(BshH + n*68 + ku);
                #pragma unroll
                for (int mt = 0; mt < 2; mt++) {
                    f4v a_ = acc[mt][nt];
                    a_ = MFMA(mah[mt], bh, a_);
                    a_ = MFMA(mal[mt], bh, a_);
                    acc[mt][nt] = a_;
                }
            }
        }
    }
    // ---- stats reduce (lanes l, l+16, l+32, l+48 share c4) + atomics ----
    #pragma unroll
    for (int j = 0; j < 4; j++) {
        s1a[j] += __shfl_down(s1a[j], 16, 64);
        s1a[j] += __shfl_down(s1a[j], 32, 64);
        s2a[j] += __shfl_down(s2a[j], 16, 64);
        s2a[j] += __shfl_down(s2a[j], 32, 64);
    }
    if (l < 16) {
        #pragma unroll
        for (int j = 0; j < 4; j++) {
            int c = c4*4 + j;
            atomicAdd(&ws[OFF_S1 + (b*64 + c)*2],     s1a[j]);
            atomicAdd(&ws[OFF_S1 + (b*64 + c)*2 + 1], s2a[j]);
        }
    }
    // ---- epilogue: pack -> TB (alias BshH), then block-contiguous PT2 write ----
    __syncthreads();
    unsigned* TB = (unsigned*)BshH;   // TB[ky][c*2+ri][h4], word stride 520 per ky
    #pragma unroll
    for (int mt = 0; mt < 2; mt++)
        #pragma unroll
        for (int nt = 0; nt < 4; nt++)
            #pragma unroll
            for (int rr = 0; rr < 4; rr++) {
                float v = acc[mt][nt][rr];
                unsigned short hi, lo; split2(v, hi, lo);
                int trow = mt*16 + (l >> 4)*4 + rr;
                int ri = trow >> 4, ky = trow & 15;
                int c = nt*16 + (l & 15);
                TB[ky*520 + (c*2 + ri)*4 + wv] = ((unsigned)hi << 16) | lo;
            }
    __syncthreads();
    unsigned* PTb = (unsigned*)(ws + OFF_PQ) + ((long)(b*32 + hp))*8192;
    #pragma unroll
    for (int i = 0; i < 8; i++) {
        int idx = i*256 + t;
        int ky = idx >> 7, m = idx & 127;
        ((uint4*)PTb)[idx] = *(const uint4*)(TB + ky*520 + m*4);
    }
}

// MFMA forward DFT along h: X[2kx+s][(c,ri)] = EdA @ PT2 (per ky,b).
// Staging reads 2KB contiguous runs per (hp,ky). grid (ky=16, b=16).
__global__ __launch_bounds__(256) void k_dfth(float* __restrict__ ws) {
    __shared__ unsigned Bsh[16384];   // BTh 32KB (128 cols x 256B) | BTl 32KB
    int t = threadIdx.x;
    int ky = blockIdx.x, b = blockIdx.y;
    int l = t & 63, wv = t >> 6;
    char* bh_base = (char*)Bsh;
    char* bl_base = bh_base + 32768;
    const uint4* PT4 = (const uint4*)((const unsigned*)(ws + OFF_PQ));
    const unsigned short* OU = (const unsigned short*)(ws + OFF_O);
    const unsigned short* EdAh = OU + 8192, *EdAl = OU + 16384;

    // ---- stage PT2: for (hp, n=(c,ri)) read uint4 (4 h), unpack -> BT[n][128 kk] ----
    #pragma unroll
    for (int i = 0; i < 16; i++) {
        int idx = i*256 + t;
        int hp = idx >> 7, n = idx & 127;
        uint4 v = PT4[((long)(b*32 + hp)*16 + ky)*128 + n];
        unsigned h01 = (v.x >> 16) | (v.y & 0xFFFF0000u);
        unsigned h23 = (v.z >> 16) | (v.w & 0xFFFF0000u);
        unsigned l01 = (v.x & 0xFFFFu) | (v.y << 16);
        unsigned l23 = (v.z & 0xFFFFu) | (v.w << 16);
        int kk = hp*4;
        unsigned ad = (unsigned)(n*256 + ((kk*2) ^ ((n & 7) << 4)));
        *(uint2*)(bh_base + ad) = make_uint2(h01, h23);
        *(uint2*)(bl_base + ad) = make_uint2(l01, l23);
    }
    // A-frags for this wave's Mtile
    bfrag ea_h[4], ea_l[4];
    #pragma unroll
    for (int kc = 0; kc < 4; kc++) {
        int off = (wv*16 + (l & 15))*128 + kc*32 + (l >> 4)*8;
        ea_h[kc] = *(const bfrag*)(EdAh + off);
        ea_l[kc] = *(const bfrag*)(EdAl + off);
    }
    __syncthreads();
    f4v acc[8];
    #pragma unroll
    for (int nt = 0; nt < 8; nt++) acc[nt] = (f4v){0.f,0.f,0.f,0.f};
    #pragma unroll
    for (int kc = 0; kc < 4; kc++)
        #pragma unroll
        for (int nt = 0; nt < 8; nt++) {
            int col = nt*16 + (l & 15);
            unsigned ro = (unsigned)(col*256 + ((kc*64 + (l >> 4)*16) ^ ((col & 7) << 4)));
            bfrag bh = *(const bfrag*)(bh_base + ro);
            bfrag bl = *(const bfrag*)(bl_base + ro);
            acc[nt] = MFMA(ea_h[kc], bh, acc[nt]);
            acc[nt] = MFMA(ea_h[kc], bl, acc[nt]);
            acc[nt] = MFMA(ea_l[kc], bh, acc[nt]);
        }
    // ---- epilogue: complex combine + store X (f32, legacy layout) ----
    float* X = ws + OFF_X;
    #pragma unroll
    for (int nt = 0; nt < 8; nt++)
        #pragma unroll
        for (int p = 0; p < 2; p++) {
            float s0 = acc[nt][2*p], s1 = acc[nt][2*p + 1];
            float partner = __shfl_xor(s1, 1, 64);
            float res = (l & 1) ? (s0 - partner) : (s0 + partner);
            int kx = wv*8 + (l >> 4)*2 + p;
            X[(((long)b*32 + kx)*16 + ky)*128 + nt*16 + (l & 15)] = res;
        }
}

// per-mode complex mix with rho1 scaling folded into X staging. grid 512 (=mode)
__global__ void k_mix(float* __restrict__ ws) {
    __shared__ float Wsh[8192];
    __shared__ float Xs[2048];
    __shared__ float rhoT[1024];
    int t = threadIdx.x;
    int mode = blockIdx.x;
    int kxI = mode >> 4, ky = mode & 15;
    const float* WT = ws + OFF_WT;
    const float* X = ws + OFF_X;
    float* O = ws + OFF_O;
    for (int i = t; i < 1024; i += 256) {
        float a = ws[OFF_S1 + 2*i], s = ws[OFF_S1 + 2*i + 1];
        float m = a * (1.f/16384.f);
        float v = s * (1.f/16384.f) - m*m;
        rhoT[i] = rsqrtf(v + 1e-5f);
    }
    for (int idx = t; idx < 8192; idx += 256) Wsh[idx] = WT[(long)mode*8192 + idx];
    __syncthreads();
    for (int idx = t; idx < 2048; idx += 256) {
        int b = idx >> 7, r = idx & 127;
        Xs[idx] = X[((b*32 + kxI)*16 + ky)*128 + r] * rhoT[b*64 + (r >> 1)];
    }
    __syncthreads();
    int o = t & 63, bg = t >> 6;
    float accr[4] = {0,0,0,0}, acci[4] = {0,0,0,0};
    for (int i = 0; i < 64; i++) {
        float wr = Wsh[(i*64 + o)*2], wi = Wsh[(i*64 + o)*2 + 1];
        #pragma unroll
        for (int j = 0; j < 4; j++) {
            float xr = Xs[(bg*4 + j)*128 + 2*i], xi = Xs[(bg*4 + j)*128 + 2*i + 1];
            accr[j] += xr*wr - xi*wi;
            acci[j] += xr*wi + xi*wr;
        }
    }
    #pragma unroll
    for (int j = 0; j < 4; j++) {
        int b = bg*4 + j;
        float2* dst = (float2*)(O + ((b*32 + kxI)*16 + ky)*128);
        dst[o] = make_float2(accr[j], acci[j]);
    }
}

// Parseval stats of y directly from O. grid (16=b, 4=gg), 256 thr.
__global__ void k_pstats(float* __restrict__ ws) {
    __shared__ float red[256];
    int t = threadIdx.x, b = blockIdx.x, gg = blockIdx.y;
    int c = t & 63, g = t >> 6;
    const float* O = ws + OFF_O + (long)b*65536;   // [(kxI*16+ky)*128 + 2c]
    float t0 = 0.f, t2 = 0.f;
    int k0 = gg*8 + g*2;
    for (int kxI = k0; kxI < k0 + 2; kxI++)
        for (int ky = 0; ky < 16; ky++) {
            float re = O[(kxI*16 + ky)*128 + 2*c];
            float im = O[(kxI*16 + ky)*128 + 2*c + 1];
            float p = re*re + im*im;
            if (ky == 0) t0 += p; else t2 += p;
        }
    float s2p = 0.5f*t0 + 2.f*t2;
    if (gg == 0 && g == 0) {
        float ar = O[2*c], ai = O[2*c + 1];        // kxI=0, ky=0
        float t1 = ar*ar - ai*ai;
        for (int k = 1; k <= 15; k++) {
            float xr = O[(k*16)*128 + 2*c],        xi = O[(k*16)*128 + 2*c + 1];
            float yr = O[((32-k)*16)*128 + 2*c],   yi = O[((32-k)*16)*128 + 2*c + 1];
            t1 += 2.f*(xr*yr - xi*yi);
        }
        s2p += 0.5f*t1;
        ws[OFF_S2 + (b*64 + c)*2] = ar;            // s1 (mean term)
    }
    red[t] = s2p;
    __syncthreads();
    if (t < 64) {
        float s = red[t] + red[t+64] + red[t+128] + red[t+192];
        atomicAdd(&ws[OFF_S2 + (b*64 + t)*2 + 1], s * (1.f/16384.f));
    }
}

// MFMA inverse DFT along h (single GEMM, no combine): Q = A @ Bst where
// A[h][2kx]=cos, A[h][2kx+1]=sin (theta = 2pi f(kx) h/128, built per-lane
// from the persistent TBL) and Bst[2kx][2o]=Or, [2kx][2o+1]=Oi,
// [2kx+1][2o]=-Oi, [2kx+1][2o+1]=Or. Then G[h][2o]=Qr, G[h][2o+1]=Qi.
// 3-term hi/lo MFMA (~f32). grid (ky=16, b=16). Q layout unchanged.
__global__ __launch_bounds__(256) void k_idfth(float* __restrict__ ws) {
    __shared__ unsigned short BstH[128*70];   // [n=o*2+ri][k 64 pad70], swz k^8(n&7)
    __shared__ unsigned short BstL[128*70];
    __shared__ float tblL[256];
    int t = threadIdx.x;
    int ky = blockIdx.x, b = blockIdx.y;
    int l = t & 63, wv = t >> 6;
    for (int i = t; i < 256; i += 256) tblL[i] = ws[OFF_TBL + i];
    const float4* O4 = (const float4*)(ws + OFF_O);

    // ---- stage O -> Bst (hi/lo) ----
    #pragma unroll
    for (int i = 0; i < 4; i++) {
        int idx = i*256 + t;
        int kx = idx >> 5, u = idx & 31;    // u: uint4 within the 128-float row
        float4 v = O4[((long)(b*32 + kx)*16 + ky)*32 + u];
        int k0 = kx*2;
        #pragma unroll
        for (int p = 0; p < 2; p++) {
            float orr = p ? v.z : v.x;
            float oii = p ? v.w : v.y;
            int n0 = (u*2 + p)*2;           // re column
            int n1 = n0 + 1;                // im column
            unsigned short hi, lo;
            split2(orr, hi, lo);
            { unsigned ad = (unsigned)(n0*70 + (k0 ^ (8*(n0 & 7)))); BstH[ad]=hi; BstL[ad]=lo; }
            { unsigned ad = (unsigned)(n1*70 + ((k0+1) ^ (8*(n1 & 7)))); BstH[ad]=hi; BstL[ad]=lo; }
            split2(oii, hi, lo);
            { unsigned ad = (unsigned)(n1*70 + (k0 ^ (8*(n1 & 7)))); BstH[ad]=hi; BstL[ad]=lo; }
            split2(-oii, hi, lo);
            { unsigned ad = (unsigned)(n0*70 + ((k0+1) ^ (8*(n0 & 7)))); BstH[ad]=hi; BstL[ad]=lo; }
        }
    }
    __syncthreads();
    // ---- A-frags built per-lane from TBL (hi/lo split in-register) ----
    bfrag ah_[2][2], al_[2][2];
    #pragma unroll
    for (int q = 0; q < 2; q++) {
        int h = (wv*2 + q)*16 + (l & 15);
        #pragma unroll
        for (int kcl = 0; kcl < 2; kcl++) {
            int kbase = kcl*32 + (l >> 4)*8;
            bfrag vh, vl;
            #pragma unroll
            for (int j = 0; j < 8; j++) {
                int k = kbase + j;
                int kx = k >> 1, f = kx < 16 ? kx : 96 + kx;
                int m = (f * h) & 127;
                float val = (k & 1) ? tblL[2*m + 1] : tblL[2*m];
                unsigned short hi, lo; split2(val, hi, lo);
                vh[j] = (short)hi; vl[j] = (short)lo;
            }
            ah_[q][kcl] = vh; al_[q][kcl] = vl;
        }
    }
    f4v acc[2][8];
    #pragma unroll
    for (int q = 0; q < 2; q++)
        #pragma unroll
        for (int nt = 0; nt < 8; nt++) acc[q][nt] = (f4v){0.f,0.f,0.f,0.f};
    #pragma unroll
    for (int kcl = 0; kcl < 2; kcl++)
        #pragma unroll
        for (int nt = 0; nt < 8; nt++) {
            int n = nt*16 + (l & 15);
            unsigned ku = (unsigned)((kcl*32 + (l >> 4)*8) ^ (8*(n & 7)));
            bfrag bh = *(const bfrag*)(BstH + n*70 + ku);
            bfrag bl = *(const bfrag*)(BstL + n*70 + ku);
            #pragma unroll
            for (int q = 0; q < 2; q++) {
                f4v a_ = acc[q][nt];
                a_ = MFMA(ah_[q][kcl], bh, a_);
                a_ = MFMA(ah_[q][kcl], bl, a_);
                a_ = MFMA(al_[q][kcl], bh, a_);
                acc[q][nt] = a_;
            }
        }
    // ---- write Q[b][h][ky][n] ----
    float* Q = ws + OFF_PQ;
    #pragma unroll
    for (int q = 0; q < 2; q++)
        #pragma unroll
        for (int nt = 0; nt < 8; nt++)
            #pragma unroll
            for (int r = 0; r < 4; r++) {
                int h = (wv*2 + q)*16 + (l >> 4)*4 + r;
                Q[((long)(b*128 + h))*2048 + ky*128 + nt*16 + (l & 15)] = acc[q][nt][r];
            }
}

// fused MFMA kernel: Y = M@Qm (iDFT-w), z = (Y-mu)*rho, h = GELU(z@W1+b1),
// out = h@W2+b2. zhS/hhS rows are wave-private -> single staging barrier.
// grid (h=128,b=16).
__global__ __launch_bounds__(256, 2) void k_mlp(const float* __restrict__ mb1,
                      const float* __restrict__ mb2,
                      float* __restrict__ out, const float* __restrict__ ws) {
    __shared__ unsigned short zhS[8192];                // z[w][64c], swz (w&7)<<4
    __shared__ unsigned short w1hS[8192];               // w1[j][64c], swz (j&7)<<4
    __shared__ unsigned short w2hS[8192];               // w2[o][128j], swz (o&15)<<4
    __shared__ unsigned short hhS[8192];                // h-half [w][64jl], swz (w&7)<<4
    __shared__ unsigned short qhS[2560], qlS[2560];     // QmT[c][40k] hi/lo
    __shared__ float muL[64], rhoL[64], b1L[128], b2L[64];
    int t = threadIdx.x;
    int h = blockIdx.x, b = blockIdx.y;
    int l = t & 63, wv = t >> 6;

    const unsigned short* xu = (const unsigned short*)(ws + OFF_X);
    const unsigned short* w1hG = xu;
    const unsigned short* w2hG = xu + 16384;
    const unsigned short* MhG  = xu + 32768, *MlG  = xu + 36864;

    for (int ch = t; ch < 1024; ch += 256) {       // w1: rows j, stride 128B
        int j = ch >> 3, c0 = (ch & 7) * 8;
        unsigned off = (unsigned)(j*128 + c0*2) ^ (unsigned)((j & 7) << 4);
        *(bfrag*)((char*)w1hS + off) = *(const bfrag*)(w1hG + ch*8);
    }
    for (int ch = t; ch < 1024; ch += 256) {       // w2: rows o, stride 256B
        int o = ch >> 4, j0 = (ch & 15) * 8;
        unsigned off = (unsigned)(o*256 + j0*2) ^ (unsigned)((o & 15) << 4);
        *(bfrag*)((char*)w2hS + off) = *(const bfrag*)(w2hG + ch*8);
    }
    const float* Qp = ws + OFF_PQ + (long)(b*128 + h)*2048;
    for (int i = t; i < 2048; i += 256) {
        int k = i & 31, c = i >> 5;
        float v = Qp[(k >> 1)*128 + c*2 + (k & 1)];
        unsigned short hi, lo; split2(v, hi, lo);
        qhS[c*40 + k] = hi; qlS[c*40 + k] = lo;
    }
    if (t < 64) {
        float s1 = ws[OFF_S2 + (b*64+t)*2], s2 = ws[OFF_S2 + (b*64+t)*2 + 1];
        float m = s1 * (1.f/16384.f);
        float v = s2 * (1.f/16384.f) - m*m;
        muL[t] = m; rhoL[t] = rsqrtf(v + 1e-5f);
        b2L[t] = mb2[t];
    }
    if (t >= 64 && t < 192) b1L[t - 64] = mb1[t - 64];
    bfrag ma_h[2], ma_l[2];
    #pragma unroll
    for (int q = 0; q < 2; q++) {
        int w = (wv + 4*q)*16 + (l & 15);
        ma_h[q] = *(const bfrag*)(MhG + w*32 + (l >> 4)*8);
        ma_l[q] = *(const bfrag*)(MlG + w*32 + (l >> 4)*8);
    }
    __syncthreads();   // cross-wave staging -- the ONLY barrier needed

    #pragma unroll
    for (int q = 0; q < 2; q++) {
        int wt = wv + 4*q;
        #pragma unroll
        for (int ct = 0; ct < 4; ct++) {
            unsigned ro = (unsigned)((ct*16 + (l & 15))*80 + (l >> 4)*16);
            bfrag bh = *(const bfrag*)((const char*)qhS + ro);
            bfrag bl = *(const bfrag*)((const char*)qlS + ro);
            f4v acc = {0.f, 0.f, 0.f, 0.f};
            acc = MFMA(ma_h[q], bh, acc);
            acc = MFMA(ma_h[q], bl, acc);
            acc = MFMA(ma_l[q], bh, acc);
            int c = ct*16 + (l & 15);
            float mu_ = muL[c], rh_ = rhoL[c];
            #pragma unroll
            for (int r = 0; r < 4; r++) {
                int w = wt*16 + (l >> 4)*4 + r;
                float z = (acc[r] - mu_) * rh_;
                unsigned off = (unsigned)(w*128 + c*2) ^ (unsigned)((w & 7) << 4);
                *(unsigned short*)((char*)zhS + off) = f2bf_rn(z);
            }
        }
    }

    bfrag za[2][2];
    #pragma unroll
    for (int q = 0; q < 2; q++) {
        int w = (wv + 4*q)*16 + (l & 15);
        #pragma unroll
        for (int ks = 0; ks < 2; ks++) {
            unsigned off = (unsigned)(w*128 + (ks*32 + (l >> 4)*8)*2) ^ (unsigned)((w & 7) << 4);
            za[q][ks] = *(const bfrag*)((const char*)zhS + off);
        }
    }
    f4v accO[2][4];
    #pragma unroll
    for (int q = 0; q < 2; q++)
        #pragma unroll
        for (int ot = 0; ot < 4; ot++) accO[q][ot] = (f4v){0.f,0.f,0.f,0.f};

    #pragma unroll
    for (int jh = 0; jh < 2; jh++) {
        #pragma unroll
        for (int q = 0; q < 2; q++) {
            int wt = wv + 4*q;
            #pragma unroll
            for (int jt = 0; jt < 4; jt++) {
                int j = jh*64 + jt*16 + (l & 15);
                f4v acc = {0.f, 0.f, 0.f, 0.f};
                #pragma unroll
                for (int ks = 0; ks < 2; ks++) {
                    unsigned off = (unsigned)(j*128 + (ks*32 + (l >> 4)*8)*2) ^ (unsigned)((j & 7) << 4);
                    bfrag bh = *(const bfrag*)((const char*)w1hS + off);
                    acc = MFMA(za[q][ks], bh, acc);
                }
                float bj = b1L[j];
                #pragma unroll
                for (int r = 0; r < 4; r++) {
                    int w = wt*16 + (l >> 4)*4 + r;
                    float hv = gelu_t(acc[r] + bj);
                    int jl = jt*16 + (l & 15);
                    unsigned off = (unsigned)(w*128 + jl*2) ^ (unsigned)((w & 7) << 4);
                    *(unsigned short*)((char*)hhS + off) = f2bf_rn(hv);
                }
            }
        }
        #pragma unroll
        for (int q = 0; q < 2; q++) {
            int w = (wv + 4*q)*16 + (l & 15);
            bfrag ha[2];
            #pragma unroll
            for (int ks = 0; ks < 2; ks++) {
                unsigned off = (unsigned)(w*128 + (ks*32 + (l >> 4)*8)*2) ^ (unsigned)((w & 7) << 4);
                ha[ks] = *(const bfrag*)((const char*)hhS + off);
            }
            #pragma unroll
            for (int ot = 0; ot < 4; ot++) {
                int o = ot*16 + (l & 15);
                f4v acc = accO[q][ot];
                #pragma unroll
                for (int ks = 0; ks < 2; ks++) {
                    int jj = jh*64 + ks*32 + (l >> 4)*8;
                    unsigned off = (unsigned)(o*256 + jj*2) ^ (unsigned)((o & 15) << 4);
                    bfrag bh = *(const bfrag*)((const char*)w2hS + off);
                    acc = MFMA(ha[ks], bh, acc);
                }
                accO[q][ot] = acc;
            }
        }
    }
    #pragma unroll
    for (int q = 0; q < 2; q++) {
        int wt = wv + 4*q;
        #pragma unroll
        for (int ot = 0; ot < 4; ot++) {
            int o = ot*16 + (l & 15);
            float bo = b2L[o];
            #pragma unroll
            for (int r = 0; r < 4; r++) {
                int w = wt*16 + (l >> 4)*4 + r;
                out[((long)(b*128 + h)*128 + w)*64 + o] = accO[q][ot][r] + bo;
            }
        }
    }
}

extern "C" void kernel_launch(void* const* d_in, const int* in_sizes, int n_in,
                              void* d_out, int out_size, void* d_ws, size_t ws_size,
                              hipStream_t stream) {
    const float* x   = (const float*)d_in[0];
    const float* w1r = (const float*)d_in[1];
    const float* w1i = (const float*)d_in[2];
    const float* w2r = (const float*)d_in[3];
    const float* w2i = (const float*)d_in[4];
    const float* mw1 = (const float*)d_in[5];
    const float* mb1 = (const float*)d_in[6];
    const float* mw2 = (const float*)d_in[7];
    const float* mb2 = (const float*)d_in[8];
    float* ws  = (float*)d_ws;
    float* out = (float*)d_out;

    k_init  <<<dim3(49),      dim3(256), 0, stream>>>(ws);
    k_trans <<<dim3(64,2),    dim3(256), 0, stream>>>(w1r, w1i, w2r, w2i, ws);
    k_dftw  <<<dim3(32,16),   dim3(256), 0, stream>>>(x, ws);   // direct x read; stats folded
    k_dfth  <<<dim3(16,16),   dim3(256), 0, stream>>>(ws);
    k_mix   <<<dim3(512),     dim3(256), 0, stream>>>(ws);
    k_wmlp  <<<dim3(80),      dim3(256), 0, stream>>>(mw1, mw2, ws);  // X dead after k_mix
    k_pstats<<<dim3(16,4),    dim3(256), 0, stream>>>(ws);
    k_idfth <<<dim3(16,16),   dim3(256), 0, stream>>>(ws);      // MFMA single-GEMM inverse
    k_mlp   <<<dim3(128,16),  dim3(256), 0, stream>>>(mb1, mb2, out, ws);
}

// Round 18
// 148.609 us; speedup vs baseline: 1.7285x; 1.0577x over previous
//
#include <hip/hip_runtime.h>
#include <math.h>

// Problem constants: B=16, H=W=128, C=64, M1=M2=16
// Workspace layout (float offsets):
#define OFF_TBL 0u            // 128 x {cos,sin}(2*pi*m/128)          (256)
#define OFF_S1  256u          // instance-norm-1 raw sums [b*64+c][2] (2048)
#define OFF_S2  2304u         // instance-norm-2 stats (s1,s2)        (2048)
#define OFF_PQ  4352u         // PT2[b][hp32][ky16][c64][ri2][h4] u32 bf16 hi|lo (4194304)
                              //   aliased later with Q[b][h][ky][o][2] f32
#define OFF_X   4198656u      // X[b][kx][ky][c][2] f32               (1048576)
#define OFF_O   5247232u      // Out[b][kx][ky][o][2] f32             (1048576)
                              //   head doubles (pre-mix) as u16 trig tables:
                              //   FdAh[32][128] @0, FdAl @4096, EdAh[64][128] @8192, EdAl @16384
#define OFF_WT  6295808u      // WT[mode][i][o][2]                    (4194304)
// total = 10490112 floats = 41.96 MB
// X region is dead after k_mix -> reuse as u16 arrays for bf16-split MLP weights:
//   u16[0..8192) w1hi   [8192..16384) w1lo   [16384..24576) w2hi
//   [24576..32768) w2lo  [32768..36864) Mhi  [36864..40960) Mlo

typedef __attribute__((ext_vector_type(8))) short bfrag;
typedef __attribute__((ext_vector_type(4))) float f4v;
#define MFMA(A,B,C) __builtin_amdgcn_mfma_f32_16x16x32_bf16(A,B,C,0,0,0)

// compile-time float4 component select -- NO address-taken indexing (scratch hazard)
#define F4GET(v, i) ((i)==0 ? (v).x : (i)==1 ? (v).y : (i)==2 ? (v).z : (v).w)

__device__ __forceinline__ unsigned short f2bf_rn(float x) {
    unsigned u = __float_as_uint(x);
    unsigned r = u + 0x7FFFu + ((u >> 16) & 1u);
    return (unsigned short)(r >> 16);
}
__device__ __forceinline__ float bf2f(unsigned short h) {
    return __uint_as_float(((unsigned)h) << 16);
}
__device__ __forceinline__ void split2(float x, unsigned short& hi, unsigned short& lo) {
    hi = f2bf_rn(x);
    lo = f2bf_rn(x - bf2f(hi));
}
// tanh-form GELU; matches exact GELU to <1e-5 for |x| <= 0.5 (our range)
__device__ __forceinline__ float gelu_t(float x) {
    float u = 0.79788456080286536f * (x + 0.044715f * x * x * x);
    float e = __expf(2.f * u);
    float th = 1.f - 2.f / (e + 1.f);
    return 0.5f * x * (1.f + th);
}

// block 0: twiddle table + zero S1/S2. blocks 1..48: bf16-split trig tables
// (F for dftw, E for dfth) into the O region (dead until k_mix overwrites).
__global__ void k_init(float* __restrict__ ws) {
    int t = threadIdx.x, bid = blockIdx.x;
    if (bid == 0) {
        if (t < 128) {
            double ang = 6.283185307179586476925286766559 * (double)t / 128.0;
            ws[OFF_TBL + 2*t]     = (float)cos(ang);
            ws[OFF_TBL + 2*t + 1] = (float)sin(ang);
        }
        for (int i = t; i < 4096; i += 256) ws[OFF_S1 + i] = 0.f;
        return;
    }
    int e = (bid - 1)*256 + t;   // 0..12287
    unsigned short* OU = (unsigned short*)(ws + OFF_O);
    const double TWO_PI = 6.283185307179586476925286766559;
    if (e < 4096) {              // FdA[row=ri*16+ky][w]: re rows cos, im rows -sin
        int row = e >> 7, w = e & 127, ky = row & 15;
        double ang = TWO_PI * (double)((ky * w) & 127) / 128.0;
        double v = (row < 16) ? cos(ang) : -sin(ang);
        unsigned short hi, lo; split2((float)v, hi, lo);
        OU[e] = hi; OU[4096 + e] = lo;
    } else {                     // EdA[row=2kx+s][h]: s=0 cos, s=1 sin (of freq f(kx))
        int e2 = e - 4096, row = e2 >> 7, h = e2 & 127;
        int kx = row >> 1, f = kx < 16 ? kx : 96 + kx;
        double ang = TWO_PI * (double)((f * h) & 127) / 128.0;
        double v = (row & 1) ? sin(ang) : cos(ang);
        unsigned short hi, lo; split2((float)v, hi, lo);
        OU[8192 + e2] = hi; OU[16384 + e2] = lo;
    }
}

// weight transpose: [i][o][kx][ky] (x4 arrays) -> WT[mode][i][o][{re,im}]. grid (64=i, 2=part)
__global__ void k_trans(const float* __restrict__ w1r, const float* __restrict__ w1i,
                        const float* __restrict__ w2r, const float* __restrict__ w2i,
                        float* __restrict__ ws) {
    __shared__ float Lr[16*257], Li[16*257];
    int t = threadIdx.x;
    int i = blockIdx.x;
    int part = blockIdx.y;
    float* WT = ws + OFF_WT;
    const float* wr = part ? w2r : w1r;
    const float* wi = part ? w2i : w1i;
    for (int oc = 0; oc < 4; oc++) {
        int o0 = oc * 16;
        __syncthreads();
        for (int idx = t; idx < 4096; idx += 256) {
            int oo = idx >> 8, m = idx & 255;
            Lr[oo*257 + m] = wr[(i*64 + o0 + oo)*256 + m];
            Li[oo*257 + m] = wi[(i*64 + o0 + oo)*256 + m];
        }
        __syncthreads();
        for (int idx = t; idx < 8192; idx += 256) {
            int mode = idx >> 5, rem = idx & 31, oo = rem >> 1, ri = rem & 1;
            float val = ri ? Li[oo*257 + mode] : Lr[oo*257 + mode];
            int gm = part*256 + mode;
            WT[((gm*64 + i)*64 + (o0 + oo))*2 + ri] = val;
        }
    }
}

// bf16-split MLP weights + iDFT-w matrix M into the dead X region. grid 80
__global__ void k_wmlp(const float* __restrict__ mw1, const float* __restrict__ mw2,
                       float* __restrict__ ws) {
    int i = blockIdx.x * 256 + threadIdx.x;   // [0, 20480)
    unsigned short* xu = (unsigned short*)(ws + OFF_X);
    if (i < 8192) {
        unsigned short hi, lo; split2(mw1[i], hi, lo);
        xu[i] = hi; xu[8192 + i] = lo;
    } else if (i < 16384) {
        int k = i - 8192;
        unsigned short hi, lo; split2(mw2[k], hi, lo);
        xu[16384 + k] = hi; xu[24576 + k] = lo;
    } else if (i < 20480) {
        int m = i - 16384;           // w*32 + k
        int w = m >> 5, k = m & 31;
        int ky = k >> 1;
        double ang = 6.283185307179586476925286766559 * (double)((ky * w) & 127) / 128.0;
        double v = (k & 1) ? -sin(ang) : cos(ang);
        double a = (ky == 0) ? 1.0 : 2.0;
        float val = (float)(v * a) * (1.f/16384.f);
        unsigned short hi, lo; split2(val, hi, lo);
        xu[32768 + m] = hi; xu[36864 + m] = lo;
    }
}

// MFMA forward DFT along w reading x DIRECTLY, x quantized to SINGLE bf16
// (lo-part dropped; F table keeps hi/lo, so 2-term MFMA). LDS 34KB.
// grid (hp=32, b=16): block = 4 h x 64 c = 256 N-cols, K=128 w (2 chunks).
// PT2[b][hp][ky][c][ri][h4] u32(hi|lo): block writes its own 32KB contiguously.
__global__ __launch_bounds__(256) void k_dftw(const float* __restrict__ x,
                                              float* __restrict__ ws) {
    __shared__ unsigned short BshH[256*68];   // [n=hl*64+c][k 64 pad68] u16, swz k^8(n&7)
    int t = threadIdx.x;
    int hp = blockIdx.x, b = blockIdx.y;
    int l = t & 63, wv = t >> 6;
    const unsigned short* OU = (const unsigned short*)(ws + OFF_O);
    const unsigned short* FdAh = OU, *FdAl = OU + 4096;
    f4v acc[2][4];
    #pragma unroll
    for (int mt = 0; mt < 2; mt++)
        #pragma unroll
        for (int nt = 0; nt < 4; nt++) acc[mt][nt] = (f4v){0.f,0.f,0.f,0.f};

    float s1a[4] = {0,0,0,0}, s2a[4] = {0,0,0,0};   // stats for c = c4*4 + j
    int c4 = t & 15;
    const float* xb = x + ((long)(b*128 + hp*4))*8192;   // 4 h rows

    for (int kc2 = 0; kc2 < 2; kc2++) {
        __syncthreads();                    // protect Bsh from prev MFMA readers
        // ---- stage direct from x: 16-lane groups read full 256B c-lines ----
        #pragma unroll
        for (int i = 0; i < 16; i++) {
            int idx = i*256 + t;
            int hw = idx >> 4;              // 0..255: hl = hw>>6, wl = hw&63
            int hl = hw >> 6, wl = hw & 63;
            float4 v = *(const float4*)(xb + ((long)hl*8192) + (kc2*64 + wl)*64 + c4*4);
            #pragma unroll
            for (int j = 0; j < 4; j++) {
                float f = F4GET(v, j);
                s1a[j] += f;
                s2a[j] += f*f;
                int n = hl*64 + c4*4 + j;
                unsigned ku = (unsigned)(wl ^ (8*(n & 7)));
                BshH[n*68 + ku] = f2bf_rn(f);       // single-bf16 x
            }
        }
        __syncthreads();
        // ---- MFMA: 4 Ntiles x 2 Mtiles, 2-term (F hi/lo x bf16 x) ----
        #pragma unroll
        for (int kcl = 0; kcl < 2; kcl++) {
            int kglob = kc2*64 + kcl*32 + (l >> 4)*8;
            bfrag mah[2], mal[2];
            #pragma unroll
            for (int mt = 0; mt < 2; mt++) {
                int row = mt*16 + (l & 15);
                mah[mt] = *(const bfrag*)(FdAh + row*128 + kglob);
                mal[mt] = *(const bfrag*)(FdAl + row*128 + kglob);
            }
            #pragma unroll
            for (int nt = 0; nt < 4; nt++) {
                int n = wv*64 + nt*16 + (l & 15);
                int kl = kcl*32 + (l >> 4)*8;
                unsigned ku = (unsigned)(kl ^ (8*(n & 7)));
                bfrag bh = *(const bfrag*)(BshH + n*68 + ku);
                #pragma unroll
                for (int mt = 0; mt < 2; mt++) {
                    f4v a_ = acc[mt][nt];
                    a_ = MFMA(mah[mt], bh, a_);
                    a_ = MFMA(mal[mt], bh, a_);
                    acc[mt][nt] = a_;
                }
            }
        }
    }
    // ---- stats reduce (lanes l, l+16, l+32, l+48 share c4) + atomics ----
    #pragma unroll
    for (int j = 0; j < 4; j++) {
        s1a[j] += __shfl_down(s1a[j], 16, 64);
        s1a[j] += __shfl_down(s1a[j], 32, 64);
        s2a[j] += __shfl_down(s2a[j], 16, 64);
        s2a[j] += __shfl_down(s2a[j], 32, 64);
    }
    if (l < 16) {
        #pragma unroll
        for (int j = 0; j < 4; j++) {
            int c = c4*4 + j;
            atomicAdd(&ws[OFF_S1 + (b*64 + c)*2],     s1a[j]);
            atomicAdd(&ws[OFF_S1 + (b*64 + c)*2 + 1], s2a[j]);
        }
    }
    // ---- epilogue: pack -> TB (alias BshH), then block-contiguous PT2 write ----
    __syncthreads();
    unsigned* TB = (unsigned*)BshH;   // TB[ky][c*2+ri][h4], word stride 520 per ky
    #pragma unroll
    for (int mt = 0; mt < 2; mt++)
        #pragma unroll
        for (int nt = 0; nt < 4; nt++)
            #pragma unroll
            for (int rr = 0; rr < 4; rr++) {
                float v = acc[mt][nt][rr];
                unsigned short hi, lo; split2(v, hi, lo);
                int trow = mt*16 + (l >> 4)*4 + rr;
                int ri = trow >> 4, ky = trow & 15;
                int c = nt*16 + (l & 15);
                TB[ky*520 + (c*2 + ri)*4 + wv] = ((unsigned)hi << 16) | lo;
            }
    __syncthreads();
    unsigned* PTb = (unsigned*)(ws + OFF_PQ) + ((long)(b*32 + hp))*8192;
    #pragma unroll
    for (int i = 0; i < 8; i++) {
        int idx = i*256 + t;
        int ky = idx >> 7, m = idx & 127;
        ((uint4*)PTb)[idx] = *(const uint4*)(TB + ky*520 + m*4);
    }
}

// MFMA forward DFT along h: X[2kx+s][(c,ri)] = EdA @ PT2 (per ky,b).
// Staging reads 2KB contiguous runs per (hp,ky). grid (ky=16, b=16).
__global__ __launch_bounds__(256) void k_dfth(float* __restrict__ ws) {
    __shared__ unsigned Bsh[16384];   // BTh 32KB (128 cols x 256B) | BTl 32KB
    int t = threadIdx.x;
    int ky = blockIdx.x, b = blockIdx.y;
    int l = t & 63, wv = t >> 6;
    char* bh_base = (char*)Bsh;
    char* bl_base = bh_base + 32768;
    const uint4* PT4 = (const uint4*)((const unsigned*)(ws + OFF_PQ));
    const unsigned short* OU = (const unsigned short*)(ws + OFF_O);
    const unsigned short* EdAh = OU + 8192, *EdAl = OU + 16384;

    // ---- stage PT2: for (hp, n=(c,ri)) read uint4 (4 h), unpack -> BT[n][128 kk] ----
    #pragma unroll
    for (int i = 0; i < 16; i++) {
        int idx = i*256 + t;
        int hp = idx >> 7, n = idx & 127;
        uint4 v = PT4[((long)(b*32 + hp)*16 + ky)*128 + n];
        unsigned h01 = (v.x >> 16) | (v.y & 0xFFFF0000u);
        unsigned h23 = (v.z >> 16) | (v.w & 0xFFFF0000u);
        unsigned l01 = (v.x & 0xFFFFu) | (v.y << 16);
        unsigned l23 = (v.z & 0xFFFFu) | (v.w << 16);
        int kk = hp*4;
        unsigned ad = (unsigned)(n*256 + ((kk*2) ^ ((n & 7) << 4)));
        *(uint2*)(bh_base + ad) = make_uint2(h01, h23);
        *(uint2*)(bl_base + ad) = make_uint2(l01, l23);
    }
    // A-frags for this wave's Mtile
    bfrag ea_h[4], ea_l[4];
    #pragma unroll
    for (int kc = 0; kc < 4; kc++) {
        int off = (wv*16 + (l & 15))*128 + kc*32 + (l >> 4)*8;
        ea_h[kc] = *(const bfrag*)(EdAh + off);
        ea_l[kc] = *(const bfrag*)(EdAl + off);
    }
    __syncthreads();
    f4v acc[8];
    #pragma unroll
    for (int nt = 0; nt < 8; nt++) acc[nt] = (f4v){0.f,0.f,0.f,0.f};
    #pragma unroll
    for (int kc = 0; kc < 4; kc++)
        #pragma unroll
        for (int nt = 0; nt < 8; nt++) {
            int col = nt*16 + (l & 15);
            unsigned ro = (unsigned)(col*256 + ((kc*64 + (l >> 4)*16) ^ ((col & 7) << 4)));
            bfrag bh = *(const bfrag*)(bh_base + ro);
            bfrag bl = *(const bfrag*)(bl_base + ro);
            acc[nt] = MFMA(ea_h[kc], bh, acc[nt]);
            acc[nt] = MFMA(ea_h[kc], bl, acc[nt]);
            acc[nt] = MFMA(ea_l[kc], bh, acc[nt]);
        }
    // ---- epilogue: complex combine + store X (f32, legacy layout) ----
    float* X = ws + OFF_X;
    #pragma unroll
    for (int nt = 0; nt < 8; nt++)
        #pragma unroll
        for (int p = 0; p < 2; p++) {
            float s0 = acc[nt][2*p], s1 = acc[nt][2*p + 1];
            float partner = __shfl_xor(s1, 1, 64);
            float res = (l & 1) ? (s0 - partner) : (s0 + partner);
            int kx = wv*8 + (l >> 4)*2 + p;
            X[(((long)b*32 + kx)*16 + ky)*128 + nt*16 + (l & 15)] = res;
        }
}

// per-mode complex mix with rho1 scaling folded into X staging. grid 512 (=mode)
__global__ void k_mix(float* __restrict__ ws) {
    __shared__ float Wsh[8192];
    __shared__ float Xs[2048];
    __shared__ float rhoT[1024];
    int t = threadIdx.x;
    int mode = blockIdx.x;
    int kxI = mode >> 4, ky = mode & 15;
    const float* WT = ws + OFF_WT;
    const float* X = ws + OFF_X;
    float* O = ws + OFF_O;
    for (int i = t; i < 1024; i += 256) {
        float a = ws[OFF_S1 + 2*i], s = ws[OFF_S1 + 2*i + 1];
        float m = a * (1.f/16384.f);
        float v = s * (1.f/16384.f) - m*m;
        rhoT[i] = rsqrtf(v + 1e-5f);
    }
    for (int idx = t; idx < 8192; idx += 256) Wsh[idx] = WT[(long)mode*8192 + idx];
    __syncthreads();
    for (int idx = t; idx < 2048; idx += 256) {
        int b = idx >> 7, r = idx & 127;
        Xs[idx] = X[((b*32 + kxI)*16 + ky)*128 + r] * rhoT[b*64 + (r >> 1)];
    }
    __syncthreads();
    int o = t & 63, bg = t >> 6;
    float accr[4] = {0,0,0,0}, acci[4] = {0,0,0,0};
    for (int i = 0; i < 64; i++) {
        float wr = Wsh[(i*64 + o)*2], wi = Wsh[(i*64 + o)*2 + 1];
        #pragma unroll
        for (int j = 0; j < 4; j++) {
            float xr = Xs[(bg*4 + j)*128 + 2*i], xi = Xs[(bg*4 + j)*128 + 2*i + 1];
            accr[j] += xr*wr - xi*wi;
            acci[j] += xr*wi + xi*wr;
        }
    }
    #pragma unroll
    for (int j = 0; j < 4; j++) {
        int b = bg*4 + j;
        float2* dst = (float2*)(O + ((b*32 + kxI)*16 + ky)*128);
        dst[o] = make_float2(accr[j], acci[j]);
    }
}

// Parseval stats of y directly from O. grid (16=b, 4=gg), 256 thr.
__global__ void k_pstats(float* __restrict__ ws) {
    __shared__ float red[256];
    int t = threadIdx.x, b = blockIdx.x, gg = blockIdx.y;
    int c = t & 63, g = t >> 6;
    const float* O = ws + OFF_O + (long)b*65536;   // [(kxI*16+ky)*128 + 2c]
    float t0 = 0.f, t2 = 0.f;
    int k0 = gg*8 + g*2;
    for (int kxI = k0; kxI < k0 + 2; kxI++)
        for (int ky = 0; ky < 16; ky++) {
            float re = O[(kxI*16 + ky)*128 + 2*c];
            float im = O[(kxI*16 + ky)*128 + 2*c + 1];
            float p = re*re + im*im;
            if (ky == 0) t0 += p; else t2 += p;
        }
    float s2p = 0.5f*t0 + 2.f*t2;
    if (gg == 0 && g == 0) {
        float ar = O[2*c], ai = O[2*c + 1];        // kxI=0, ky=0
        float t1 = ar*ar - ai*ai;
        for (int k = 1; k <= 15; k++) {
            float xr = O[(k*16)*128 + 2*c],        xi = O[(k*16)*128 + 2*c + 1];
            float yr = O[((32-k)*16)*128 + 2*c],   yi = O[((32-k)*16)*128 + 2*c + 1];
            t1 += 2.f*(xr*yr - xi*yi);
        }
        s2p += 0.5f*t1;
        ws[OFF_S2 + (b*64 + c)*2] = ar;            // s1 (mean term)
    }
    red[t] = s2p;
    __syncthreads();
    if (t < 64) {
        float s = red[t] + red[t+64] + red[t+128] + red[t+192];
        atomicAdd(&ws[OFF_S2 + (b*64 + t)*2 + 1], s * (1.f/16384.f));
    }
}

// MFMA inverse DFT along h (single GEMM, no combine): Q = A @ Bst where
// A[h][2kx]=cos, A[h][2kx+1]=sin (theta = 2pi f(kx) h/128, built per-lane
// from the persistent TBL) and Bst[2kx][2o]=Or, [2kx][2o+1]=Oi,
// [2kx+1][2o]=-Oi, [2kx+1][2o+1]=Or. Then G[h][2o]=Qr, G[h][2o+1]=Qi.
// 3-term hi/lo MFMA (~f32). grid (ky=16, b=16). Q layout unchanged.
__global__ __launch_bounds__(256) void k_idfth(float* __restrict__ ws) {
    __shared__ unsigned short BstH[128*70];   // [n=o*2+ri][k 64 pad70], swz k^8(n&7)
    __shared__ unsigned short BstL[128*70];
    __shared__ float tblL[256];
    int t = threadIdx.x;
    int ky = blockIdx.x, b = blockIdx.y;
    int l = t & 63, wv = t >> 6;
    for (int i = t; i < 256; i += 256) tblL[i] = ws[OFF_TBL + i];
    const float4* O4 = (const float4*)(ws + OFF_O);

    // ---- stage O -> Bst (hi/lo) ----
    #pragma unroll
    for (int i = 0; i < 4; i++) {
        int idx = i*256 + t;
        int kx = idx >> 5, u = idx & 31;    // u: uint4 within the 128-float row
        float4 v = O4[((long)(b*32 + kx)*16 + ky)*32 + u];
        int k0 = kx*2;
        #pragma unroll
        for (int p = 0; p < 2; p++) {
            float orr = p ? v.z : v.x;
            float oii = p ? v.w : v.y;
            int n0 = (u*2 + p)*2;           // re column
            int n1 = n0 + 1;                // im column
            unsigned short hi, lo;
            split2(orr, hi, lo);
            { unsigned ad = (unsigned)(n0*70 + (k0 ^ (8*(n0 & 7)))); BstH[ad]=hi; BstL[ad]=lo; }
            { unsigned ad = (unsigned)(n1*70 + ((k0+1) ^ (8*(n1 & 7)))); BstH[ad]=hi; BstL[ad]=lo; }
            split2(oii, hi, lo);
            { unsigned ad = (unsigned)(n1*70 + (k0 ^ (8*(n1 & 7)))); BstH[ad]=hi; BstL[ad]=lo; }
            split2(-oii, hi, lo);
            { unsigned ad = (unsigned)(n0*70 + ((k0+1) ^ (8*(n0 & 7)))); BstH[ad]=hi; BstL[ad]=lo; }
        }
    }
    __syncthreads();
    // ---- A-frags built per-lane from TBL (hi/lo split in-register) ----
    bfrag ah_[2][2], al_[2][2];
    #pragma unroll
    for (int q = 0; q < 2; q++) {
        int h = (wv*2 + q)*16 + (l & 15);
        #pragma unroll
        for (int kcl = 0; kcl < 2; kcl++) {
            int kbase = kcl*32 + (l >> 4)*8;
            bfrag vh, vl;
            #pragma unroll
            for (int j = 0; j < 8; j++) {
                int k = kbase + j;
                int kx = k >> 1, f = kx < 16 ? kx : 96 + kx;
                int m = (f * h) & 127;
                float val = (k & 1) ? tblL[2*m + 1] : tblL[2*m];
                unsigned short hi, lo; split2(val, hi, lo);
                vh[j] = (short)hi; vl[j] = (short)lo;
            }
            ah_[q][kcl] = vh; al_[q][kcl] = vl;
        }
    }
    f4v acc[2][8];
    #pragma unroll
    for (int q = 0; q < 2; q++)
        #pragma unroll
        for (int nt = 0; nt < 8; nt++) acc[q][nt] = (f4v){0.f,0.f,0.f,0.f};
    #pragma unroll
    for (int kcl = 0; kcl < 2; kcl++)
        #pragma unroll
        for (int nt = 0; nt < 8; nt++) {
            int n = nt*16 + (l & 15);
            unsigned ku = (unsigned)((kcl*32 + (l >> 4)*8) ^ (8*(n & 7)));
            bfrag bh = *(const bfrag*)(BstH + n*70 + ku);
            bfrag bl = *(const bfrag*)(BstL + n*70 + ku);
            #pragma unroll
            for (int q = 0; q < 2; q++) {
                f4v a_ = acc[q][nt];
                a_ = MFMA(ah_[q][kcl], bh, a_);
                a_ = MFMA(ah_[q][kcl], bl, a_);
                a_ = MFMA(al_[q][kcl], bh, a_);
                acc[q][nt] = a_;
            }
        }
    // ---- write Q[b][h][ky][n] ----
    float* Q = ws + OFF_PQ;
    #pragma unroll
    for (int q = 0; q < 2; q++)
        #pragma unroll
        for (int nt = 0; nt < 8; nt++)
            #pragma unroll
            for (int r = 0; r < 4; r++) {
                int h = (wv*2 + q)*16 + (l >> 4)*4 + r;
                Q[((long)(b*128 + h))*2048 + ky*128 + nt*16 + (l & 15)] = acc[q][nt][r];
            }
}

// fused MFMA kernel: Y = M@Qm (iDFT-w), z = (Y-mu)*rho, h = GELU(z@W1+b1),
// out = h@W2+b2. LDS diet: hhS aliased onto zhS (wave-private rows, za read
// before first G2 write); Q staged single-bf16 coalesced; norm/bias via L1.
// 52.5KB LDS -> 3 blocks/CU. grid (h=128,b=16).
__global__ __launch_bounds__(256, 3) void k_mlp(const float* __restrict__ mb1,
                      const float* __restrict__ mb2,
                      float* __restrict__ out, const float* __restrict__ ws) {
    __shared__ unsigned short zhS[8192];        // z[w][64c] swz (w&7)<<4; ALIASED as h-half after za read
    __shared__ unsigned short w1hS[8192];       // w1[j][64c], swz (j&7)<<4
    __shared__ unsigned short w2hS[8192];       // w2[o][128j], swz (o&15)<<4
    __shared__ unsigned short qhS[2304];        // QmT[c][36k] single-bf16 (k=2ky+ri, 32 used)
    int t = threadIdx.x;
    int h = blockIdx.x, b = blockIdx.y;
    int l = t & 63, wv = t >> 6;

    const unsigned short* xu = (const unsigned short*)(ws + OFF_X);
    const unsigned short* w1hG = xu;
    const unsigned short* w2hG = xu + 16384;
    const unsigned short* MhG  = xu + 32768, *MlG  = xu + 36864;

    for (int ch = t; ch < 1024; ch += 256) {       // w1: rows j, stride 128B
        int j = ch >> 3, c0 = (ch & 7) * 8;
        unsigned off = (unsigned)(j*128 + c0*2) ^ (unsigned)((j & 7) << 4);
        *(bfrag*)((char*)w1hS + off) = *(const bfrag*)(w1hG + ch*8);
    }
    for (int ch = t; ch < 1024; ch += 256) {       // w2: rows o, stride 256B
        int o = ch >> 4, j0 = (ch & 15) * 8;
        unsigned off = (unsigned)(o*256 + j0*2) ^ (unsigned)((o & 15) << 4);
        *(bfrag*)((char*)w2hS + off) = *(const bfrag*)(w2hG + ch*8);
    }
    // ---- Q staging: coalesced (c fast), single-bf16 ----
    const float* Qp = ws + OFF_PQ + (long)(b*128 + h)*2048;
    for (int i = t; i < 2048; i += 256) {
        int c = i & 63, k = i >> 6;
        float v = Qp[(k >> 1)*128 + c*2 + (k & 1)];
        qhS[c*36 + k] = f2bf_rn(v);
    }
    // M A-frags from global (rows w of this wave's two 16-row tiles)
    bfrag ma_h[2], ma_l[2];
    #pragma unroll
    for (int q = 0; q < 2; q++) {
        int w = (wv + 4*q)*16 + (l & 15);
        ma_h[q] = *(const bfrag*)(MhG + w*32 + (l >> 4)*8);
        ma_l[q] = *(const bfrag*)(MlG + w*32 + (l >> 4)*8);
    }
    // norm params for this lane's 4 ct columns (L1-cached global reads)
    float muA[4], rhA[4];
    #pragma unroll
    for (int ct = 0; ct < 4; ct++) {
        int c = ct*16 + (l & 15);
        float s1 = ws[OFF_S2 + (b*64 + c)*2], s2 = ws[OFF_S2 + (b*64 + c)*2 + 1];
        float m = s1 * (1.f/16384.f);
        float v = s2 * (1.f/16384.f) - m*m;
        muA[ct] = m; rhA[ct] = rsqrtf(v + 1e-5f);
    }
    __syncthreads();   // cross-wave staging -- the ONLY barrier needed

    // ---- G1: Y = M @ Qm ; z = (Y - mu) * rho -> zhS (2-term MFMA) ----
    #pragma unroll
    for (int q = 0; q < 2; q++) {
        int wt = wv + 4*q;
        #pragma unroll
        for (int ct = 0; ct < 4; ct++) {
            unsigned ro = (unsigned)((ct*16 + (l & 15))*72 + (l >> 4)*16);
            bfrag bh = *(const bfrag*)((const char*)qhS + ro);
            f4v acc = {0.f, 0.f, 0.f, 0.f};
            acc = MFMA(ma_h[q], bh, acc);
            acc = MFMA(ma_l[q], bh, acc);
            float mu_ = muA[ct], rh_ = rhA[ct];
            int c = ct*16 + (l & 15);
            #pragma unroll
            for (int r = 0; r < 4; r++) {
                int w = wt*16 + (l >> 4)*4 + r;
                float z = (acc[r] - mu_) * rh_;
                unsigned off = (unsigned)(w*128 + c*2) ^ (unsigned)((w & 7) << 4);
                *(unsigned short*)((char*)zhS + off) = f2bf_rn(z);
            }
        }
    }
    // cache z A-frags (read own-wave rows BEFORE zhS is reused as h-buffer)
    bfrag za[2][2];
    #pragma unroll
    for (int q = 0; q < 2; q++) {
        int w = (wv + 4*q)*16 + (l & 15);
        #pragma unroll
        for (int ks = 0; ks < 2; ks++) {
            unsigned off = (unsigned)(w*128 + (ks*32 + (l >> 4)*8)*2) ^ (unsigned)((w & 7) << 4);
            za[q][ks] = *(const bfrag*)((const char*)zhS + off);
        }
    }
    f4v accO[2][4];
    #pragma unroll
    for (int q = 0; q < 2; q++)
        #pragma unroll
        for (int ot = 0; ot < 4; ot++) accO[q][ot] = (f4v){0.f,0.f,0.f,0.f};

    unsigned short* hhS = zhS;   // alias: both hold only this wave's 32 rows
    #pragma unroll
    for (int jh = 0; jh < 2; jh++) {
        // ---- G2: h-half = GELU(z @ W1[:, jh*64 .. +64) + b1) ----
        #pragma unroll
        for (int q = 0; q < 2; q++) {
            int wt = wv + 4*q;
            #pragma unroll
            for (int jt = 0; jt < 4; jt++) {
                int j = jh*64 + jt*16 + (l & 15);
                f4v acc = {0.f, 0.f, 0.f, 0.f};
                #pragma unroll
                for (int ks = 0; ks < 2; ks++) {
                    unsigned off = (unsigned)(j*128 + (ks*32 + (l >> 4)*8)*2) ^ (unsigned)((j & 7) << 4);
                    bfrag bh = *(const bfrag*)((const char*)w1hS + off);
                    acc = MFMA(za[q][ks], bh, acc);
                }
                float bj = mb1[j];
                #pragma unroll
                for (int r = 0; r < 4; r++) {
                    int w = wt*16 + (l >> 4)*4 + r;
                    float hv = gelu_t(acc[r] + bj);
                    int jl = jt*16 + (l & 15);
                    unsigned off = (unsigned)(w*128 + jl*2) ^ (unsigned)((w & 7) << 4);
                    *(unsigned short*)((char*)hhS + off) = f2bf_rn(hv);
                }
            }
        }
        // ---- G3 partial: out += h-half @ W2[jh*64.., :] (own-wave rows) ----
        #pragma unroll
        for (int q = 0; q < 2; q++) {
            int w = (wv + 4*q)*16 + (l & 15);
            bfrag ha[2];
            #pragma unroll
            for (int ks = 0; ks < 2; ks++) {
                unsigned off = (unsigned)(w*128 + (ks*32 + (l >> 4)*8)*2) ^ (unsigned)((w & 7) << 4);
                ha[ks] = *(const bfrag*)((const char*)hhS + off);
            }
            #pragma unroll
            for (int ot = 0; ot < 4; ot++) {
                int o = ot*16 + (l & 15);
                f4v acc = accO[q][ot];
                #pragma unroll
                for (int ks = 0; ks < 2; ks++) {
                    int jj = jh*64 + ks*32 + (l >> 4)*8;
                    unsigned off = (unsigned)(o*256 + jj*2) ^ (unsigned)((o & 15) << 4);
                    bfrag bh = *(const bfrag*)((const char*)w2hS + off);
                    acc = MFMA(ha[ks], bh, acc);
                }
                accO[q][ot] = acc;
            }
        }
    }
    // ---- store out + b2 (L1) ----
    #pragma unroll
    for (int q = 0; q < 2; q++) {
        int wt = wv + 4*q;
        #pragma unroll
        for (int ot = 0; ot < 4; ot++) {
            int o = ot*16 + (l & 15);
            float bo = mb2[o];
            #pragma unroll
            for (int r = 0; r < 4; r++) {
                int w = wt*16 + (l >> 4)*4 + r;
                out[((long)(b*128 + h)*128 + w)*64 + o] = accO[q][ot][r] + bo;
            }
        }
    }
}

extern "C" void kernel_launch(void* const* d_in, const int* in_sizes, int n_in,
                              void* d_out, int out_size, void* d_ws, size_t ws_size,
                              hipStream_t stream) {
    const float* x   = (const float*)d_in[0];
    const float* w1r = (const float*)d_in[1];
    const float* w1i = (const float*)d_in[2];
    const float* w2r = (const float*)d_in[3];
    const float* w2i = (const float*)d_in[4];
    const float* mw1 = (const float*)d_in[5];
    const float* mb1 = (const float*)d_in[6];
    const float* mw2 = (const float*)d_in[7];
    const float* mb2 = (const float*)d_in[8];
    float* ws  = (float*)d_ws;
    float* out = (float*)d_out;

    k_init  <<<dim3(49),      dim3(256), 0, stream>>>(ws);
    k_trans <<<dim3(64,2),    dim3(256), 0, stream>>>(w1r, w1i, w2r, w2i, ws);
    k_dftw  <<<dim3(32,16),   dim3(256), 0, stream>>>(x, ws);   // direct x read; stats folded
    k_dfth  <<<dim3(16,16),   dim3(256), 0, stream>>>(ws);
    k_mix   <<<dim3(512),     dim3(256), 0, stream>>>(ws);
    k_wmlp  <<<dim3(80),      dim3(256), 0, stream>>>(mw1, mw2, ws);  // X dead after k_mix
    k_pstats<<<dim3(16,4),    dim3(256), 0, stream>>>(ws);
    k_idfth <<<dim3(16,16),   dim3(256), 0, stream>>>(ws);      // MFMA single-GEMM inverse
    k_mlp   <<<dim3(128,16),  dim3(256), 0, stream>>>(mb1, mb2, out, ws);
}

// Round 19
// 140.226 us; speedup vs baseline: 1.8319x; 1.0598x over previous
//
#include <hip/hip_runtime.h>
#include <math.h>

// Problem constants: B=16, H=W=128, C=64, M1=M2=16
// Workspace layout (float offsets):
#define OFF_TBL 0u            // 128 x {cos,sin}(2*pi*m/128)          (256)
#define OFF_S1  256u          // instance-norm-1 raw sums [b*64+c][2] (2048)
#define OFF_S2  2304u         // instance-norm-2 stats (s1,s2)        (2048)
#define OFF_PQ  4352u         // PT2[b][hp32][ky16][c64][ri2][h4] u32 bf16 hi|lo (4194304)
                              //   aliased later with Q[b][h][ky][o][2] f32
#define OFF_X   4198656u      // X[b][kx][ky][c][2] f32               (1048576)
#define OFF_O   5247232u      // Out[b][kx][ky][o][2] f32             (1048576)
                              //   head doubles (pre-mix) as u16 trig tables:
                              //   FdAh[32][128] @0, FdAl @4096, EdAh[64][128] @8192, EdAl @16384
#define OFF_WT  6295808u      // WT[mode][i][o][2]                    (4194304)
// total = 10490112 floats = 41.96 MB
// X region is dead after k_mix -> reuse as u16 arrays for bf16-split MLP weights:
//   u16[0..8192) w1hi   [8192..16384) w1lo   [16384..24576) w2hi
//   [24576..32768) w2lo  [32768..36864) Mhi  [36864..40960) Mlo

typedef __attribute__((ext_vector_type(8))) short bfrag;
typedef __attribute__((ext_vector_type(4))) float f4v;
#define MFMA(A,B,C) __builtin_amdgcn_mfma_f32_16x16x32_bf16(A,B,C,0,0,0)

// compile-time float4 component select -- NO address-taken indexing (scratch hazard)
#define F4GET(v, i) ((i)==0 ? (v).x : (i)==1 ? (v).y : (i)==2 ? (v).z : (v).w)

__device__ __forceinline__ unsigned short f2bf_rn(float x) {
    unsigned u = __float_as_uint(x);
    unsigned r = u + 0x7FFFu + ((u >> 16) & 1u);
    return (unsigned short)(r >> 16);
}
__device__ __forceinline__ float bf2f(unsigned short h) {
    return __uint_as_float(((unsigned)h) << 16);
}
__device__ __forceinline__ void split2(float x, unsigned short& hi, unsigned short& lo) {
    hi = f2bf_rn(x);
    lo = f2bf_rn(x - bf2f(hi));
}
// tanh-form GELU; matches exact GELU to <1e-5 for |x| <= 0.5 (our range)
__device__ __forceinline__ float gelu_t(float x) {
    float u = 0.79788456080286536f * (x + 0.044715f * x * x * x);
    float e = __expf(2.f * u);
    float th = 1.f - 2.f / (e + 1.f);
    return 0.5f * x * (1.f + th);
}

// block 0: twiddle table + zero S1/S2. blocks 1..48: bf16-split trig tables
// (F for dftw, E for dfth) into the O region (dead until k_mix overwrites).
__global__ void k_init(float* __restrict__ ws) {
    int t = threadIdx.x, bid = blockIdx.x;
    if (bid == 0) {
        if (t < 128) {
            double ang = 6.283185307179586476925286766559 * (double)t / 128.0;
            ws[OFF_TBL + 2*t]     = (float)cos(ang);
            ws[OFF_TBL + 2*t + 1] = (float)sin(ang);
        }
        for (int i = t; i < 4096; i += 256) ws[OFF_S1 + i] = 0.f;
        return;
    }
    int e = (bid - 1)*256 + t;   // 0..12287
    unsigned short* OU = (unsigned short*)(ws + OFF_O);
    const double TWO_PI = 6.283185307179586476925286766559;
    if (e < 4096) {              // FdA[row=ri*16+ky][w]: re rows cos, im rows -sin
        int row = e >> 7, w = e & 127, ky = row & 15;
        double ang = TWO_PI * (double)((ky * w) & 127) / 128.0;
        double v = (row < 16) ? cos(ang) : -sin(ang);
        unsigned short hi, lo; split2((float)v, hi, lo);
        OU[e] = hi; OU[4096 + e] = lo;
    } else {                     // EdA[row=2kx+s][h]: s=0 cos, s=1 sin (of freq f(kx))
        int e2 = e - 4096, row = e2 >> 7, h = e2 & 127;
        int kx = row >> 1, f = kx < 16 ? kx : 96 + kx;
        double ang = TWO_PI * (double)((f * h) & 127) / 128.0;
        double v = (row & 1) ? sin(ang) : cos(ang);
        unsigned short hi, lo; split2((float)v, hi, lo);
        OU[8192 + e2] = hi; OU[16384 + e2] = lo;
    }
}

// MERGED: blocks [0,512) = MFMA forward DFT-w (direct x read, single-bf16 x,
// stats folded); blocks [512,640) = spectral weight transpose (independent of
// dftw -> rides in dftw's idle issue slots). LDS union 34816B.
__global__ __launch_bounds__(256) void k_big(const float* __restrict__ x,
        const float* __restrict__ w1r, const float* __restrict__ w1i,
        const float* __restrict__ w2r, const float* __restrict__ w2i,
        float* __restrict__ ws) {
    __shared__ __align__(16) char smem[34816];
    int bid = blockIdx.x;
    int t = threadIdx.x;
    if (bid < 512) {
        // ================= dftw branch =================
        unsigned short* BshH = (unsigned short*)smem;   // [n=hl*64+c][k 64 pad68]
        int hp = bid & 31, b = bid >> 5;
        int l = t & 63, wv = t >> 6;
        const unsigned short* OU = (const unsigned short*)(ws + OFF_O);
        const unsigned short* FdAh = OU, *FdAl = OU + 4096;
        f4v acc[2][4];
        #pragma unroll
        for (int mt = 0; mt < 2; mt++)
            #pragma unroll
            for (int nt = 0; nt < 4; nt++) acc[mt][nt] = (f4v){0.f,0.f,0.f,0.f};

        float s1a[4] = {0,0,0,0}, s2a[4] = {0,0,0,0};   // stats for c = c4*4 + j
        int c4 = t & 15;
        const float* xb = x + ((long)(b*128 + hp*4))*8192;   // 4 h rows

        for (int kc2 = 0; kc2 < 2; kc2++) {
            __syncthreads();                    // protect Bsh from prev MFMA readers
            #pragma unroll
            for (int i = 0; i < 16; i++) {
                int idx = i*256 + t;
                int hw = idx >> 4;              // 0..255: hl = hw>>6, wl = hw&63
                int hl = hw >> 6, wl = hw & 63;
                float4 v = *(const float4*)(xb + ((long)hl*8192) + (kc2*64 + wl)*64 + c4*4);
                #pragma unroll
                for (int j = 0; j < 4; j++) {
                    float f = F4GET(v, j);
                    s1a[j] += f;
                    s2a[j] += f*f;
                    int n = hl*64 + c4*4 + j;
                    unsigned ku = (unsigned)(wl ^ (8*(n & 7)));
                    BshH[n*68 + ku] = f2bf_rn(f);       // single-bf16 x
                }
            }
            __syncthreads();
            #pragma unroll
            for (int kcl = 0; kcl < 2; kcl++) {
                int kglob = kc2*64 + kcl*32 + (l >> 4)*8;
                bfrag mah[2], mal[2];
                #pragma unroll
                for (int mt = 0; mt < 2; mt++) {
                    int row = mt*16 + (l & 15);
                    mah[mt] = *(const bfrag*)(FdAh + row*128 + kglob);
                    mal[mt] = *(const bfrag*)(FdAl + row*128 + kglob);
                }
                #pragma unroll
                for (int nt = 0; nt < 4; nt++) {
                    int n = wv*64 + nt*16 + (l & 15);
                    int kl = kcl*32 + (l >> 4)*8;
                    unsigned ku = (unsigned)(kl ^ (8*(n & 7)));
                    bfrag bh = *(const bfrag*)(BshH + n*68 + ku);
                    #pragma unroll
                    for (int mt = 0; mt < 2; mt++) {
                        f4v a_ = acc[mt][nt];
                        a_ = MFMA(mah[mt], bh, a_);
                        a_ = MFMA(mal[mt], bh, a_);
                        acc[mt][nt] = a_;
                    }
                }
            }
        }
        #pragma unroll
        for (int j = 0; j < 4; j++) {
            s1a[j] += __shfl_down(s1a[j], 16, 64);
            s1a[j] += __shfl_down(s1a[j], 32, 64);
            s2a[j] += __shfl_down(s2a[j], 16, 64);
            s2a[j] += __shfl_down(s2a[j], 32, 64);
        }
        if (l < 16) {
            #pragma unroll
            for (int j = 0; j < 4; j++) {
                int c = c4*4 + j;
                atomicAdd(&ws[OFF_S1 + (b*64 + c)*2],     s1a[j]);
                atomicAdd(&ws[OFF_S1 + (b*64 + c)*2 + 1], s2a[j]);
            }
        }
        __syncthreads();
        unsigned* TB = (unsigned*)smem;   // TB[ky][c*2+ri][h4], stride 520 u32/ky
        #pragma unroll
        for (int mt = 0; mt < 2; mt++)
            #pragma unroll
            for (int nt = 0; nt < 4; nt++)
                #pragma unroll
                for (int rr = 0; rr < 4; rr++) {
                    float v = acc[mt][nt][rr];
                    unsigned short hi, lo; split2(v, hi, lo);
                    int trow = mt*16 + (l >> 4)*4 + rr;
                    int ri = trow >> 4, ky = trow & 15;
                    int c = nt*16 + (l & 15);
                    TB[ky*520 + (c*2 + ri)*4 + wv] = ((unsigned)hi << 16) | lo;
                }
        __syncthreads();
        unsigned* PTb = (unsigned*)(ws + OFF_PQ) + ((long)(b*32 + hp))*8192;
        #pragma unroll
        for (int i = 0; i < 8; i++) {
            int idx = i*256 + t;
            int ky = idx >> 7, m = idx & 127;
            ((uint4*)PTb)[idx] = *(const uint4*)(TB + ky*520 + m*4);
        }
    } else {
        // ================= trans branch =================
        float* Lr = (float*)smem;           // [16][257]
        float* Li = Lr + 16*257;
        int rel = bid - 512;
        int i = rel & 63, part = rel >> 6;
        float* WT = ws + OFF_WT;
        const float* wr = part ? w2r : w1r;
        const float* wi = part ? w2i : w1i;
        for (int oc = 0; oc < 4; oc++) {
            int o0 = oc * 16;
            __syncthreads();
            for (int idx = t; idx < 4096; idx += 256) {
                int oo = idx >> 8, m = idx & 255;
                Lr[oo*257 + m] = wr[(i*64 + o0 + oo)*256 + m];
                Li[oo*257 + m] = wi[(i*64 + o0 + oo)*256 + m];
            }
            __syncthreads();
            for (int idx = t; idx < 8192; idx += 256) {
                int mode = idx >> 5, rem = idx & 31, oo = rem >> 1, ri = rem & 1;
                float val = ri ? Li[oo*257 + mode] : Lr[oo*257 + mode];
                int gm = part*256 + mode;
                WT[((gm*64 + i)*64 + (o0 + oo))*2 + ri] = val;
            }
        }
    }
}

// MFMA forward DFT along h: X[2kx+s][(c,ri)] = EdA @ PT2 (per ky,b).
// Staging reads 2KB contiguous runs per (hp,ky). grid (ky=16, b=16).
__global__ __launch_bounds__(256) void k_dfth(float* __restrict__ ws) {
    __shared__ unsigned Bsh[16384];   // BTh 32KB (128 cols x 256B) | BTl 32KB
    int t = threadIdx.x;
    int ky = blockIdx.x, b = blockIdx.y;
    int l = t & 63, wv = t >> 6;
    char* bh_base = (char*)Bsh;
    char* bl_base = bh_base + 32768;
    const uint4* PT4 = (const uint4*)((const unsigned*)(ws + OFF_PQ));
    const unsigned short* OU = (const unsigned short*)(ws + OFF_O);
    const unsigned short* EdAh = OU + 8192, *EdAl = OU + 16384;

    #pragma unroll
    for (int i = 0; i < 16; i++) {
        int idx = i*256 + t;
        int hp = idx >> 7, n = idx & 127;
        uint4 v = PT4[((long)(b*32 + hp)*16 + ky)*128 + n];
        unsigned h01 = (v.x >> 16) | (v.y & 0xFFFF0000u);
        unsigned h23 = (v.z >> 16) | (v.w & 0xFFFF0000u);
        unsigned l01 = (v.x & 0xFFFFu) | (v.y << 16);
        unsigned l23 = (v.z & 0xFFFFu) | (v.w << 16);
        int kk = hp*4;
        unsigned ad = (unsigned)(n*256 + ((kk*2) ^ ((n & 7) << 4)));
        *(uint2*)(bh_base + ad) = make_uint2(h01, h23);
        *(uint2*)(bl_base + ad) = make_uint2(l01, l23);
    }
    bfrag ea_h[4], ea_l[4];
    #pragma unroll
    for (int kc = 0; kc < 4; kc++) {
        int off = (wv*16 + (l & 15))*128 + kc*32 + (l >> 4)*8;
        ea_h[kc] = *(const bfrag*)(EdAh + off);
        ea_l[kc] = *(const bfrag*)(EdAl + off);
    }
    __syncthreads();
    f4v acc[8];
    #pragma unroll
    for (int nt = 0; nt < 8; nt++) acc[nt] = (f4v){0.f,0.f,0.f,0.f};
    #pragma unroll
    for (int kc = 0; kc < 4; kc++)
        #pragma unroll
        for (int nt = 0; nt < 8; nt++) {
            int col = nt*16 + (l & 15);
            unsigned ro = (unsigned)(col*256 + ((kc*64 + (l >> 4)*16) ^ ((col & 7) << 4)));
            bfrag bh = *(const bfrag*)(bh_base + ro);
            bfrag bl = *(const bfrag*)(bl_base + ro);
            acc[nt] = MFMA(ea_h[kc], bh, acc[nt]);
            acc[nt] = MFMA(ea_h[kc], bl, acc[nt]);
            acc[nt] = MFMA(ea_l[kc], bh, acc[nt]);
        }
    float* X = ws + OFF_X;
    #pragma unroll
    for (int nt = 0; nt < 8; nt++)
        #pragma unroll
        for (int p = 0; p < 2; p++) {
            float s0 = acc[nt][2*p], s1 = acc[nt][2*p + 1];
            float partner = __shfl_xor(s1, 1, 64);
            float res = (l & 1) ? (s0 - partner) : (s0 + partner);
            int kx = wv*8 + (l >> 4)*2 + p;
            X[(((long)b*32 + kx)*16 + ky)*128 + nt*16 + (l & 15)] = res;
        }
}

// per-mode complex mix with rho1 scaling folded into X staging. grid 512 (=mode)
__global__ void k_mix(float* __restrict__ ws) {
    __shared__ float Wsh[8192];
    __shared__ float Xs[2048];
    __shared__ float rhoT[1024];
    int t = threadIdx.x;
    int mode = blockIdx.x;
    int kxI = mode >> 4, ky = mode & 15;
    const float* WT = ws + OFF_WT;
    const float* X = ws + OFF_X;
    float* O = ws + OFF_O;
    for (int i = t; i < 1024; i += 256) {
        float a = ws[OFF_S1 + 2*i], s = ws[OFF_S1 + 2*i + 1];
        float m = a * (1.f/16384.f);
        float v = s * (1.f/16384.f) - m*m;
        rhoT[i] = rsqrtf(v + 1e-5f);
    }
    for (int idx = t; idx < 8192; idx += 256) Wsh[idx] = WT[(long)mode*8192 + idx];
    __syncthreads();
    for (int idx = t; idx < 2048; idx += 256) {
        int b = idx >> 7, r = idx & 127;
        Xs[idx] = X[((b*32 + kxI)*16 + ky)*128 + r] * rhoT[b*64 + (r >> 1)];
    }
    __syncthreads();
    int o = t & 63, bg = t >> 6;
    float accr[4] = {0,0,0,0}, acci[4] = {0,0,0,0};
    for (int i = 0; i < 64; i++) {
        float wr = Wsh[(i*64 + o)*2], wi = Wsh[(i*64 + o)*2 + 1];
        #pragma unroll
        for (int j = 0; j < 4; j++) {
            float xr = Xs[(bg*4 + j)*128 + 2*i], xi = Xs[(bg*4 + j)*128 + 2*i + 1];
            accr[j] += xr*wr - xi*wi;
            acci[j] += xr*wi + xi*wr;
        }
    }
    #pragma unroll
    for (int j = 0; j < 4; j++) {
        int b = bg*4 + j;
        float2* dst = (float2*)(O + ((b*32 + kxI)*16 + ky)*128);
        dst[o] = make_float2(accr[j], acci[j]);
    }
}

// MERGED TAIL: blocks [0,256) = MFMA inverse DFT-h with Parseval stats folded
// into the staging pass (k_pstats deleted); blocks [256,336) = MLP-weight
// bf16-split prep into the dead X region (independent of idfth).
__global__ __launch_bounds__(256) void k_tail(const float* __restrict__ mw1,
        const float* __restrict__ mw2, float* __restrict__ ws) {
    __shared__ unsigned short BstH[128*70];   // [n=o*2+ri][k 64 pad70], swz k^8(n&7)
    __shared__ unsigned short BstL[128*70];
    __shared__ float tblL[256];
    __shared__ float redP[4][32][2];
    int bid = blockIdx.x, t = threadIdx.x;
    if (bid >= 256) {
        // ---- wmlp branch ----
        int i = (bid - 256)*256 + t;   // [0, 20480)
        unsigned short* xu = (unsigned short*)(ws + OFF_X);
        if (i < 8192) {
            unsigned short hi, lo; split2(mw1[i], hi, lo);
            xu[i] = hi; xu[8192 + i] = lo;
        } else if (i < 16384) {
            int k = i - 8192;
            unsigned short hi, lo; split2(mw2[k], hi, lo);
            xu[16384 + k] = hi; xu[24576 + k] = lo;
        } else if (i < 20480) {
            int m = i - 16384;           // w*32 + k
            int w = m >> 5, k = m & 31;
            int ky = k >> 1;
            double ang = 6.283185307179586476925286766559 * (double)((ky * w) & 127) / 128.0;
            double v = (k & 1) ? -sin(ang) : cos(ang);
            double a = (ky == 0) ? 1.0 : 2.0;
            float val = (float)(v * a) * (1.f/16384.f);
            unsigned short hi, lo; split2(val, hi, lo);
            xu[32768 + m] = hi; xu[36864 + m] = lo;
        }
        return;
    }
    // ---- idfth branch (+ pstats fold) ----
    int ky = bid & 15, b = bid >> 4;
    int l = t & 63, wv = t >> 6;
    for (int i = t; i < 256; i += 256) tblL[i] = ws[OFF_TBL + i];
    const float4* O4 = (const float4*)(ws + OFF_O);

    float pw0 = 0.f, pw1 = 0.f;
    #pragma unroll
    for (int i = 0; i < 4; i++) {
        int idx = i*256 + t;
        int kx = idx >> 5, u = idx & 31;    // u: uint4 within the 128-float row
        float4 v = O4[((long)(b*32 + kx)*16 + ky)*32 + u];
        pw0 += v.x*v.x + v.y*v.y;           // power for o = 2u
        pw1 += v.z*v.z + v.w*v.w;           // power for o = 2u+1
        int k0 = kx*2;
        #pragma unroll
        for (int p = 0; p < 2; p++) {
            float orr = p ? v.z : v.x;
            float oii = p ? v.w : v.y;
            int n0 = (u*2 + p)*2;           // re column
            int n1 = n0 + 1;                // im column
            unsigned short hi, lo;
            split2(orr, hi, lo);
            { unsigned ad = (unsigned)(n0*70 + (k0 ^ (8*(n0 & 7)))); BstH[ad]=hi; BstL[ad]=lo; }
            { unsigned ad = (unsigned)(n1*70 + ((k0+1) ^ (8*(n1 & 7)))); BstH[ad]=hi; BstL[ad]=lo; }
            split2(oii, hi, lo);
            { unsigned ad = (unsigned)(n1*70 + (k0 ^ (8*(n1 & 7)))); BstH[ad]=hi; BstL[ad]=lo; }
            split2(-oii, hi, lo);
            { unsigned ad = (unsigned)(n0*70 + ((k0+1) ^ (8*(n0 & 7)))); BstH[ad]=hi; BstL[ad]=lo; }
        }
    }
    pw0 += __shfl_down(pw0, 32, 64);
    pw1 += __shfl_down(pw1, 32, 64);
    if (l < 32) { redP[wv][l][0] = pw0; redP[wv][l][1] = pw1; }
    __syncthreads();
    // ---- Parseval stats: one atomic per o (t<64 -> o=t) ----
    if (t < 64) {
        int u = t >> 1, oo = t & 1;
        int o = t;
        float p = redP[0][u][oo] + redP[1][u][oo] + redP[2][u][oo] + redP[3][u][oo];
        float s2add = (ky == 0 ? 0.5f : 2.f) * p;
        if (ky == 0) {
            const float* Ob = ws + OFF_O + (long)b*65536;
            float ar0 = Ob[2*o], ai0 = Ob[2*o + 1];
            float t1 = ar0*ar0 - ai0*ai0;
            for (int k = 1; k <= 15; k++) {
                float xr = Ob[(k*16)*128 + 2*o],        xi = Ob[(k*16)*128 + 2*o + 1];
                float yr = Ob[((32-k)*16)*128 + 2*o],   yi = Ob[((32-k)*16)*128 + 2*o + 1];
                t1 += 2.f*(xr*yr - xi*yi);
            }
            s2add += 0.5f*t1;
            ws[OFF_S2 + (b*64 + o)*2] = ar0;    // s1 (mean term), unique writer
        }
        atomicAdd(&ws[OFF_S2 + (b*64 + o)*2 + 1], s2add * (1.f/16384.f));
    }
    // ---- A-frags built per-lane from TBL (hi/lo split in-register) ----
    bfrag ah_[2][2], al_[2][2];
    #pragma unroll
    for (int q = 0; q < 2; q++) {
        int h = (wv*2 + q)*16 + (l & 15);
        #pragma unroll
        for (int kcl = 0; kcl < 2; kcl++) {
            int kbase = kcl*32 + (l >> 4)*8;
            bfrag vh, vl;
            #pragma unroll
            for (int j = 0; j < 8; j++) {
                int k = kbase + j;
                int kx = k >> 1, f = kx < 16 ? kx : 96 + kx;
                int m = (f * h) & 127;
                float val = (k & 1) ? tblL[2*m + 1] : tblL[2*m];
                unsigned short hi, lo; split2(val, hi, lo);
                vh[j] = (short)hi; vl[j] = (short)lo;
            }
            ah_[q][kcl] = vh; al_[q][kcl] = vl;
        }
    }
    f4v acc[2][8];
    #pragma unroll
    for (int q = 0; q < 2; q++)
        #pragma unroll
        for (int nt = 0; nt < 8; nt++) acc[q][nt] = (f4v){0.f,0.f,0.f,0.f};
    #pragma unroll
    for (int kcl = 0; kcl < 2; kcl++)
        #pragma unroll
        for (int nt = 0; nt < 8; nt++) {
            int n = nt*16 + (l & 15);
            unsigned ku = (unsigned)((kcl*32 + (l >> 4)*8) ^ (8*(n & 7)));
            bfrag bh = *(const bfrag*)(BstH + n*70 + ku);
            bfrag bl = *(const bfrag*)(BstL + n*70 + ku);
            #pragma unroll
            for (int q = 0; q < 2; q++) {
                f4v a_ = acc[q][nt];
                a_ = MFMA(ah_[q][kcl], bh, a_);
                a_ = MFMA(ah_[q][kcl], bl, a_);
                a_ = MFMA(al_[q][kcl], bh, a_);
                acc[q][nt] = a_;
            }
        }
    // ---- write Q[b][h][ky][n] ----
    float* Q = ws + OFF_PQ;
    #pragma unroll
    for (int q = 0; q < 2; q++)
        #pragma unroll
        for (int nt = 0; nt < 8; nt++)
            #pragma unroll
            for (int r = 0; r < 4; r++) {
                int h = (wv*2 + q)*16 + (l >> 4)*4 + r;
                Q[((long)(b*128 + h))*2048 + ky*128 + nt*16 + (l & 15)] = acc[q][nt][r];
            }
}

// fused MFMA kernel: Y = M@Qm (iDFT-w), z = (Y-mu)*rho, h = GELU(z@W1+b1),
// out = h@W2+b2. LDS diet: hhS aliased onto zhS (wave-private rows, za read
// before first G2 write); Q staged single-bf16 coalesced; norm/bias via L1.
// 52.5KB LDS -> 3 blocks/CU. grid (h=128,b=16).
__global__ __launch_bounds__(256, 3) void k_mlp(const float* __restrict__ mb1,
                      const float* __restrict__ mb2,
                      float* __restrict__ out, const float* __restrict__ ws) {
    __shared__ unsigned short zhS[8192];        // z[w][64c] swz (w&7)<<4; ALIASED as h-half after za read
    __shared__ unsigned short w1hS[8192];       // w1[j][64c], swz (j&7)<<4
    __shared__ unsigned short w2hS[8192];       // w2[o][128j], swz (o&15)<<4
    __shared__ unsigned short qhS[2304];        // QmT[c][36k] single-bf16 (k=2ky+ri, 32 used)
    int t = threadIdx.x;
    int h = blockIdx.x, b = blockIdx.y;
    int l = t & 63, wv = t >> 6;

    const unsigned short* xu = (const unsigned short*)(ws + OFF_X);
    const unsigned short* w1hG = xu;
    const unsigned short* w2hG = xu + 16384;
    const unsigned short* MhG  = xu + 32768, *MlG  = xu + 36864;

    for (int ch = t; ch < 1024; ch += 256) {       // w1: rows j, stride 128B
        int j = ch >> 3, c0 = (ch & 7) * 8;
        unsigned off = (unsigned)(j*128 + c0*2) ^ (unsigned)((j & 7) << 4);
        *(bfrag*)((char*)w1hS + off) = *(const bfrag*)(w1hG + ch*8);
    }
    for (int ch = t; ch < 1024; ch += 256) {       // w2: rows o, stride 256B
        int o = ch >> 4, j0 = (ch & 15) * 8;
        unsigned off = (unsigned)(o*256 + j0*2) ^ (unsigned)((o & 15) << 4);
        *(bfrag*)((char*)w2hS + off) = *(const bfrag*)(w2hG + ch*8);
    }
    // ---- Q staging: coalesced (c fast), single-bf16 ----
    const float* Qp = ws + OFF_PQ + (long)(b*128 + h)*2048;
    for (int i = t; i < 2048; i += 256) {
        int c = i & 63, k = i >> 6;
        float v = Qp[(k >> 1)*128 + c*2 + (k & 1)];
        qhS[c*36 + k] = f2bf_rn(v);
    }
    // M A-frags from global (rows w of this wave's two 16-row tiles)
    bfrag ma_h[2], ma_l[2];
    #pragma unroll
    for (int q = 0; q < 2; q++) {
        int w = (wv + 4*q)*16 + (l & 15);
        ma_h[q] = *(const bfrag*)(MhG + w*32 + (l >> 4)*8);
        ma_l[q] = *(const bfrag*)(MlG + w*32 + (l >> 4)*8);
    }
    // norm params for this lane's 4 ct columns (L1-cached global reads)
    float muA[4], rhA[4];
    #pragma unroll
    for (int ct = 0; ct < 4; ct++) {
        int c = ct*16 + (l & 15);
        float s1 = ws[OFF_S2 + (b*64 + c)*2], s2 = ws[OFF_S2 + (b*64 + c)*2 + 1];
        float m = s1 * (1.f/16384.f);
        float v = s2 * (1.f/16384.f) - m*m;
        muA[ct] = m; rhA[ct] = rsqrtf(v + 1e-5f);
    }
    __syncthreads();   // cross-wave staging -- the ONLY barrier needed

    // ---- G1: Y = M @ Qm ; z = (Y - mu) * rho -> zhS (2-term MFMA) ----
    #pragma unroll
    for (int q = 0; q < 2; q++) {
        int wt = wv + 4*q;
        #pragma unroll
        for (int ct = 0; ct < 4; ct++) {
            unsigned ro = (unsigned)((ct*16 + (l & 15))*72 + (l >> 4)*16);
            bfrag bh = *(const bfrag*)((const char*)qhS + ro);
            f4v acc = {0.f, 0.f, 0.f, 0.f};
            acc = MFMA(ma_h[q], bh, acc);
            acc = MFMA(ma_l[q], bh, acc);
            float mu_ = muA[ct], rh_ = rhA[ct];
            int c = ct*16 + (l & 15);
            #pragma unroll
            for (int r = 0; r < 4; r++) {
                int w = wt*16 + (l >> 4)*4 + r;
                float z = (acc[r] - mu_) * rh_;
                unsigned off = (unsigned)(w*128 + c*2) ^ (unsigned)((w & 7) << 4);
                *(unsigned short*)((char*)zhS + off) = f2bf_rn(z);
            }
        }
    }
    // cache z A-frags (read own-wave rows BEFORE zhS is reused as h-buffer)
    bfrag za[2][2];
    #pragma unroll
    for (int q = 0; q < 2; q++) {
        int w = (wv + 4*q)*16 + (l & 15);
        #pragma unroll
        for (int ks = 0; ks < 2; ks++) {
            unsigned off = (unsigned)(w*128 + (ks*32 + (l >> 4)*8)*2) ^ (unsigned)((w & 7) << 4);
            za[q][ks] = *(const bfrag*)((const char*)zhS + off);
        }
    }
    f4v accO[2][4];
    #pragma unroll
    for (int q = 0; q < 2; q++)
        #pragma unroll
        for (int ot = 0; ot < 4; ot++) accO[q][ot] = (f4v){0.f,0.f,0.f,0.f};

    unsigned short* hhS = zhS;   // alias: both hold only this wave's 32 rows
    #pragma unroll
    for (int jh = 0; jh < 2; jh++) {
        // ---- G2: h-half = GELU(z @ W1[:, jh*64 .. +64) + b1) ----
        #pragma unroll
        for (int q = 0; q < 2; q++) {
            int wt = wv + 4*q;
            #pragma unroll
            for (int jt = 0; jt < 4; jt++) {
                int j = jh*64 + jt*16 + (l & 15);
                f4v acc = {0.f, 0.f, 0.f, 0.f};
                #pragma unroll
                for (int ks = 0; ks < 2; ks++) {
                    unsigned off = (unsigned)(j*128 + (ks*32 + (l >> 4)*8)*2) ^ (unsigned)((j & 7) << 4);
                    bfrag bh = *(const bfrag*)((const char*)w1hS + off);
                    acc = MFMA(za[q][ks], bh, acc);
                }
                float bj = mb1[j];
                #pragma unroll
                for (int r = 0; r < 4; r++) {
                    int w = wt*16 + (l >> 4)*4 + r;
                    float hv = gelu_t(acc[r] + bj);
                    int jl = jt*16 + (l & 15);
                    unsigned off = (unsigned)(w*128 + jl*2) ^ (unsigned)((w & 7) << 4);
                    *(unsigned short*)((char*)hhS + off) = f2bf_rn(hv);
                }
            }
        }
        // ---- G3 partial: out += h-half @ W2[jh*64.., :] (own-wave rows) ----
        #pragma unroll
        for (int q = 0; q < 2; q++) {
            int w = (wv + 4*q)*16 + (l & 15);
            bfrag ha[2];
            #pragma unroll
            for (int ks = 0; ks < 2; ks++) {
                unsigned off = (unsigned)(w*128 + (ks*32 + (l >> 4)*8)*2) ^ (unsigned)((w & 7) << 4);
                ha[ks] = *(const bfrag*)((const char*)hhS + off);
            }
            #pragma unroll
            for (int ot = 0; ot < 4; ot++) {
                int o = ot*16 + (l & 15);
                f4v acc = accO[q][ot];
                #pragma unroll
                for (int ks = 0; ks < 2; ks++) {
                    int jj = jh*64 + ks*32 + (l >> 4)*8;
                    unsigned off = (unsigned)(o*256 + jj*2) ^ (unsigned)((o & 15) << 4);
                    bfrag bh = *(const bfrag*)((const char*)w2hS + off);
                    acc = MFMA(ha[ks], bh, acc);
                }
                accO[q][ot] = acc;
            }
        }
    }
    // ---- store out + b2 (L1) ----
    #pragma unroll
    for (int q = 0; q < 2; q++) {
        int wt = wv + 4*q;
        #pragma unroll
        for (int ot = 0; ot < 4; ot++) {
            int o = ot*16 + (l & 15);
            float bo = mb2[o];
            #pragma unroll
            for (int r = 0; r < 4; r++) {
                int w = wt*16 + (l >> 4)*4 + r;
                out[((long)(b*128 + h)*128 + w)*64 + o] = accO[q][ot][r] + bo;
            }
        }
    }
}

extern "C" void kernel_launch(void* const* d_in, const int* in_sizes, int n_in,
                              void* d_out, int out_size, void* d_ws, size_t ws_size,
                              hipStream_t stream) {
    const float* x   = (const float*)d_in[0];
    const float* w1r = (const float*)d_in[1];
    const float* w1i = (const float*)d_in[2];
    const float* w2r = (const float*)d_in[3];
    const float* w2i = (const float*)d_in[4];
    const float* mw1 = (const float*)d_in[5];
    const float* mb1 = (const float*)d_in[6];
    const float* mw2 = (const float*)d_in[7];
    const float* mb2 = (const float*)d_in[8];
    float* ws  = (float*)d_ws;
    float* out = (float*)d_out;

    k_init <<<dim3(49),      dim3(256), 0, stream>>>(ws);
    k_big  <<<dim3(640),     dim3(256), 0, stream>>>(x, w1r, w1i, w2r, w2i, ws); // dftw ∪ trans
    k_dfth <<<dim3(16,16),   dim3(256), 0, stream>>>(ws);
    k_mix  <<<dim3(512),     dim3(256), 0, stream>>>(ws);
    k_tail <<<dim3(336),     dim3(256), 0, stream>>>(mw1, mw2, ws);  // idfth+pstats ∪ wmlp
    k_mlp  <<<dim3(128,16),  dim3(256), 0, stream>>>(mb1, mb2, out, ws);
}

// Round 20
// 106.743 us; speedup vs baseline: 2.4065x; 1.3137x over previous
//
#include <hip/hip_runtime.h>
#include <math.h>

// Problem constants: B=16, H=W=128, C=64, M1=M2=16
// Workspace layout (float offsets):
#define OFF_TBL 0u            // 128 x {cos,sin}(2*pi*m/128)          (256)
#define OFF_S1  256u          // instance-norm-1 raw sums [b*64+c][2] (2048)
#define OFF_S2  2304u         // instance-norm-2 stats (s1,s2)        (2048)
#define OFF_PQ  4352u         // PT2[b][hp32][ky16][c64][ri2][h4] u32 bf16 hi|lo (4194304)
                              //   aliased later with Q[b][h][ky][o][2] f32
#define OFF_X   4198656u      // X[b][kx][ky][c][2] f32               (1048576)
#define OFF_O   5247232u      // Out[b][kx][ky][o][2] f32             (1048576)
                              //   head doubles (pre-mix) as u16 trig tables:
                              //   FdAh[32][128] @0, FdAl @4096, EdAh[64][128] @8192, EdAl @16384
#define OFF_WT  6295808u      // WT[mode][i][o][2]                    (4194304)
// total = 10490112 floats = 41.96 MB
// X region is dead after k_mix -> reuse as u16 arrays for bf16-split MLP weights:
//   u16[0..8192) w1hi   [8192..16384) w1lo   [16384..24576) w2hi
//   [24576..32768) w2lo  [32768..36864) Mhi  [36864..40960) Mlo

typedef __attribute__((ext_vector_type(8))) short bfrag;
typedef __attribute__((ext_vector_type(4))) float f4v;
#define MFMA(A,B,C) __builtin_amdgcn_mfma_f32_16x16x32_bf16(A,B,C,0,0,0)

// compile-time float4 component select -- NO address-taken indexing (scratch hazard)
#define F4GET(v, i) ((i)==0 ? (v).x : (i)==1 ? (v).y : (i)==2 ? (v).z : (v).w)

__device__ __forceinline__ unsigned short f2bf_rn(float x) {
    unsigned u = __float_as_uint(x);
    unsigned r = u + 0x7FFFu + ((u >> 16) & 1u);
    return (unsigned short)(r >> 16);
}
__device__ __forceinline__ float bf2f(unsigned short h) {
    return __uint_as_float(((unsigned)h) << 16);
}
__device__ __forceinline__ void split2(float x, unsigned short& hi, unsigned short& lo) {
    hi = f2bf_rn(x);
    lo = f2bf_rn(x - bf2f(hi));
}
// tanh-form GELU; matches exact GELU to <1e-5 for |x| <= 0.5 (our range)
__device__ __forceinline__ float gelu_t(float x) {
    float u = 0.79788456080286536f * (x + 0.044715f * x * x * x);
    float e = __expf(2.f * u);
    float th = 1.f - 2.f / (e + 1.f);
    return 0.5f * x * (1.f + th);
}

// async DMA: 64 lanes x 16B -> LDS at (uniform base + lane*16)
__device__ __forceinline__ void gload_lds16(const float* g, float* l) {
    __builtin_amdgcn_global_load_lds(
        (const __attribute__((address_space(1))) void*)g,
        (__attribute__((address_space(3))) void*)l, 16, 0, 0);
}

// block 0: twiddle table + zero S1/S2. blocks 1..48: bf16-split trig tables
// (F for dftw, E for dfth) into the O region (dead until k_mix overwrites).
__global__ void k_init(float* __restrict__ ws) {
    int t = threadIdx.x, bid = blockIdx.x;
    if (bid == 0) {
        if (t < 128) {
            double ang = 6.283185307179586476925286766559 * (double)t / 128.0;
            ws[OFF_TBL + 2*t]     = (float)cos(ang);
            ws[OFF_TBL + 2*t + 1] = (float)sin(ang);
        }
        for (int i = t; i < 4096; i += 256) ws[OFF_S1 + i] = 0.f;
        return;
    }
    int e = (bid - 1)*256 + t;   // 0..12287
    unsigned short* OU = (unsigned short*)(ws + OFF_O);
    const double TWO_PI = 6.283185307179586476925286766559;
    if (e < 4096) {              // FdA[row=ri*16+ky][w]: re rows cos, im rows -sin
        int row = e >> 7, w = e & 127, ky = row & 15;
        double ang = TWO_PI * (double)((ky * w) & 127) / 128.0;
        double v = (row < 16) ? cos(ang) : -sin(ang);
        unsigned short hi, lo; split2((float)v, hi, lo);
        OU[e] = hi; OU[4096 + e] = lo;
    } else {                     // EdA[row=2kx+s][h]: s=0 cos, s=1 sin (of freq f(kx))
        int e2 = e - 4096, row = e2 >> 7, h = e2 & 127;
        int kx = row >> 1, f = kx < 16 ? kx : 96 + kx;
        double ang = TWO_PI * (double)((f * h) & 127) / 128.0;
        double v = (row & 1) ? sin(ang) : cos(ang);
        unsigned short hi, lo; split2((float)v, hi, lo);
        OU[8192 + e2] = hi; OU[16384 + e2] = lo;
    }
}

// MERGED: blocks [0,512) = MFMA forward DFT-w via global_load_lds DMA (f32 x
// straight to LDS, convert at frag-build, stats folded there; wave-private
// chunks -> no block barriers in K-loop); blocks [512,640) = weight transpose.
__global__ __launch_bounds__(256) void k_big(const float* __restrict__ x,
        const float* __restrict__ w1r, const float* __restrict__ w1i,
        const float* __restrict__ w2r, const float* __restrict__ w2i,
        float* __restrict__ ws) {
    __shared__ __align__(16) char smem[33280];
    int bid = blockIdx.x;
    int t = threadIdx.x;
    if (bid < 512) {
        // ================= dftw branch (DMA ingest) =================
        float* Xf = (float*)smem;     // per-wave [8 calls][260 f32] (1040B calls, pad 16B)
        int hp = bid & 31, b = bid >> 5;
        int l = t & 63, wv = t >> 6;
        const unsigned short* OU = (const unsigned short*)(ws + OFF_O);
        const unsigned short* FdAh = OU, *FdAl = OU + 4096;
        f4v acc[2][4];
        #pragma unroll
        for (int mt = 0; mt < 2; mt++)
            #pragma unroll
            for (int nt = 0; nt < 4; nt++) acc[mt][nt] = (f4v){0.f,0.f,0.f,0.f};
        float s1a[4] = {0,0,0,0}, s2a[4] = {0,0,0,0};   // per nt: c = nt*16 + (l&15)
        const float* xb = x + ((long)(b*128 + hp*4 + wv))*8192;   // this wave's h row
        float* XfW = Xf + wv*2080;

        for (int kc = 0; kc < 4; kc++) {
            if (kc) {   // prior chunk's ds_reads must complete before DMA overwrite
                asm volatile("s_waitcnt lgkmcnt(0)" ::: "memory");
                __builtin_amdgcn_sched_barrier(0);
            }
            #pragma unroll
            for (int j = 0; j < 8; j++)
                gload_lds16(xb + (kc*32 + j*4)*64 + l*4, XfW + j*260);
            // A-frags for this chunk (global, L2-hot); covered by the vmcnt wait
            int kglob = kc*32 + (l >> 4)*8;
            bfrag mah[2], mal[2];
            #pragma unroll
            for (int mt = 0; mt < 2; mt++) {
                int row = mt*16 + (l & 15);
                mah[mt] = *(const bfrag*)(FdAh + row*128 + kglob);
                mal[mt] = *(const bfrag*)(FdAl + row*128 + kglob);
            }
            asm volatile("s_waitcnt vmcnt(0)" ::: "memory");
            __builtin_amdgcn_sched_barrier(0);
            #pragma unroll
            for (int nt = 0; nt < 4; nt++) {
                bfrag bh;
                #pragma unroll
                for (int j = 0; j < 8; j++) {
                    int k = (l >> 4)*8 + j;
                    float f = XfW[(k >> 2)*260 + (k & 3)*64 + nt*16 + (l & 15)];
                    s1a[nt] += f;
                    s2a[nt] += f*f;
                    bh[j] = (short)f2bf_rn(f);
                }
                #pragma unroll
                for (int mt = 0; mt < 2; mt++) {
                    f4v a_ = acc[mt][nt];
                    a_ = MFMA(mah[mt], bh, a_);
                    a_ = MFMA(mal[mt], bh, a_);
                    acc[mt][nt] = a_;
                }
            }
        }
        // ---- stats reduce (quads share c) + atomics ----
        #pragma unroll
        for (int nt = 0; nt < 4; nt++) {
            s1a[nt] += __shfl_down(s1a[nt], 16, 64);
            s1a[nt] += __shfl_down(s1a[nt], 32, 64);
            s2a[nt] += __shfl_down(s2a[nt], 16, 64);
            s2a[nt] += __shfl_down(s2a[nt], 32, 64);
        }
        if (l < 16) {
            #pragma unroll
            for (int nt = 0; nt < 4; nt++) {
                int c = nt*16 + l;
                atomicAdd(&ws[OFF_S1 + (b*64 + c)*2],     s1a[nt]);
                atomicAdd(&ws[OFF_S1 + (b*64 + c)*2 + 1], s2a[nt]);
            }
        }
        // ---- epilogue: pack -> TB (aliases Xf), then block-contiguous PT2 ----
        __syncthreads();
        unsigned* TB = (unsigned*)smem;   // TB[ky][c*2+ri][h4], stride 520 u32/ky
        #pragma unroll
        for (int mt = 0; mt < 2; mt++)
            #pragma unroll
            for (int nt = 0; nt < 4; nt++)
                #pragma unroll
                for (int rr = 0; rr < 4; rr++) {
                    float v = acc[mt][nt][rr];
                    unsigned short hi, lo; split2(v, hi, lo);
                    int trow = mt*16 + (l >> 4)*4 + rr;
                    int ri = trow >> 4, ky = trow & 15;
                    int c = nt*16 + (l & 15);
                    TB[ky*520 + (c*2 + ri)*4 + wv] = ((unsigned)hi << 16) | lo;
                }
        __syncthreads();
        unsigned* PTb = (unsigned*)(ws + OFF_PQ) + ((long)(b*32 + hp))*8192;
        #pragma unroll
        for (int i = 0; i < 8; i++) {
            int idx = i*256 + t;
            int ky = idx >> 7, m = idx & 127;
            ((uint4*)PTb)[idx] = *(const uint4*)(TB + ky*520 + m*4);
        }
    } else {
        // ================= trans branch =================
        float* Lr = (float*)smem;           // [16][257]
        float* Li = Lr + 16*257;
        int rel = bid - 512;
        int i = rel & 63, part = rel >> 6;
        float* WT = ws + OFF_WT;
        const float* wr = part ? w2r : w1r;
        const float* wi = part ? w2i : w1i;
        for (int oc = 0; oc < 4; oc++) {
            int o0 = oc * 16;
            __syncthreads();
            for (int idx = t; idx < 4096; idx += 256) {
                int oo = idx >> 8, m = idx & 255;
                Lr[oo*257 + m] = wr[(i*64 + o0 + oo)*256 + m];
                Li[oo*257 + m] = wi[(i*64 + o0 + oo)*256 + m];
            }
            __syncthreads();
            for (int idx = t; idx < 8192; idx += 256) {
                int mode = idx >> 5, rem = idx & 31, oo = rem >> 1, ri = rem & 1;
                float val = ri ? Li[oo*257 + mode] : Lr[oo*257 + mode];
                int gm = part*256 + mode;
                WT[((gm*64 + i)*64 + (o0 + oo))*2 + ri] = val;
            }
        }
    }
}

// MFMA forward DFT along h: X[2kx+s][(c,ri)] = EdA @ PT2 (per ky,b).
// Staging reads 2KB contiguous runs per (hp,ky). grid (ky=16, b=16).
__global__ __launch_bounds__(256) void k_dfth(float* __restrict__ ws) {
    __shared__ unsigned Bsh[16384];   // BTh 32KB (128 cols x 256B) | BTl 32KB
    int t = threadIdx.x;
    int ky = blockIdx.x, b = blockIdx.y;
    int l = t & 63, wv = t >> 6;
    char* bh_base = (char*)Bsh;
    char* bl_base = bh_base + 32768;
    const uint4* PT4 = (const uint4*)((const unsigned*)(ws + OFF_PQ));
    const unsigned short* OU = (const unsigned short*)(ws + OFF_O);
    const unsigned short* EdAh = OU + 8192, *EdAl = OU + 16384;

    #pragma unroll
    for (int i = 0; i < 16; i++) {
        int idx = i*256 + t;
        int hp = idx >> 7, n = idx & 127;
        uint4 v = PT4[((long)(b*32 + hp)*16 + ky)*128 + n];
        unsigned h01 = (v.x >> 16) | (v.y & 0xFFFF0000u);
        unsigned h23 = (v.z >> 16) | (v.w & 0xFFFF0000u);
        unsigned l01 = (v.x & 0xFFFFu) | (v.y << 16);
        unsigned l23 = (v.z & 0xFFFFu) | (v.w << 16);
        int kk = hp*4;
        unsigned ad = (unsigned)(n*256 + ((kk*2) ^ ((n & 7) << 4)));
        *(uint2*)(bh_base + ad) = make_uint2(h01, h23);
        *(uint2*)(bl_base + ad) = make_uint2(l01, l23);
    }
    bfrag ea_h[4], ea_l[4];
    #pragma unroll
    for (int kc = 0; kc < 4; kc++) {
        int off = (wv*16 + (l & 15))*128 + kc*32 + (l >> 4)*8;
        ea_h[kc] = *(const bfrag*)(EdAh + off);
        ea_l[kc] = *(const bfrag*)(EdAl + off);
    }
    __syncthreads();
    f4v acc[8];
    #pragma unroll
    for (int nt = 0; nt < 8; nt++) acc[nt] = (f4v){0.f,0.f,0.f,0.f};
    #pragma unroll
    for (int kc = 0; kc < 4; kc++)
        #pragma unroll
        for (int nt = 0; nt < 8; nt++) {
            int col = nt*16 + (l & 15);
            unsigned ro = (unsigned)(col*256 + ((kc*64 + (l >> 4)*16) ^ ((col & 7) << 4)));
            bfrag bh = *(const bfrag*)(bh_base + ro);
            bfrag bl = *(const bfrag*)(bl_base + ro);
            acc[nt] = MFMA(ea_h[kc], bh, acc[nt]);
            acc[nt] = MFMA(ea_h[kc], bl, acc[nt]);
            acc[nt] = MFMA(ea_l[kc], bh, acc[nt]);
        }
    float* X = ws + OFF_X;
    #pragma unroll
    for (int nt = 0; nt < 8; nt++)
        #pragma unroll
        for (int p = 0; p < 2; p++) {
            float s0 = acc[nt][2*p], s1 = acc[nt][2*p + 1];
            float partner = __shfl_xor(s1, 1, 64);
            float res = (l & 1) ? (s0 - partner) : (s0 + partner);
            int kx = wv*8 + (l >> 4)*2 + p;
            X[(((long)b*32 + kx)*16 + ky)*128 + nt*16 + (l & 15)] = res;
        }
}

// per-mode complex mix with rho1 scaling folded into X staging. grid 512 (=mode)
__global__ void k_mix(float* __restrict__ ws) {
    __shared__ float Wsh[8192];
    __shared__ float Xs[2048];
    __shared__ float rhoT[1024];
    int t = threadIdx.x;
    int mode = blockIdx.x;
    int kxI = mode >> 4, ky = mode & 15;
    const float* WT = ws + OFF_WT;
    const float* X = ws + OFF_X;
    float* O = ws + OFF_O;
    for (int i = t; i < 1024; i += 256) {
        float a = ws[OFF_S1 + 2*i], s = ws[OFF_S1 + 2*i + 1];
        float m = a * (1.f/16384.f);
        float v = s * (1.f/16384.f) - m*m;
        rhoT[i] = rsqrtf(v + 1e-5f);
    }
    for (int idx = t; idx < 8192; idx += 256) Wsh[idx] = WT[(long)mode*8192 + idx];
    __syncthreads();
    for (int idx = t; idx < 2048; idx += 256) {
        int b = idx >> 7, r = idx & 127;
        Xs[idx] = X[((b*32 + kxI)*16 + ky)*128 + r] * rhoT[b*64 + (r >> 1)];
    }
    __syncthreads();
    int o = t & 63, bg = t >> 6;
    float accr[4] = {0,0,0,0}, acci[4] = {0,0,0,0};
    for (int i = 0; i < 64; i++) {
        float wr = Wsh[(i*64 + o)*2], wi = Wsh[(i*64 + o)*2 + 1];
        #pragma unroll
        for (int j = 0; j < 4; j++) {
            float xr = Xs[(bg*4 + j)*128 + 2*i], xi = Xs[(bg*4 + j)*128 + 2*i + 1];
            accr[j] += xr*wr - xi*wi;
            acci[j] += xr*wi + xi*wr;
        }
    }
    #pragma unroll
    for (int j = 0; j < 4; j++) {
        int b = bg*4 + j;
        float2* dst = (float2*)(O + ((b*32 + kxI)*16 + ky)*128);
        dst[o] = make_float2(accr[j], acci[j]);
    }
}

// MERGED TAIL: blocks [0,256) = MFMA inverse DFT-h with Parseval stats folded
// into the staging pass; blocks [256,336) = MLP-weight bf16-split prep.
__global__ __launch_bounds__(256) void k_tail(const float* __restrict__ mw1,
        const float* __restrict__ mw2, float* __restrict__ ws) {
    __shared__ unsigned short BstH[128*70];   // [n=o*2+ri][k 64 pad70], swz k^8(n&7)
    __shared__ unsigned short BstL[128*70];
    __shared__ float tblL[256];
    __shared__ float redP[4][32][2];
    int bid = blockIdx.x, t = threadIdx.x;
    if (bid >= 256) {
        // ---- wmlp branch ----
        int i = (bid - 256)*256 + t;   // [0, 20480)
        unsigned short* xu = (unsigned short*)(ws + OFF_X);
        if (i < 8192) {
            unsigned short hi, lo; split2(mw1[i], hi, lo);
            xu[i] = hi; xu[8192 + i] = lo;
        } else if (i < 16384) {
            int k = i - 8192;
            unsigned short hi, lo; split2(mw2[k], hi, lo);
            xu[16384 + k] = hi; xu[24576 + k] = lo;
        } else if (i < 20480) {
            int m = i - 16384;           // w*32 + k
            int w = m >> 5, k = m & 31;
            int ky = k >> 1;
            double ang = 6.283185307179586476925286766559 * (double)((ky * w) & 127) / 128.0;
            double v = (k & 1) ? -sin(ang) : cos(ang);
            double a = (ky == 0) ? 1.0 : 2.0;
            float val = (float)(v * a) * (1.f/16384.f);
            unsigned short hi, lo; split2(val, hi, lo);
            xu[32768 + m] = hi; xu[36864 + m] = lo;
        }
        return;
    }
    // ---- idfth branch (+ pstats fold) ----
    int ky = bid & 15, b = bid >> 4;
    int l = t & 63, wv = t >> 6;
    for (int i = t; i < 256; i += 256) tblL[i] = ws[OFF_TBL + i];
    const float4* O4 = (const float4*)(ws + OFF_O);

    float pw0 = 0.f, pw1 = 0.f;
    #pragma unroll
    for (int i = 0; i < 4; i++) {
        int idx = i*256 + t;
        int kx = idx >> 5, u = idx & 31;    // u: uint4 within the 128-float row
        float4 v = O4[((long)(b*32 + kx)*16 + ky)*32 + u];
        pw0 += v.x*v.x + v.y*v.y;           // power for o = 2u
        pw1 += v.z*v.z + v.w*v.w;           // power for o = 2u+1
        int k0 = kx*2;
        #pragma unroll
        for (int p = 0; p < 2; p++) {
            float orr = p ? v.z : v.x;
            float oii = p ? v.w : v.y;
            int n0 = (u*2 + p)*2;           // re column
            int n1 = n0 + 1;                // im column
            unsigned short hi, lo;
            split2(orr, hi, lo);
            { unsigned ad = (unsigned)(n0*70 + (k0 ^ (8*(n0 & 7)))); BstH[ad]=hi; BstL[ad]=lo; }
            { unsigned ad = (unsigned)(n1*70 + ((k0+1) ^ (8*(n1 & 7)))); BstH[ad]=hi; BstL[ad]=lo; }
            split2(oii, hi, lo);
            { unsigned ad = (unsigned)(n1*70 + (k0 ^ (8*(n1 & 7)))); BstH[ad]=hi; BstL[ad]=lo; }
            split2(-oii, hi, lo);
            { unsigned ad = (unsigned)(n0*70 + ((k0+1) ^ (8*(n0 & 7)))); BstH[ad]=hi; BstL[ad]=lo; }
        }
    }
    pw0 += __shfl_down(pw0, 32, 64);
    pw1 += __shfl_down(pw1, 32, 64);
    if (l < 32) { redP[wv][l][0] = pw0; redP[wv][l][1] = pw1; }
    __syncthreads();
    if (t < 64) {
        int u = t >> 1, oo = t & 1;
        int o = t;
        float p = redP[0][u][oo] + redP[1][u][oo] + redP[2][u][oo] + redP[3][u][oo];
        float s2add = (ky == 0 ? 0.5f : 2.f) * p;
        if (ky == 0) {
            const float* Ob = ws + OFF_O + (long)b*65536;
            float ar0 = Ob[2*o], ai0 = Ob[2*o + 1];
            float t1 = ar0*ar0 - ai0*ai0;
            for (int k = 1; k <= 15; k++) {
                float xr = Ob[(k*16)*128 + 2*o],        xi = Ob[(k*16)*128 + 2*o + 1];
                float yr = Ob[((32-k)*16)*128 + 2*o],   yi = Ob[((32-k)*16)*128 + 2*o + 1];
                t1 += 2.f*(xr*yr - xi*yi);
            }
            s2add += 0.5f*t1;
            ws[OFF_S2 + (b*64 + o)*2] = ar0;    // s1 (mean term), unique writer
        }
        atomicAdd(&ws[OFF_S2 + (b*64 + o)*2 + 1], s2add * (1.f/16384.f));
    }
    bfrag ah_[2][2], al_[2][2];
    #pragma unroll
    for (int q = 0; q < 2; q++) {
        int h = (wv*2 + q)*16 + (l & 15);
        #pragma unroll
        for (int kcl = 0; kcl < 2; kcl++) {
            int kbase = kcl*32 + (l >> 4)*8;
            bfrag vh, vl;
            #pragma unroll
            for (int j = 0; j < 8; j++) {
                int k = kbase + j;
                int kx = k >> 1, f = kx < 16 ? kx : 96 + kx;
                int m = (f * h) & 127;
                float val = (k & 1) ? tblL[2*m + 1] : tblL[2*m];
                unsigned short hi, lo; split2(val, hi, lo);
                vh[j] = (short)hi; vl[j] = (short)lo;
            }
            ah_[q][kcl] = vh; al_[q][kcl] = vl;
        }
    }
    f4v acc[2][8];
    #pragma unroll
    for (int q = 0; q < 2; q++)
        #pragma unroll
        for (int nt = 0; nt < 8; nt++) acc[q][nt] = (f4v){0.f,0.f,0.f,0.f};
    #pragma unroll
    for (int kcl = 0; kcl < 2; kcl++)
        #pragma unroll
        for (int nt = 0; nt < 8; nt++) {
            int n = nt*16 + (l & 15);
            unsigned ku = (unsigned)((kcl*32 + (l >> 4)*8) ^ (8*(n & 7)));
            bfrag bh = *(const bfrag*)(BstH + n*70 + ku);
            bfrag bl = *(const bfrag*)(BstL + n*70 + ku);
            #pragma unroll
            for (int q = 0; q < 2; q++) {
                f4v a_ = acc[q][nt];
                a_ = MFMA(ah_[q][kcl], bh, a_);
                a_ = MFMA(ah_[q][kcl], bl, a_);
                a_ = MFMA(al_[q][kcl], bh, a_);
                acc[q][nt] = a_;
            }
        }
    float* Q = ws + OFF_PQ;
    #pragma unroll
    for (int q = 0; q < 2; q++)
        #pragma unroll
        for (int nt = 0; nt < 8; nt++)
            #pragma unroll
            for (int r = 0; r < 4; r++) {
                int h = (wv*2 + q)*16 + (l >> 4)*4 + r;
                Q[((long)(b*128 + h))*2048 + ky*128 + nt*16 + (l & 15)] = acc[q][nt][r];
            }
}

// fused MFMA kernel: Y = M@Qm (iDFT-w), z = (Y-mu)*rho, h = GELU(z@W1+b1),
// out = h@W2+b2. 52.5KB LDS -> 3 blocks/CU. grid (h=128,b=16).
__global__ __launch_bounds__(256, 3) void k_mlp(const float* __restrict__ mb1,
                      const float* __restrict__ mb2,
                      float* __restrict__ out, const float* __restrict__ ws) {
    __shared__ unsigned short zhS[8192];        // z[w][64c] swz (w&7)<<4; ALIASED as h-half after za read
    __shared__ unsigned short w1hS[8192];       // w1[j][64c], swz (j&7)<<4
    __shared__ unsigned short w2hS[8192];       // w2[o][128j], swz (o&15)<<4
    __shared__ unsigned short qhS[2304];        // QmT[c][36k] single-bf16 (k=2ky+ri, 32 used)
    int t = threadIdx.x;
    int h = blockIdx.x, b = blockIdx.y;
    int l = t & 63, wv = t >> 6;

    const unsigned short* xu = (const unsigned short*)(ws + OFF_X);
    const unsigned short* w1hG = xu;
    const unsigned short* w2hG = xu + 16384;
    const unsigned short* MhG  = xu + 32768, *MlG  = xu + 36864;

    for (int ch = t; ch < 1024; ch += 256) {       // w1: rows j, stride 128B
        int j = ch >> 3, c0 = (ch & 7) * 8;
        unsigned off = (unsigned)(j*128 + c0*2) ^ (unsigned)((j & 7) << 4);
        *(bfrag*)((char*)w1hS + off) = *(const bfrag*)(w1hG + ch*8);
    }
    for (int ch = t; ch < 1024; ch += 256) {       // w2: rows o, stride 256B
        int o = ch >> 4, j0 = (ch & 15) * 8;
        unsigned off = (unsigned)(o*256 + j0*2) ^ (unsigned)((o & 15) << 4);
        *(bfrag*)((char*)w2hS + off) = *(const bfrag*)(w2hG + ch*8);
    }
    // ---- Q staging: coalesced (c fast), single-bf16 ----
    const float* Qp = ws + OFF_PQ + (long)(b*128 + h)*2048;
    for (int i = t; i < 2048; i += 256) {
        int c = i & 63, k = i >> 6;
        float v = Qp[(k >> 1)*128 + c*2 + (k & 1)];
        qhS[c*36 + k] = f2bf_rn(v);
    }
    bfrag ma_h[2], ma_l[2];
    #pragma unroll
    for (int q = 0; q < 2; q++) {
        int w = (wv + 4*q)*16 + (l & 15);
        ma_h[q] = *(const bfrag*)(MhG + w*32 + (l >> 4)*8);
        ma_l[q] = *(const bfrag*)(MlG + w*32 + (l >> 4)*8);
    }
    float muA[4], rhA[4];
    #pragma unroll
    for (int ct = 0; ct < 4; ct++) {
        int c = ct*16 + (l & 15);
        float s1 = ws[OFF_S2 + (b*64 + c)*2], s2 = ws[OFF_S2 + (b*64 + c)*2 + 1];
        float m = s1 * (1.f/16384.f);
        float v = s2 * (1.f/16384.f) - m*m;
        muA[ct] = m; rhA[ct] = rsqrtf(v + 1e-5f);
    }
    __syncthreads();   // cross-wave staging -- the ONLY barrier needed

    #pragma unroll
    for (int q = 0; q < 2; q++) {
        int wt = wv + 4*q;
        #pragma unroll
        for (int ct = 0; ct < 4; ct++) {
            unsigned ro = (unsigned)((ct*16 + (l & 15))*72 + (l >> 4)*16);
            bfrag bh = *(const bfrag*)((const char*)qhS + ro);
            f4v acc = {0.f, 0.f, 0.f, 0.f};
            acc = MFMA(ma_h[q], bh, acc);
            acc = MFMA(ma_l[q], bh, acc);
            float mu_ = muA[ct], rh_ = rhA[ct];
            int c = ct*16 + (l & 15);
            #pragma unroll
            for (int r = 0; r < 4; r++) {
                int w = wt*16 + (l >> 4)*4 + r;
                float z = (acc[r] - mu_) * rh_;
                unsigned off = (unsigned)(w*128 + c*2) ^ (unsigned)((w & 7) << 4);
                *(unsigned short*)((char*)zhS + off) = f2bf_rn(z);
            }
        }
    }
    bfrag za[2][2];
    #pragma unroll
    for (int q = 0; q < 2; q++) {
        int w = (wv + 4*q)*16 + (l & 15);
        #pragma unroll
        for (int ks = 0; ks < 2; ks++) {
            unsigned off = (unsigned)(w*128 + (ks*32 + (l >> 4)*8)*2) ^ (unsigned)((w & 7) << 4);
            za[q][ks] = *(const bfrag*)((const char*)zhS + off);
        }
    }
    f4v accO[2][4];
    #pragma unroll
    for (int q = 0; q < 2; q++)
        #pragma unroll
        for (int ot = 0; ot < 4; ot++) accO[q][ot] = (f4v){0.f,0.f,0.f,0.f};

    unsigned short* hhS = zhS;   // alias: both hold only this wave's 32 rows
    #pragma unroll
    for (int jh = 0; jh < 2; jh++) {
        #pragma unroll
        for (int q = 0; q < 2; q++) {
            int wt = wv + 4*q;
            #pragma unroll
            for (int jt = 0; jt < 4; jt++) {
                int j = jh*64 + jt*16 + (l & 15);
                f4v acc = {0.f, 0.f, 0.f, 0.f};
                #pragma unroll
                for (int ks = 0; ks < 2; ks++) {
                    unsigned off = (unsigned)(j*128 + (ks*32 + (l >> 4)*8)*2) ^ (unsigned)((j & 7) << 4);
                    bfrag bh = *(const bfrag*)((const char*)w1hS + off);
                    acc = MFMA(za[q][ks], bh, acc);
                }
                float bj = mb1[j];
                #pragma unroll
                for (int r = 0; r < 4; r++) {
                    int w = wt*16 + (l >> 4)*4 + r;
                    float hv = gelu_t(acc[r] + bj);
                    int jl = jt*16 + (l & 15);
                    unsigned off = (unsigned)(w*128 + jl*2) ^ (unsigned)((w & 7) << 4);
                    *(unsigned short*)((char*)hhS + off) = f2bf_rn(hv);
                }
            }
        }
        #pragma unroll
        for (int q = 0; q < 2; q++) {
            int w = (wv + 4*q)*16 + (l & 15);
            bfrag ha[2];
            #pragma unroll
            for (int ks = 0; ks < 2; ks++) {
                unsigned off = (unsigned)(w*128 + (ks*32 + (l >> 4)*8)*2) ^ (unsigned)((w & 7) << 4);
                ha[ks] = *(const bfrag*)((const char*)hhS + off);
            }
            #pragma unroll
            for (int ot = 0; ot < 4; ot++) {
                int o = ot*16 + (l & 15);
                f4v acc = accO[q][ot];
                #pragma unroll
                for (int ks = 0; ks < 2; ks++) {
                    int jj = jh*64 + ks*32 + (l >> 4)*8;
                    unsigned off = (unsigned)(o*256 + jj*2) ^ (unsigned)((o & 15) << 4);
                    bfrag bh = *(const bfrag*)((const char*)w2hS + off);
                    acc = MFMA(ha[ks], bh, acc);
                }
                accO[q][ot] = acc;
            }
        }
    }
    #pragma unroll
    for (int q = 0; q < 2; q++) {
        int wt = wv + 4*q;
        #pragma unroll
        for (int ot = 0; ot < 4; ot++) {
            int o = ot*16 + (l & 15);
            float bo = mb2[o];
            #pragma unroll
            for (int r = 0; r < 4; r++) {
                int w = wt*16 + (l >> 4)*4 + r;
                out[((long)(b*128 + h)*128 + w)*64 + o] = accO[q][ot][r] + bo;
            }
        }
    }
}

extern "C" void kernel_launch(void* const* d_in, const int* in_sizes, int n_in,
                              void* d_out, int out_size, void* d_ws, size_t ws_size,
                              hipStream_t stream) {
    const float* x   = (const float*)d_in[0];
    const float* w1r = (const float*)d_in[1];
    const float* w1i = (const float*)d_in[2];
    const float* w2r = (const float*)d_in[3];
    const float* w2i = (const float*)d_in[4];
    const float* mw1 = (const float*)d_in[5];
    const float* mb1 = (const float*)d_in[6];
    const float* mw2 = (const float*)d_in[7];
    const float* mb2 = (const float*)d_in[8];
    float* ws  = (float*)d_ws;
    float* out = (float*)d_out;

    k_init <<<dim3(49),      dim3(256), 0, stream>>>(ws);
    k_big  <<<dim3(640),     dim3(256), 0, stream>>>(x, w1r, w1i, w2r, w2i, ws); // dftw(DMA) ∪ trans
    k_dfth <<<dim3(16,16),   dim3(256), 0, stream>>>(ws);
    k_mix  <<<dim3(512),     dim3(256), 0, stream>>>(ws);
    k_tail <<<dim3(336),     dim3(256), 0, stream>>>(mw1, mw2, ws);  // idfth+pstats ∪ wmlp
    k_mlp  <<<dim3(128,16),  dim3(256), 0, stream>>>(mb1, mb2, out, ws);
}

// Round 21
// 98.014 us; speedup vs baseline: 2.6208x; 1.0890x over previous
//
#include <hip/hip_runtime.h>
#include <hip/hip_bf16.h>
#include <math.h>

// Problem constants: B=16, H=W=128, C=64, M1=M2=16
// Workspace layout (float offsets):
#define OFF_TBL 0u            // 128 x {cos,sin}(2*pi*m/128)          (256)
#define OFF_S1  256u          // instance-norm-1 raw sums [b*64+c][2] (2048)
#define OFF_S2  2304u         // instance-norm-2 stats (s1,s2)        (2048)
#define OFF_PQ  4352u         // PT2[b][hp32][ky16][c64][ri2][h4] u32 bf16 hi|lo (4194304)
                              //   aliased later with Q[b][h][ky][o][2] f32
#define OFF_X   4198656u      // X[b][kx][ky][c][2] f32               (1048576)
#define OFF_O   5247232u      // Out[b][kx][ky][o][2] f32             (1048576)
                              //   head doubles (pre-mix) as u16 trig tables:
                              //   FdAh[32][128] @0, FdAl @4096, EdAh[64][128] @8192, EdAl @16384
#define OFF_WT  6295808u      // WT[mode][i][o][2]                    (4194304)
// total = 10490112 floats = 41.96 MB
// X region is dead after k_mix -> reuse as u16 arrays for bf16-split MLP weights:
//   u16[0..8192) w1hi   [8192..16384) w1lo   [16384..24576) w2hi
//   [24576..32768) w2lo  [32768..36864) Mhi  [36864..40960) Mlo

typedef __attribute__((ext_vector_type(8))) short bfrag;
typedef __attribute__((ext_vector_type(4))) float f4v;
#define MFMA(A,B,C) __builtin_amdgcn_mfma_f32_16x16x32_bf16(A,B,C,0,0,0)

// compile-time float4 component select -- NO address-taken indexing (scratch hazard)
#define F4GET(v, i) ((i)==0 ? (v).x : (i)==1 ? (v).y : (i)==2 ? (v).z : (v).w)

__device__ __forceinline__ unsigned short f2bf_rn(float x) {
    unsigned u = __float_as_uint(x);
    unsigned r = u + 0x7FFFu + ((u >> 16) & 1u);
    return (unsigned short)(r >> 16);
}
// native RNE conversion (same rounding as f2bf_rn; compiler emits v_cvt)
__device__ __forceinline__ unsigned short f2bf_n(float x) {
    __hip_bfloat16 b = __float2bfloat16(x);
    return __builtin_bit_cast(unsigned short, b);
}
__device__ __forceinline__ float bf2f(unsigned short h) {
    return __uint_as_float(((unsigned)h) << 16);
}
__device__ __forceinline__ void split2(float x, unsigned short& hi, unsigned short& lo) {
    hi = f2bf_rn(x);
    lo = f2bf_rn(x - bf2f(hi));
}
// GELU, sigmoid-rcp form: 0.5x(1+tanh(u)) == x * rcp(1 + exp(-2u)),
// u = 0.79788456(x + 0.044715 x^3). Matches exact GELU <1e-5 for |x|<=0.5.
__device__ __forceinline__ float gelu_t(float x) {
    float t2 = x*x*x;
    float p = __builtin_fmaf(0.044715f, t2, x);
    float e = __expf(-1.5957691216057308f * p);
    return x * __builtin_amdgcn_rcpf(1.f + e);
}

// async DMA: 64 lanes x 16B -> LDS at (uniform base + lane*16)
__device__ __forceinline__ void gload_lds16(const float* g, float* l) {
    __builtin_amdgcn_global_load_lds(
        (const __attribute__((address_space(1))) void*)g,
        (__attribute__((address_space(3))) void*)l, 16, 0, 0);
}

// block 0: twiddle table + zero S1/S2. blocks 1..48: bf16-split trig tables
// (F for dftw, E for dfth) into the O region (dead until k_mix overwrites).
__global__ void k_init(float* __restrict__ ws) {
    int t = threadIdx.x, bid = blockIdx.x;
    if (bid == 0) {
        if (t < 128) {
            double ang = 6.283185307179586476925286766559 * (double)t / 128.0;
            ws[OFF_TBL + 2*t]     = (float)cos(ang);
            ws[OFF_TBL + 2*t + 1] = (float)sin(ang);
        }
        for (int i = t; i < 4096; i += 256) ws[OFF_S1 + i] = 0.f;
        return;
    }
    int e = (bid - 1)*256 + t;   // 0..12287
    unsigned short* OU = (unsigned short*)(ws + OFF_O);
    const double TWO_PI = 6.283185307179586476925286766559;
    if (e < 4096) {              // FdA[row=ri*16+ky][w]: re rows cos, im rows -sin
        int row = e >> 7, w = e & 127, ky = row & 15;
        double ang = TWO_PI * (double)((ky * w) & 127) / 128.0;
        double v = (row < 16) ? cos(ang) : -sin(ang);
        unsigned short hi, lo; split2((float)v, hi, lo);
        OU[e] = hi; OU[4096 + e] = lo;
    } else {                     // EdA[row=2kx+s][h]: s=0 cos, s=1 sin (of freq f(kx))
        int e2 = e - 4096, row = e2 >> 7, h = e2 & 127;
        int kx = row >> 1, f = kx < 16 ? kx : 96 + kx;
        double ang = TWO_PI * (double)((f * h) & 127) / 128.0;
        double v = (row & 1) ? sin(ang) : cos(ang);
        unsigned short hi, lo; split2((float)v, hi, lo);
        OU[8192 + e2] = hi; OU[16384 + e2] = lo;
    }
}

// MERGED: blocks [0,512) = MFMA forward DFT-w via global_load_lds DMA (f32 x
// straight to LDS, convert at frag-build, stats folded there; wave-private
// chunks -> no block barriers in K-loop); blocks [512,640) = weight transpose.
__global__ __launch_bounds__(256) void k_big(const float* __restrict__ x,
        const float* __restrict__ w1r, const float* __restrict__ w1i,
        const float* __restrict__ w2r, const float* __restrict__ w2i,
        float* __restrict__ ws) {
    __shared__ __align__(16) char smem[33280];
    int bid = blockIdx.x;
    int t = threadIdx.x;
    if (bid < 512) {
        // ================= dftw branch (DMA ingest) =================
        float* Xf = (float*)smem;     // per-wave [8 calls][260 f32] (1040B calls, pad 16B)
        int hp = bid & 31, b = bid >> 5;
        int l = t & 63, wv = t >> 6;
        const unsigned short* OU = (const unsigned short*)(ws + OFF_O);
        const unsigned short* FdAh = OU, *FdAl = OU + 4096;
        f4v acc[2][4];
        #pragma unroll
        for (int mt = 0; mt < 2; mt++)
            #pragma unroll
            for (int nt = 0; nt < 4; nt++) acc[mt][nt] = (f4v){0.f,0.f,0.f,0.f};
        float s1a[4] = {0,0,0,0}, s2a[4] = {0,0,0,0};   // per nt: c = nt*16 + (l&15)
        const float* xb = x + ((long)(b*128 + hp*4 + wv))*8192;   // this wave's h row
        float* XfW = Xf + wv*2080;

        for (int kc = 0; kc < 4; kc++) {
            if (kc) {   // prior chunk's ds_reads must complete before DMA overwrite
                asm volatile("s_waitcnt lgkmcnt(0)" ::: "memory");
                __builtin_amdgcn_sched_barrier(0);
            }
            #pragma unroll
            for (int j = 0; j < 8; j++)
                gload_lds16(xb + (kc*32 + j*4)*64 + l*4, XfW + j*260);
            // A-frags for this chunk (global, L2-hot); covered by the vmcnt wait
            int kglob = kc*32 + (l >> 4)*8;
            bfrag mah[2], mal[2];
            #pragma unroll
            for (int mt = 0; mt < 2; mt++) {
                int row = mt*16 + (l & 15);
                mah[mt] = *(const bfrag*)(FdAh + row*128 + kglob);
                mal[mt] = *(const bfrag*)(FdAl + row*128 + kglob);
            }
            asm volatile("s_waitcnt vmcnt(0)" ::: "memory");
            __builtin_amdgcn_sched_barrier(0);
            #pragma unroll
            for (int nt = 0; nt < 4; nt++) {
                bfrag bh;
                #pragma unroll
                for (int j = 0; j < 8; j++) {
                    int k = (l >> 4)*8 + j;
                    float f = XfW[(k >> 2)*260 + (k & 3)*64 + nt*16 + (l & 15)];
                    s1a[nt] += f;
                    s2a[nt] += f*f;
                    bh[j] = (short)f2bf_rn(f);
                }
                #pragma unroll
                for (int mt = 0; mt < 2; mt++) {
                    f4v a_ = acc[mt][nt];
                    a_ = MFMA(mah[mt], bh, a_);
                    a_ = MFMA(mal[mt], bh, a_);
                    acc[mt][nt] = a_;
                }
            }
        }
        // ---- stats reduce (quads share c) + atomics ----
        #pragma unroll
        for (int nt = 0; nt < 4; nt++) {
            s1a[nt] += __shfl_down(s1a[nt], 16, 64);
            s1a[nt] += __shfl_down(s1a[nt], 32, 64);
            s2a[nt] += __shfl_down(s2a[nt], 16, 64);
            s2a[nt] += __shfl_down(s2a[nt], 32, 64);
        }
        if (l < 16) {
            #pragma unroll
            for (int nt = 0; nt < 4; nt++) {
                int c = nt*16 + l;
                atomicAdd(&ws[OFF_S1 + (b*64 + c)*2],     s1a[nt]);
                atomicAdd(&ws[OFF_S1 + (b*64 + c)*2 + 1], s2a[nt]);
            }
        }
        // ---- epilogue: pack -> TB (aliases Xf), then block-contiguous PT2 ----
        __syncthreads();
        unsigned* TB = (unsigned*)smem;   // TB[ky][c*2+ri][h4], stride 520 u32/ky
        #pragma unroll
        for (int mt = 0; mt < 2; mt++)
            #pragma unroll
            for (int nt = 0; nt < 4; nt++)
                #pragma unroll
                for (int rr = 0; rr < 4; rr++) {
                    float v = acc[mt][nt][rr];
                    unsigned short hi, lo; split2(v, hi, lo);
                    int trow = mt*16 + (l >> 4)*4 + rr;
                    int ri = trow >> 4, ky = trow & 15;
                    int c = nt*16 + (l & 15);
                    TB[ky*520 + (c*2 + ri)*4 + wv] = ((unsigned)hi << 16) | lo;
                }
        __syncthreads();
        unsigned* PTb = (unsigned*)(ws + OFF_PQ) + ((long)(b*32 + hp))*8192;
        #pragma unroll
        for (int i = 0; i < 8; i++) {
            int idx = i*256 + t;
            int ky = idx >> 7, m = idx & 127;
            ((uint4*)PTb)[idx] = *(const uint4*)(TB + ky*520 + m*4);
        }
    } else {
        // ================= trans branch =================
        float* Lr = (float*)smem;           // [16][257]
        float* Li = Lr + 16*257;
        int rel = bid - 512;
        int i = rel & 63, part = rel >> 6;
        float* WT = ws + OFF_WT;
        const float* wr = part ? w2r : w1r;
        const float* wi = part ? w2i : w1i;
        for (int oc = 0; oc < 4; oc++) {
            int o0 = oc * 16;
            __syncthreads();
            for (int idx = t; idx < 4096; idx += 256) {
                int oo = idx >> 8, m = idx & 255;
                Lr[oo*257 + m] = wr[(i*64 + o0 + oo)*256 + m];
                Li[oo*257 + m] = wi[(i*64 + o0 + oo)*256 + m];
            }
            __syncthreads();
            for (int idx = t; idx < 8192; idx += 256) {
                int mode = idx >> 5, rem = idx & 31, oo = rem >> 1, ri = rem & 1;
                float val = ri ? Li[oo*257 + mode] : Lr[oo*257 + mode];
                int gm = part*256 + mode;
                WT[((gm*64 + i)*64 + (o0 + oo))*2 + ri] = val;
            }
        }
    }
}

// MFMA forward DFT along h: X[2kx+s][(c,ri)] = EdA @ PT2 (per ky,b).
// Staging reads 2KB contiguous runs per (hp,ky). grid (ky=16, b=16).
__global__ __launch_bounds__(256) void k_dfth(float* __restrict__ ws) {
    __shared__ unsigned Bsh[16384];   // BTh 32KB (128 cols x 256B) | BTl 32KB
    int t = threadIdx.x;
    int ky = blockIdx.x, b = blockIdx.y;
    int l = t & 63, wv = t >> 6;
    char* bh_base = (char*)Bsh;
    char* bl_base = bh_base + 32768;
    const uint4* PT4 = (const uint4*)((const unsigned*)(ws + OFF_PQ));
    const unsigned short* OU = (const unsigned short*)(ws + OFF_O);
    const unsigned short* EdAh = OU + 8192, *EdAl = OU + 16384;

    #pragma unroll
    for (int i = 0; i < 16; i++) {
        int idx = i*256 + t;
        int hp = idx >> 7, n = idx & 127;
        uint4 v = PT4[((long)(b*32 + hp)*16 + ky)*128 + n];
        unsigned h01 = (v.x >> 16) | (v.y & 0xFFFF0000u);
        unsigned h23 = (v.z >> 16) | (v.w & 0xFFFF0000u);
        unsigned l01 = (v.x & 0xFFFFu) | (v.y << 16);
        unsigned l23 = (v.z & 0xFFFFu) | (v.w << 16);
        int kk = hp*4;
        unsigned ad = (unsigned)(n*256 + ((kk*2) ^ ((n & 7) << 4)));
        *(uint2*)(bh_base + ad) = make_uint2(h01, h23);
        *(uint2*)(bl_base + ad) = make_uint2(l01, l23);
    }
    bfrag ea_h[4], ea_l[4];
    #pragma unroll
    for (int kc = 0; kc < 4; kc++) {
        int off = (wv*16 + (l & 15))*128 + kc*32 + (l >> 4)*8;
        ea_h[kc] = *(const bfrag*)(EdAh + off);
        ea_l[kc] = *(const bfrag*)(EdAl + off);
    }
    __syncthreads();
    f4v acc[8];
    #pragma unroll
    for (int nt = 0; nt < 8; nt++) acc[nt] = (f4v){0.f,0.f,0.f,0.f};
    #pragma unroll
    for (int kc = 0; kc < 4; kc++)
        #pragma unroll
        for (int nt = 0; nt < 8; nt++) {
            int col = nt*16 + (l & 15);
            unsigned ro = (unsigned)(col*256 + ((kc*64 + (l >> 4)*16) ^ ((col & 7) << 4)));
            bfrag bh = *(const bfrag*)(bh_base + ro);
            bfrag bl = *(const bfrag*)(bl_base + ro);
            acc[nt] = MFMA(ea_h[kc], bh, acc[nt]);
            acc[nt] = MFMA(ea_h[kc], bl, acc[nt]);
            acc[nt] = MFMA(ea_l[kc], bh, acc[nt]);
        }
    float* X = ws + OFF_X;
    #pragma unroll
    for (int nt = 0; nt < 8; nt++)
        #pragma unroll
        for (int p = 0; p < 2; p++) {
            float s0 = acc[nt][2*p], s1 = acc[nt][2*p + 1];
            float partner = __shfl_xor(s1, 1, 64);
            float res = (l & 1) ? (s0 - partner) : (s0 + partner);
            int kx = wv*8 + (l >> 4)*2 + p;
            X[(((long)b*32 + kx)*16 + ky)*128 + nt*16 + (l & 15)] = res;
        }
}

// per-mode complex mix with rho1 scaling folded into X staging. grid 512 (=mode)
__global__ void k_mix(float* __restrict__ ws) {
    __shared__ float Wsh[8192];
    __shared__ float Xs[2048];
    __shared__ float rhoT[1024];
    int t = threadIdx.x;
    int mode = blockIdx.x;
    int kxI = mode >> 4, ky = mode & 15;
    const float* WT = ws + OFF_WT;
    const float* X = ws + OFF_X;
    float* O = ws + OFF_O;
    for (int i = t; i < 1024; i += 256) {
        float a = ws[OFF_S1 + 2*i], s = ws[OFF_S1 + 2*i + 1];
        float m = a * (1.f/16384.f);
        float v = s * (1.f/16384.f) - m*m;
        rhoT[i] = rsqrtf(v + 1e-5f);
    }
    for (int idx = t; idx < 8192; idx += 256) Wsh[idx] = WT[(long)mode*8192 + idx];
    __syncthreads();
    for (int idx = t; idx < 2048; idx += 256) {
        int b = idx >> 7, r = idx & 127;
        Xs[idx] = X[((b*32 + kxI)*16 + ky)*128 + r] * rhoT[b*64 + (r >> 1)];
    }
    __syncthreads();
    int o = t & 63, bg = t >> 6;
    float accr[4] = {0,0,0,0}, acci[4] = {0,0,0,0};
    for (int i = 0; i < 64; i++) {
        float wr = Wsh[(i*64 + o)*2], wi = Wsh[(i*64 + o)*2 + 1];
        #pragma unroll
        for (int j = 0; j < 4; j++) {
            float xr = Xs[(bg*4 + j)*128 + 2*i], xi = Xs[(bg*4 + j)*128 + 2*i + 1];
            accr[j] += xr*wr - xi*wi;
            acci[j] += xr*wi + xi*wr;
        }
    }
    #pragma unroll
    for (int j = 0; j < 4; j++) {
        int b = bg*4 + j;
        float2* dst = (float2*)(O + ((b*32 + kxI)*16 + ky)*128);
        dst[o] = make_float2(accr[j], acci[j]);
    }
}

// MERGED TAIL: blocks [0,256) = MFMA inverse DFT-h with Parseval stats folded
// into the staging pass; blocks [256,336) = MLP-weight bf16-split prep.
__global__ __launch_bounds__(256) void k_tail(const float* __restrict__ mw1,
        const float* __restrict__ mw2, float* __restrict__ ws) {
    __shared__ unsigned short BstH[128*70];   // [n=o*2+ri][k 64 pad70], swz k^8(n&7)
    __shared__ unsigned short BstL[128*70];
    __shared__ float tblL[256];
    __shared__ float redP[4][32][2];
    int bid = blockIdx.x, t = threadIdx.x;
    if (bid >= 256) {
        // ---- wmlp branch ----
        int i = (bid - 256)*256 + t;   // [0, 20480)
        unsigned short* xu = (unsigned short*)(ws + OFF_X);
        if (i < 8192) {
            unsigned short hi, lo; split2(mw1[i], hi, lo);
            xu[i] = hi; xu[8192 + i] = lo;
        } else if (i < 16384) {
            int k = i - 8192;
            unsigned short hi, lo; split2(mw2[k], hi, lo);
            xu[16384 + k] = hi; xu[24576 + k] = lo;
        } else if (i < 20480) {
            int m = i - 16384;           // w*32 + k
            int w = m >> 5, k = m & 31;
            int ky = k >> 1;
            double ang = 6.283185307179586476925286766559 * (double)((ky * w) & 127) / 128.0;
            double v = (k & 1) ? -sin(ang) : cos(ang);
            double a = (ky == 0) ? 1.0 : 2.0;
            float val = (float)(v * a) * (1.f/16384.f);
            unsigned short hi, lo; split2(val, hi, lo);
            xu[32768 + m] = hi; xu[36864 + m] = lo;
        }
        return;
    }
    // ---- idfth branch (+ pstats fold) ----
    int ky = bid & 15, b = bid >> 4;
    int l = t & 63, wv = t >> 6;
    for (int i = t; i < 256; i += 256) tblL[i] = ws[OFF_TBL + i];
    const float4* O4 = (const float4*)(ws + OFF_O);

    float pw0 = 0.f, pw1 = 0.f;
    #pragma unroll
    for (int i = 0; i < 4; i++) {
        int idx = i*256 + t;
        int kx = idx >> 5, u = idx & 31;    // u: uint4 within the 128-float row
        float4 v = O4[((long)(b*32 + kx)*16 + ky)*32 + u];
        pw0 += v.x*v.x + v.y*v.y;           // power for o = 2u
        pw1 += v.z*v.z + v.w*v.w;           // power for o = 2u+1
        int k0 = kx*2;
        #pragma unroll
        for (int p = 0; p < 2; p++) {
            float orr = p ? v.z : v.x;
            float oii = p ? v.w : v.y;
            int n0 = (u*2 + p)*2;           // re column
            int n1 = n0 + 1;                // im column
            unsigned short hi, lo;
            split2(orr, hi, lo);
            { unsigned ad = (unsigned)(n0*70 + (k0 ^ (8*(n0 & 7)))); BstH[ad]=hi; BstL[ad]=lo; }
            { unsigned ad = (unsigned)(n1*70 + ((k0+1) ^ (8*(n1 & 7)))); BstH[ad]=hi; BstL[ad]=lo; }
            split2(oii, hi, lo);
            { unsigned ad = (unsigned)(n1*70 + (k0 ^ (8*(n1 & 7)))); BstH[ad]=hi; BstL[ad]=lo; }
            split2(-oii, hi, lo);
            { unsigned ad = (unsigned)(n0*70 + ((k0+1) ^ (8*(n0 & 7)))); BstH[ad]=hi; BstL[ad]=lo; }
        }
    }
    pw0 += __shfl_down(pw0, 32, 64);
    pw1 += __shfl_down(pw1, 32, 64);
    if (l < 32) { redP[wv][l][0] = pw0; redP[wv][l][1] = pw1; }
    __syncthreads();
    if (t < 64) {
        int u = t >> 1, oo = t & 1;
        int o = t;
        float p = redP[0][u][oo] + redP[1][u][oo] + redP[2][u][oo] + redP[3][u][oo];
        float s2add = (ky == 0 ? 0.5f : 2.f) * p;
        if (ky == 0) {
            const float* Ob = ws + OFF_O + (long)b*65536;
            float ar0 = Ob[2*o], ai0 = Ob[2*o + 1];
            float t1 = ar0*ar0 - ai0*ai0;
            for (int k = 1; k <= 15; k++) {
                float xr = Ob[(k*16)*128 + 2*o],        xi = Ob[(k*16)*128 + 2*o + 1];
                float yr = Ob[((32-k)*16)*128 + 2*o],   yi = Ob[((32-k)*16)*128 + 2*o + 1];
                t1 += 2.f*(xr*yr - xi*yi);
            }
            s2add += 0.5f*t1;
            ws[OFF_S2 + (b*64 + o)*2] = ar0;    // s1 (mean term), unique writer
        }
        atomicAdd(&ws[OFF_S2 + (b*64 + o)*2 + 1], s2add * (1.f/16384.f));
    }
    bfrag ah_[2][2], al_[2][2];
    #pragma unroll
    for (int q = 0; q < 2; q++) {
        int h = (wv*2 + q)*16 + (l & 15);
        #pragma unroll
        for (int kcl = 0; kcl < 2; kcl++) {
            int kbase = kcl*32 + (l >> 4)*8;
            bfrag vh, vl;
            #pragma unroll
            for (int j = 0; j < 8; j++) {
                int k = kbase + j;
                int kx = k >> 1, f = kx < 16 ? kx : 96 + kx;
                int m = (f * h) & 127;
                float val = (k & 1) ? tblL[2*m + 1] : tblL[2*m];
                unsigned short hi, lo; split2(val, hi, lo);
                vh[j] = (short)hi; vl[j] = (short)lo;
            }
            ah_[q][kcl] = vh; al_[q][kcl] = vl;
        }
    }
    f4v acc[2][8];
    #pragma unroll
    for (int q = 0; q < 2; q++)
        #pragma unroll
        for (int nt = 0; nt < 8; nt++) acc[q][nt] = (f4v){0.f,0.f,0.f,0.f};
    #pragma unroll
    for (int kcl = 0; kcl < 2; kcl++)
        #pragma unroll
        for (int nt = 0; nt < 8; nt++) {
            int n = nt*16 + (l & 15);
            unsigned ku = (unsigned)((kcl*32 + (l >> 4)*8) ^ (8*(n & 7)));
            bfrag bh = *(const bfrag*)(BstH + n*70 + ku);
            bfrag bl = *(const bfrag*)(BstL + n*70 + ku);
            #pragma unroll
            for (int q = 0; q < 2; q++) {
                f4v a_ = acc[q][nt];
                a_ = MFMA(ah_[q][kcl], bh, a_);
                a_ = MFMA(ah_[q][kcl], bl, a_);
                a_ = MFMA(al_[q][kcl], bh, a_);
                acc[q][nt] = a_;
            }
        }
    float* Q = ws + OFF_PQ;
    #pragma unroll
    for (int q = 0; q < 2; q++)
        #pragma unroll
        for (int nt = 0; nt < 8; nt++)
            #pragma unroll
            for (int r = 0; r < 4; r++) {
                int h = (wv*2 + q)*16 + (l >> 4)*4 + r;
                Q[((long)(b*128 + h))*2048 + ky*128 + nt*16 + (l & 15)] = acc[q][nt][r];
            }
}

// fused MFMA kernel: Y = M@Qm (iDFT-w), z = (Y-mu)*rho, h = GELU(z@W1+b1),
// out = h@W2+b2. VALU diet: native bf16 cvts + sigmoid-rcp GELU.
// 52.5KB LDS -> 3 blocks/CU. grid (h=128,b=16).
__global__ __launch_bounds__(256, 3) void k_mlp(const float* __restrict__ mb1,
                      const float* __restrict__ mb2,
                      float* __restrict__ out, const float* __restrict__ ws) {
    __shared__ unsigned short zhS[8192];        // z[w][64c] swz (w&7)<<4; ALIASED as h-half after za read
    __shared__ unsigned short w1hS[8192];       // w1[j][64c], swz (j&7)<<4
    __shared__ unsigned short w2hS[8192];       // w2[o][128j], swz (o&15)<<4
    __shared__ unsigned short qhS[2304];        // QmT[c][36k] single-bf16 (k=2ky+ri, 32 used)
    int t = threadIdx.x;
    int h = blockIdx.x, b = blockIdx.y;
    int l = t & 63, wv = t >> 6;

    const unsigned short* xu = (const unsigned short*)(ws + OFF_X);
    const unsigned short* w1hG = xu;
    const unsigned short* w2hG = xu + 16384;
    const unsigned short* MhG  = xu + 32768, *MlG  = xu + 36864;

    for (int ch = t; ch < 1024; ch += 256) {       // w1: rows j, stride 128B
        int j = ch >> 3, c0 = (ch & 7) * 8;
        unsigned off = (unsigned)(j*128 + c0*2) ^ (unsigned)((j & 7) << 4);
        *(bfrag*)((char*)w1hS + off) = *(const bfrag*)(w1hG + ch*8);
    }
    for (int ch = t; ch < 1024; ch += 256) {       // w2: rows o, stride 256B
        int o = ch >> 4, j0 = (ch & 15) * 8;
        unsigned off = (unsigned)(o*256 + j0*2) ^ (unsigned)((o & 15) << 4);
        *(bfrag*)((char*)w2hS + off) = *(const bfrag*)(w2hG + ch*8);
    }
    // ---- Q staging: coalesced (c fast), single-bf16, native cvt ----
    const float* Qp = ws + OFF_PQ + (long)(b*128 + h)*2048;
    for (int i = t; i < 2048; i += 256) {
        int c = i & 63, k = i >> 6;
        float v = Qp[(k >> 1)*128 + c*2 + (k & 1)];
        qhS[c*36 + k] = f2bf_n(v);
    }
    bfrag ma_h[2], ma_l[2];
    #pragma unroll
    for (int q = 0; q < 2; q++) {
        int w = (wv + 4*q)*16 + (l & 15);
        ma_h[q] = *(const bfrag*)(MhG + w*32 + (l >> 4)*8);
        ma_l[q] = *(const bfrag*)(MlG + w*32 + (l >> 4)*8);
    }
    float muA[4], rhA[4];
    #pragma unroll
    for (int ct = 0; ct < 4; ct++) {
        int c = ct*16 + (l & 15);
        float s1 = ws[OFF_S2 + (b*64 + c)*2], s2 = ws[OFF_S2 + (b*64 + c)*2 + 1];
        float m = s1 * (1.f/16384.f);
        float v = s2 * (1.f/16384.f) - m*m;
        muA[ct] = m; rhA[ct] = rsqrtf(v + 1e-5f);
    }
    __syncthreads();   // cross-wave staging -- the ONLY barrier needed

    #pragma unroll
    for (int q = 0; q < 2; q++) {
        int wt = wv + 4*q;
        #pragma unroll
        for (int ct = 0; ct < 4; ct++) {
            unsigned ro = (unsigned)((ct*16 + (l & 15))*72 + (l >> 4)*16);
            bfrag bh = *(const bfrag*)((const char*)qhS + ro);
            f4v acc = {0.f, 0.f, 0.f, 0.f};
            acc = MFMA(ma_h[q], bh, acc);
            acc = MFMA(ma_l[q], bh, acc);
            float mu_ = muA[ct], rh_ = rhA[ct];
            int c = ct*16 + (l & 15);
            #pragma unroll
            for (int r = 0; r < 4; r++) {
                int w = wt*16 + (l >> 4)*4 + r;
                float z = (acc[r] - mu_) * rh_;
                unsigned off = (unsigned)(w*128 + c*2) ^ (unsigned)((w & 7) << 4);
                *(unsigned short*)((char*)zhS + off) = f2bf_n(z);
            }
        }
    }
    bfrag za[2][2];
    #pragma unroll
    for (int q = 0; q < 2; q++) {
        int w = (wv + 4*q)*16 + (l & 15);
        #pragma unroll
        for (int ks = 0; ks < 2; ks++) {
            unsigned off = (unsigned)(w*128 + (ks*32 + (l >> 4)*8)*2) ^ (unsigned)((w & 7) << 4);
            za[q][ks] = *(const bfrag*)((const char*)zhS + off);
        }
    }
    f4v accO[2][4];
    #pragma unroll
    for (int q = 0; q < 2; q++)
        #pragma unroll
        for (int ot = 0; ot < 4; ot++) accO[q][ot] = (f4v){0.f,0.f,0.f,0.f};

    unsigned short* hhS = zhS;   // alias: both hold only this wave's 32 rows
    #pragma unroll
    for (int jh = 0; jh < 2; jh++) {
        #pragma unroll
        for (int q = 0; q < 2; q++) {
            int wt = wv + 4*q;
            #pragma unroll
            for (int jt = 0; jt < 4; jt++) {
                int j = jh*64 + jt*16 + (l & 15);
                f4v acc = {0.f, 0.f, 0.f, 0.f};
                #pragma unroll
                for (int ks = 0; ks < 2; ks++) {
                    unsigned off = (unsigned)(j*128 + (ks*32 + (l >> 4)*8)*2) ^ (unsigned)((j & 7) << 4);
                    bfrag bh = *(const bfrag*)((const char*)w1hS + off);
                    acc = MFMA(za[q][ks], bh, acc);
                }
                float bj = mb1[j];
                #pragma unroll
                for (int r = 0; r < 4; r++) {
                    int w = wt*16 + (l >> 4)*4 + r;
                    float hv = gelu_t(acc[r] + bj);
                    int jl = jt*16 + (l & 15);
                    unsigned off = (unsigned)(w*128 + jl*2) ^ (unsigned)((w & 7) << 4);
                    *(unsigned short*)((char*)hhS + off) = f2bf_n(hv);
                }
            }
        }
        #pragma unroll
        for (int q = 0; q < 2; q++) {
            int w = (wv + 4*q)*16 + (l & 15);
            bfrag ha[2];
            #pragma unroll
            for (int ks = 0; ks < 2; ks++) {
                unsigned off = (unsigned)(w*128 + (ks*32 + (l >> 4)*8)*2) ^ (unsigned)((w & 7) << 4);
                ha[ks] = *(const bfrag*)((const char*)hhS + off);
            }
            #pragma unroll
            for (int ot = 0; ot < 4; ot++) {
                int o = ot*16 + (l & 15);
                f4v acc = accO[q][ot];
                #pragma unroll
                for (int ks = 0; ks < 2; ks++) {
                    int jj = jh*64 + ks*32 + (l >> 4)*8;
                    unsigned off = (unsigned)(o*256 + jj*2) ^ (unsigned)((o & 15) << 4);
                    bfrag bh = *(const bfrag*)((const char*)w2hS + off);
                    acc = MFMA(ha[ks], bh, acc);
                }
                accO[q][ot] = acc;
            }
        }
    }
    #pragma unroll
    for (int q = 0; q < 2; q++) {
        int wt = wv + 4*q;
        #pragma unroll
        for (int ot = 0; ot < 4; ot++) {
            int o = ot*16 + (l & 15);
            float bo = mb2[o];
            #pragma unroll
            for (int r = 0; r < 4; r++) {
                int w = wt*16 + (l >> 4)*4 + r;
                out[((long)(b*128 + h)*128 + w)*64 + o] = accO[q][ot][r] + bo;
            }
        }
    }
}

extern "C" void kernel_launch(void* const* d_in, const int* in_sizes, int n_in,
                              void* d_out, int out_size, void* d_ws, size_t ws_size,
                              hipStream_t stream) {
    const float* x   = (const float*)d_in[0];
    const float* w1r = (const float*)d_in[1];
    const float* w1i = (const float*)d_in[2];
    const float* w2r = (const float*)d_in[3];
    const float* w2i = (const float*)d_in[4];
    const float* mw1 = (const float*)d_in[5];
    const float* mb1 = (const float*)d_in[6];
    const float* mw2 = (const float*)d_in[7];
    const float* mb2 = (const float*)d_in[8];
    float* ws  = (float*)d_ws;
    float* out = (float*)d_out;

    k_init <<<dim3(49),      dim3(256), 0, stream>>>(ws);
    k_big  <<<dim3(640),     dim3(256), 0, stream>>>(x, w1r, w1i, w2r, w2i, ws); // dftw(DMA) ∪ trans
    k_dfth <<<dim3(16,16),   dim3(256), 0, stream>>>(ws);
    k_mix  <<<dim3(512),     dim3(256), 0, stream>>>(ws);
    k_tail <<<dim3(336),     dim3(256), 0, stream>>>(mw1, mw2, ws);  // idfth+pstats ∪ wmlp
    k_mlp  <<<dim3(128,16),  dim3(256), 0, stream>>>(mb1, mb2, out, ws);
}